// Round 1
// baseline (11148.530 us; speedup 1.0000x reference)
//
#include <hip/hip_runtime.h>
#include <cfloat>
#include <cstdint>

// ---------------- constants ----------------
static constexpr int Bb   = 128;
static constexpr int SEQ  = 250;
static constexpr int DM   = 384;
static constexpr int NH   = 8;
static constexpr int DHd  = 48;
static constexpr int HID  = 342;
static constexpr int UU   = 30;   // U == u == 30

// ---------------- threefry2x32 (JAX-exact) ----------------
__device__ __forceinline__ uint32_t rotl32(uint32_t x, int n){ return (x<<n)|(x>>(32-n)); }
#define TF_R(x0,x1,r) { x0 += x1; x1 = rotl32(x1,(r)); x1 ^= x0; }
__device__ inline void threefry(uint32_t k0, uint32_t k1, uint32_t x0, uint32_t x1,
                                uint32_t &o0, uint32_t &o1){
  uint32_t ks2 = k0 ^ k1 ^ 0x1BD11BDAu;
  x0 += k0; x1 += k1;
  TF_R(x0,x1,13) TF_R(x0,x1,15) TF_R(x0,x1,26) TF_R(x0,x1,6)
  x0 += k1; x1 += ks2 + 1u;
  TF_R(x0,x1,17) TF_R(x0,x1,29) TF_R(x0,x1,16) TF_R(x0,x1,24)
  x0 += ks2; x1 += k0 + 2u;
  TF_R(x0,x1,13) TF_R(x0,x1,15) TF_R(x0,x1,26) TF_R(x0,x1,6)
  x0 += k0; x1 += k1 + 3u;
  TF_R(x0,x1,17) TF_R(x0,x1,29) TF_R(x0,x1,16) TF_R(x0,x1,24)
  x0 += k1; x1 += ks2 + 4u;
  TF_R(x0,x1,13) TF_R(x0,x1,15) TF_R(x0,x1,26) TF_R(x0,x1,6)
  x0 += ks2; x1 += k0 + 5u;
  o0 = x0; o1 = x1;
}

// idx = jax.random.randint(fold_in(key(42), l), (250,30), 0, 250) for l in 0..3
__global__ void idx_kernel(int* __restrict__ IDX){
  int i = blockIdx.x*256 + threadIdx.x;
  if (i >= 4*7500) return;
  int l = i / 7500;        // layer
  int t = i % 7500;        // flat index into (250,30)
  uint32_t fk0, fk1;
  threefry(0u, 42u, 0u, (uint32_t)l, fk0, fk1);      // fold_in
  uint32_t a0,a1,b0,b1;
  threefry(fk0, fk1, 0u, 2u, a0, a1);                // split: block (0,2)
  threefry(fk0, fk1, 1u, 3u, b0, b1);                // split: block (1,3)
  // k1 = (a0,b0) -> higher bits; k2 = (a1,b1) -> lower bits
  uint32_t c0 = (t < 3750) ? (uint32_t)t          : (uint32_t)(t-3750);
  uint32_t c1 = (t < 3750) ? (uint32_t)(t+3750)   : (uint32_t)t;
  uint32_t y0, y1, hi, lo;
  threefry(a0, b0, c0, c1, y0, y1); hi = (t < 3750) ? y0 : y1;
  threefry(a1, b1, c0, c1, y0, y1); lo = (t < 3750) ? y0 : y1;
  uint32_t val = ((hi % 250u) * 46u + (lo % 250u)) % 250u;  // 46 = (2^16%250)^2 % 250
  IDX[i] = (int)val;
}

// ---------------- block reductions ----------------
__device__ __forceinline__ float block_sum(float v, float* red){
  v += __shfl_down(v,32); v += __shfl_down(v,16); v += __shfl_down(v,8);
  v += __shfl_down(v,4);  v += __shfl_down(v,2);  v += __shfl_down(v,1);
  int lane = threadIdx.x & 63, wid = threadIdx.x >> 6, nw = blockDim.x >> 6;
  __syncthreads();
  if (lane == 0) red[wid] = v;
  __syncthreads();
  float r = red[0];
  for (int i=1;i<nw;i++) r += red[i];
  return r;
}
__device__ __forceinline__ float block_max(float v, float* red){
  v = fmaxf(v, __shfl_down(v,32)); v = fmaxf(v, __shfl_down(v,16)); v = fmaxf(v, __shfl_down(v,8));
  v = fmaxf(v, __shfl_down(v,4));  v = fmaxf(v, __shfl_down(v,2));  v = fmaxf(v, __shfl_down(v,1));
  int lane = threadIdx.x & 63, wid = threadIdx.x >> 6, nw = blockDim.x >> 6;
  __syncthreads();
  if (lane == 0) red[wid] = v;
  __syncthreads();
  float r = red[0];
  for (int i=1;i<nw;i++) r = fmaxf(r, red[i]);
  return r;
}

__device__ __forceinline__ float gelu_tanh(float x){
  float t = 0.7978845608028654f * (x + 0.044715f * x * x * x);
  return 0.5f * x * (1.f + tanhf(t));
}

// ---------------- pool (max over 4) + LN + pos ----------------
__global__ __launch_bounds__(384) void pool_ln_pos(const float* __restrict__ xin,
    const float* __restrict__ pos, const float* __restrict__ w, const float* __restrict__ b,
    float* __restrict__ X){
  __shared__ float red[8];
  int bs = blockIdx.x; int bb = bs / SEQ, s = bs % SEQ; int d = threadIdx.x;
  const float* xp = xin + ((size_t)bb*1000 + (size_t)s*4)*DM + d;
  float v = fmaxf(fmaxf(xp[0], xp[DM]), fmaxf(xp[2*DM], xp[3*DM]));
  float mu = block_sum(v, red) * (1.f/DM);
  float diff = v - mu;
  float var = block_sum(diff*diff, red) * (1.f/DM);
  X[(size_t)bs*DM + d] = diff * rsqrtf(var + 1e-5f) * w[d] + b[d] + pos[(size_t)s*DM + d];
}

// ---------------- LayerNorm over last dim (384) ----------------
__global__ __launch_bounds__(384) void ln384(const float* __restrict__ in, float* __restrict__ outp,
    const float* __restrict__ w, const float* __restrict__ b){
  __shared__ float red[8];
  size_t row = blockIdx.x; int d = threadIdx.x;
  float v = in[row*DM + d];
  float mu = block_sum(v, red) * (1.f/DM);
  float diff = v - mu;
  float var = block_sum(diff*diff, red) * (1.f/DM);
  outp[row*DM + d] = diff * rsqrtf(var + 1e-5f) * w[d] + b[d];
}

// ---------------- f32 GEMM: C = A(MxK) @ W(KxN) (+bias) (+=) ----------------
template<bool ACC, bool BIAS>
__global__ __launch_bounds__(256) void gemm128(const float* __restrict__ A, const float* __restrict__ Bm,
    const float* __restrict__ bias, float* __restrict__ C, int M, int N, int K){
  __shared__ float As[8][128];
  __shared__ float Bs[8][128];
  int bm = blockIdx.y * 128, bn = blockIdx.x * 128;
  int tid = threadIdx.x;
  int tx = tid & 15, ty = tid >> 4;
  int arow = tid >> 1, acol = (tid & 1) * 4;
  int brow = tid >> 5, bcol = (tid & 31) * 4;
  const float* Aptr = A + (size_t)(bm + arow)*K + acol;
  const float* Bptr = Bm + (size_t)brow*N + bn + bcol;
  float acc[8][8];
  #pragma unroll
  for (int i=0;i<8;i++)
    #pragma unroll
    for (int j=0;j<8;j++) acc[i][j] = 0.f;
  for (int k0=0; k0<K; k0+=8){
    float4 av = *reinterpret_cast<const float4*>(Aptr + k0);
    float4 bv = *reinterpret_cast<const float4*>(Bptr + (size_t)k0*N);
    __syncthreads();
    As[acol+0][arow]=av.x; As[acol+1][arow]=av.y; As[acol+2][arow]=av.z; As[acol+3][arow]=av.w;
    *reinterpret_cast<float4*>(&Bs[brow][bcol]) = bv;
    __syncthreads();
    #pragma unroll
    for (int kk=0; kk<8; kk++){
      float a[8], bb[8];
      #pragma unroll
      for (int i=0;i<8;i++) a[i] = As[kk][ty*8+i];
      #pragma unroll
      for (int j=0;j<8;j++) bb[j] = Bs[kk][tx*8+j];
      #pragma unroll
      for (int i=0;i<8;i++)
        #pragma unroll
        for (int j=0;j<8;j++) acc[i][j] = fmaf(a[i], bb[j], acc[i][j]);
    }
  }
  #pragma unroll
  for (int i=0;i<8;i++){
    int r = bm + ty*8 + i;
    #pragma unroll
    for (int j=0;j<8;j++){
      int c = bn + tx*8 + j;
      float v = acc[i][j];
      if (BIAS) v += bias[c];
      size_t off = (size_t)r*N + c;
      if (ACC) C[off] += v; else C[off] = v;
    }
  }
}

// ---------------- sampled-score M = max_u(qk) - mean_u(qk) ----------------
__global__ void probe_kernel(const float* __restrict__ Q, const float* __restrict__ Kb,
                             const int* __restrict__ idx, float* __restrict__ M){
  int i = blockIdx.x*256 + threadIdx.x;
  if (i >= Bb*NH*SEQ) return;
  int l = i % SEQ; int h = (i/SEQ) % NH; int b = i / (NH*SEQ);
  const float* q = Q + ((size_t)(b*SEQ + l))*DM + h*DHd;
  float qr[DHd];
  #pragma unroll
  for (int z=0; z<DHd; z++) qr[z] = q[z];
  const int* ip = idx + l*UU;
  float mx = -FLT_MAX, sm = 0.f;
  for (int u=0; u<UU; u++){
    int j = ip[u];
    const float* kp = Kb + ((size_t)(b*SEQ + j))*DM + h*DHd;
    float d = 0.f;
    #pragma unroll
    for (int z=0; z<DHd; z++) d += qr[z]*kp[z];
    mx = fmaxf(mx, d); sm += d;
  }
  M[i] = mx - sm/(float)UU;
}

// ---------------- top-k (30 of 250) per (b,h), JAX tie-break ----------------
__global__ __launch_bounds__(64) void topk_kernel(const float* __restrict__ M, int* __restrict__ TOP){
  int bh = blockIdx.x; int lane = threadIdx.x;
  float vals[4]; int ids[4];
  #pragma unroll
  for (int r=0;r<4;r++){
    int l = r*64 + lane;
    if (l < SEQ){ vals[r] = M[(size_t)bh*SEQ + l]; ids[r] = l; }
    else        { vals[r] = -FLT_MAX; ids[r] = 1<<30; }
  }
  for (int sel=0; sel<UU; sel++){
    float bv = -FLT_MAX; int bi = 1<<30;
    #pragma unroll
    for (int r=0;r<4;r++)
      if (vals[r] > bv || (vals[r] == bv && ids[r] < bi)){ bv = vals[r]; bi = ids[r]; }
    for (int off=32; off; off>>=1){
      float ov = __shfl_xor(bv, off);
      int   oi = __shfl_xor(bi, off);
      if (ov > bv || (ov == bv && oi < bi)){ bv = ov; bi = oi; }
    }
    if (lane == 0) TOP[(size_t)bh*UU + sel] = bi;
    #pragma unroll
    for (int r=0;r<4;r++) if (ids[r] == bi) vals[r] = -FLT_MAX;
  }
}

// ---------------- fused scores+softmax+PV for one (b,h,u) ----------------
__global__ __launch_bounds__(256) void attn_ctx(const float* __restrict__ Q, const float* __restrict__ K,
    const float* __restrict__ V, const int* __restrict__ TOP, float* __restrict__ CT){
  __shared__ float red[8];
  __shared__ float qred[DHd];
  __shared__ float p[SEQ];
  __shared__ float part[5][DHd];
  int bhu = blockIdx.x;
  int u = bhu % UU; int bh = bhu / UU; int h = bh & 7; int b = bh >> 3;
  int t = threadIdx.x;
  int l0 = TOP[bh*UU + u];
  if (t < DHd) qred[t] = Q[((size_t)(b*SEQ + l0))*DM + h*DHd + t];
  __syncthreads();
  float s = -FLT_MAX;
  if (t < SEQ){
    const float* kp = K + ((size_t)(b*SEQ + t))*DM + h*DHd;
    float dacc = 0.f;
    #pragma unroll
    for (int z=0; z<DHd; z++) dacc += qred[z]*kp[z];
    s = dacc / 6.92820323027550917f;   // sqrt(48)
  }
  float mxv = block_max(s, red);
  float e = (t < SEQ) ? expf(s - mxv) : 0.f;
  if (t < SEQ) p[t] = e;
  float sum = block_sum(e, red);
  float inv = 1.f / sum;
  if (t < 240){
    int dh = t % DHd, pr = t / DHd;
    const float* vp = V + ((size_t)b*SEQ)*DM + h*DHd + dh;
    float acc = 0.f;
    int j0 = pr*50;
    for (int j=j0; j<j0+50; j++) acc += p[j] * vp[(size_t)j*DM];
    part[pr][dh] = acc;
  }
  __syncthreads();
  if (t < DHd){
    float acc = (part[0][t]+part[1][t]+part[2][t]+part[3][t]+part[4][t]) * inv;
    CT[((size_t)bh*UU + u)*DHd + t] = acc;
  }
}

// ---------------- v mean over L per (b,h,dh) ----------------
__global__ void vmean_kernel(const float* __restrict__ V, float* __restrict__ VM){
  int i = blockIdx.x*256 + threadIdx.x;
  if (i >= Bb*NH*DHd) return;
  int c = i % DM;          // c = h*48+dh since layout (b, h, dh) == (b, c)
  int b = i / DM;
  const float* vp = V + ((size_t)b*SEQ)*DM + c;
  float s = 0.f;
  for (int l=0;l<SEQ;l++) s += vp[(size_t)l*DM];
  VM[i] = s / (float)SEQ;
}

// ---------------- ctx = broadcast(vmean), then scatter ctx_top ----------------
__global__ void fill_ctx(const float* __restrict__ VM, float* __restrict__ CTX){
  int i = blockIdx.x*256 + threadIdx.x;
  if (i >= Bb*SEQ*DM) return;
  int c = i % DM; int b = i / (SEQ*DM);
  CTX[i] = VM[(size_t)b*DM + c];
}
__global__ void scatter_ctx(const float* __restrict__ CT, const int* __restrict__ TOP,
                            float* __restrict__ CTX){
  int i = blockIdx.x*256 + threadIdx.x;
  if (i >= Bb*NH*UU*DHd) return;
  int dh = i % DHd; int u = (i/DHd) % UU; int bh = i/(DHd*UU); int h = bh & 7; int b = bh >> 3;
  int l = TOP[bh*UU + u];
  CTX[((size_t)(b*SEQ + l))*DM + h*DHd + dh] = CT[i];
}

// ---------------- conv1a: (B,L,384)->(B,L,342), groups=3, k=3, SAME, gelu ----------------
__global__ __launch_bounds__(384) void conv1a_kernel(const float* __restrict__ Hin,
    const float* __restrict__ Wc, const float* __restrict__ bc, float* __restrict__ O){
  int blk = blockIdx.x; int b = blk / 25; int l0 = (blk % 25) * 10;
  __shared__ float hrow[12][DM];
  for (int i = threadIdx.x; i < 12*DM; i += 384){
    int r = i / DM, d = i % DM; int ll = l0 + r - 1;
    hrow[r][d] = (ll >= 0 && ll < SEQ) ? Hin[((size_t)b*SEQ + ll)*DM + d] : 0.f;
  }
  __syncthreads();
  int co = threadIdx.x;
  if (co < HID){
    int g = co / 114;
    const float* wp = Wc + (size_t)co * 128 * 3;
    float acc[10];
    float bbv = bc[co];
    #pragma unroll
    for (int i=0;i<10;i++) acc[i] = bbv;
    for (int ci=0; ci<128; ci++){
      float w0 = wp[ci*3+0], w1 = wp[ci*3+1], w2 = wp[ci*3+2];
      int d = g*128 + ci;
      #pragma unroll
      for (int i=0;i<10;i++)
        acc[i] += w0*hrow[i][d] + w1*hrow[i+1][d] + w2*hrow[i+2][d];
    }
    for (int i=0;i<10;i++)
      O[((size_t)b*SEQ + l0+i)*HID + co] = gelu_tanh(acc[i]);
  }
}

// ---------------- conv1b: (B,L,342)->(B,L,384), groups=3, k=3, SAME, += into X ----------------
__global__ __launch_bounds__(384) void conv1b_kernel(const float* __restrict__ G1,
    const float* __restrict__ Wc, const float* __restrict__ bc, float* __restrict__ X){
  int blk = blockIdx.x; int b = blk / 25; int l0 = (blk % 25) * 10;
  __shared__ float hrow[12][HID];
  for (int i = threadIdx.x; i < 12*HID; i += 384){
    int r = i / HID, d = i % HID; int ll = l0 + r - 1;
    hrow[r][d] = (ll >= 0 && ll < SEQ) ? G1[((size_t)b*SEQ + ll)*HID + d] : 0.f;
  }
  __syncthreads();
  int co = threadIdx.x;       // 0..383, all active
  int g = co >> 7;            // /128
  const float* wp = Wc + (size_t)co * 114 * 3;
  float acc[10];
  float bbv = bc[co];
  #pragma unroll
  for (int i=0;i<10;i++) acc[i] = bbv;
  for (int ci=0; ci<114; ci++){
    float w0 = wp[ci*3+0], w1 = wp[ci*3+1], w2 = wp[ci*3+2];
    int d = g*114 + ci;
    #pragma unroll
    for (int i=0;i<10;i++)
      acc[i] += w0*hrow[i][d] + w1*hrow[i+1][d] + w2*hrow[i+2][d];
  }
  for (int i=0;i<10;i++)
    X[((size_t)b*SEQ + l0+i)*DM + co] += acc[i];
}

// ---------------- conv2: channels=L(250), spatial=D(384), groups=2, k=3, SAME, gelu, += X ----------------
__global__ __launch_bounds__(384) void conv2_kernel(const float* __restrict__ Hin,
    const float* __restrict__ Wc, const float* __restrict__ bc, float* __restrict__ X){
  int blk = blockIdx.x; int b = blk / SEQ; int lo = blk % SEQ;
  int g = lo / 125;
  __shared__ float wrow[375];
  for (int i = threadIdx.x; i < 375; i += 384) wrow[i] = Wc[(size_t)lo*375 + i];
  __syncthreads();
  int d = threadIdx.x;
  const float* hb = Hin + ((size_t)(b*SEQ) + g*125)*DM;
  float acc = bc[lo];
  for (int li=0; li<125; li++){
    const float* hr = hb + (size_t)li*DM;
    float w0 = wrow[li*3+0], w1 = wrow[li*3+1], w2 = wrow[li*3+2];
    float xm1 = (d > 0)   ? hr[d-1] : 0.f;
    float x0  = hr[d];
    float xp1 = (d < 383) ? hr[d+1] : 0.f;
    acc += w0*xm1 + w1*x0 + w2*xp1;
  }
  X[((size_t)(b*SEQ) + lo)*DM + d] += gelu_tanh(acc);
}

// ---------------- final: max over L -> LN(ln2) -> FC ----------------
__global__ __launch_bounds__(384) void final_kernel(const float* __restrict__ Hin,
    const float* __restrict__ w, const float* __restrict__ bparm,
    const float* __restrict__ fcw, const float* __restrict__ fcb, float* __restrict__ out){
  __shared__ float red[8];
  __shared__ float ybuf[DM];
  int b = blockIdx.x; int d = threadIdx.x;
  const float* hp = Hin + (size_t)b*SEQ*DM + d;
  float mx = -FLT_MAX;
  for (int l=0;l<SEQ;l++) mx = fmaxf(mx, hp[(size_t)l*DM]);
  float mu = block_sum(mx, red) * (1.f/DM);
  float diff = mx - mu;
  float var = block_sum(diff*diff, red) * (1.f/DM);
  float y = diff * rsqrtf(var + 1e-5f) * w[d] + bparm[d];
  ybuf[d] = y;
  __syncthreads();
  if (d < 10){
    float acc = fcb[d];
    for (int k=0;k<DM;k++) acc += ybuf[k] * fcw[k*10 + d];
    out[b*10 + d] = acc;
  }
}

// ---------------- host orchestration ----------------
extern "C" void kernel_launch(void* const* d_in, const int* in_sizes, int n_in,
                              void* d_out, int out_size, void* d_ws, size_t ws_size,
                              hipStream_t stream) {
  const float* x     = (const float*)d_in[0];
  const float* pos   = (const float*)d_in[1];
  const float* lniw  = (const float*)d_in[2];
  const float* lnib  = (const float*)d_in[3];
  const float* lnAw  = (const float*)d_in[4];
  const float* lnAb  = (const float*)d_in[5];
  const float* Wq    = (const float*)d_in[6];
  const float* bq    = (const float*)d_in[7];
  const float* Wk    = (const float*)d_in[8];
  const float* bk    = (const float*)d_in[9];
  const float* Wv    = (const float*)d_in[10];
  const float* bv    = (const float*)d_in[11];
  const float* Wo    = (const float*)d_in[12];
  const float* bo    = (const float*)d_in[13];
  const float* lnBw  = (const float*)d_in[14];
  const float* lnBb  = (const float*)d_in[15];
  const float* c1aw  = (const float*)d_in[16];
  const float* c1ab  = (const float*)d_in[17];
  const float* c1bw  = (const float*)d_in[18];
  const float* c1bb  = (const float*)d_in[19];
  const float* lnCw  = (const float*)d_in[20];
  const float* lnCb  = (const float*)d_in[21];
  const float* c2w   = (const float*)d_in[22];
  const float* c2b   = (const float*)d_in[23];
  const float* ln2w  = (const float*)d_in[24];
  const float* ln2b  = (const float*)d_in[25];
  const float* fcw   = (const float*)d_in[26];
  const float* fcb   = (const float*)d_in[27];
  float* out = (float*)d_out;

  const size_t NTOK = (size_t)Bb*SEQ;          // 32000
  const size_t ACT  = NTOK*DM;                  // 12,288,000 floats
  float* Xb  = (float*)d_ws;
  float* Hb  = Xb  + ACT;
  float* Qb  = Hb  + ACT;
  float* Kb  = Qb  + ACT;
  float* Vb  = Kb  + ACT;
  float* CTX = Vb  + ACT;                       // also reused as conv1 mid (B,L,342)
  float* CT  = CTX + ACT;                       // 128*8*30*48 = 1,474,560
  float* Mb  = CT  + (size_t)Bb*NH*UU*DHd;      // 256,000
  float* VM  = Mb  + (size_t)Bb*NH*SEQ;         // 49,152
  int*   TOP = (int*)(VM + (size_t)Bb*DM);      // 30,720 ints
  int*   IDX = TOP + (size_t)Bb*NH*UU;          // 30,000 ints

  idx_kernel<<<dim3(118), dim3(256), 0, stream>>>(IDX);
  pool_ln_pos<<<dim3(32000), dim3(384), 0, stream>>>(x, pos, lniw, lnib, Xb);

  for (int l = 0; l < 4; l++){
    const size_t wofs = (size_t)l*DM*DM;
    ln384<<<dim3(32000), dim3(384), 0, stream>>>(Xb, Hb, lnAw + l*DM, lnAb + l*DM);
    gemm128<false,true><<<dim3(3,250), dim3(256), 0, stream>>>(Hb, Wq + wofs, bq + l*DM, Qb, 32000, DM, DM);
    gemm128<false,true><<<dim3(3,250), dim3(256), 0, stream>>>(Hb, Wk + wofs, bk + l*DM, Kb, 32000, DM, DM);
    gemm128<false,true><<<dim3(3,250), dim3(256), 0, stream>>>(Hb, Wv + wofs, bv + l*DM, Vb, 32000, DM, DM);
    probe_kernel<<<dim3(1000), dim3(256), 0, stream>>>(Qb, Kb, IDX + l*7500, Mb);
    topk_kernel<<<dim3(Bb*NH), dim3(64), 0, stream>>>(Mb, TOP);
    attn_ctx<<<dim3(Bb*NH*UU), dim3(256), 0, stream>>>(Qb, Kb, Vb, TOP, CT);
    vmean_kernel<<<dim3(192), dim3(256), 0, stream>>>(Vb, VM);
    fill_ctx<<<dim3(48000), dim3(256), 0, stream>>>(VM, CTX);
    scatter_ctx<<<dim3(5760), dim3(256), 0, stream>>>(CT, TOP, CTX);
    gemm128<true,true><<<dim3(3,250), dim3(256), 0, stream>>>(CTX, Wo + wofs, bo + l*DM, Xb, 32000, DM, DM);

    ln384<<<dim3(32000), dim3(384), 0, stream>>>(Xb, Hb, lnBw + l*DM, lnBb + l*DM);
    conv1a_kernel<<<dim3(Bb*25), dim3(384), 0, stream>>>(Hb, c1aw + (size_t)l*HID*128*3, c1ab + l*HID, CTX);
    conv1b_kernel<<<dim3(Bb*25), dim3(384), 0, stream>>>(CTX, c1bw + (size_t)l*DM*114*3, c1bb + l*DM, Xb);

    ln384<<<dim3(32000), dim3(384), 0, stream>>>(Xb, Hb, lnCw + l*DM, lnCb + l*DM);
    conv2_kernel<<<dim3(32000), dim3(384), 0, stream>>>(Hb, c2w + (size_t)l*SEQ*125*3, c2b + l*SEQ, Xb);
  }

  ln384<<<dim3(32000), dim3(384), 0, stream>>>(Xb, Hb, ln2w, ln2b);
  final_kernel<<<dim3(Bb), dim3(384), 0, stream>>>(Hb, ln2w, ln2b, fcw, fcb, out);
}

// Round 2
// 8978.592 us; speedup vs baseline: 1.2417x; 1.2417x over previous
//
#include <hip/hip_runtime.h>
#include <cfloat>
#include <cstdint>

// ---------------- constants ----------------
static constexpr int Bb   = 128;
static constexpr int SEQ  = 250;
static constexpr int DM   = 384;
static constexpr int NH   = 8;
static constexpr int DHd  = 48;
static constexpr int HID  = 342;
static constexpr int UU   = 30;   // U == u == 30

// ---------------- threefry2x32 (JAX-exact) ----------------
__device__ __forceinline__ uint32_t rotl32(uint32_t x, int n){ return (x<<n)|(x>>(32-n)); }
#define TF_R(x0,x1,r) { x0 += x1; x1 = rotl32(x1,(r)); x1 ^= x0; }
__device__ inline void threefry(uint32_t k0, uint32_t k1, uint32_t x0, uint32_t x1,
                                uint32_t &o0, uint32_t &o1){
  uint32_t ks2 = k0 ^ k1 ^ 0x1BD11BDAu;
  x0 += k0; x1 += k1;
  TF_R(x0,x1,13) TF_R(x0,x1,15) TF_R(x0,x1,26) TF_R(x0,x1,6)
  x0 += k1; x1 += ks2 + 1u;
  TF_R(x0,x1,17) TF_R(x0,x1,29) TF_R(x0,x1,16) TF_R(x0,x1,24)
  x0 += ks2; x1 += k0 + 2u;
  TF_R(x0,x1,13) TF_R(x0,x1,15) TF_R(x0,x1,26) TF_R(x0,x1,6)
  x0 += k0; x1 += k1 + 3u;
  TF_R(x0,x1,17) TF_R(x0,x1,29) TF_R(x0,x1,16) TF_R(x0,x1,24)
  x0 += k1; x1 += ks2 + 4u;
  TF_R(x0,x1,13) TF_R(x0,x1,15) TF_R(x0,x1,26) TF_R(x0,x1,6)
  x0 += ks2; x1 += k0 + 5u;
  o0 = x0; o1 = x1;
}

// idx = jax.random.randint(fold_in(key(42), l), (250,30), 0, 250) for l in 0..3
__global__ void idx_kernel(int* __restrict__ IDX){
  int i = blockIdx.x*256 + threadIdx.x;
  if (i >= 4*7500) return;
  int l = i / 7500;        // layer
  int t = i % 7500;        // flat index into (250,30)
  uint32_t fk0, fk1;
  threefry(0u, 42u, 0u, (uint32_t)l, fk0, fk1);      // fold_in
  uint32_t a0,a1,b0,b1;
  threefry(fk0, fk1, 0u, 2u, a0, a1);                // split: block (0,2)
  threefry(fk0, fk1, 1u, 3u, b0, b1);                // split: block (1,3)
  uint32_t c0 = (t < 3750) ? (uint32_t)t          : (uint32_t)(t-3750);
  uint32_t c1 = (t < 3750) ? (uint32_t)(t+3750)   : (uint32_t)t;
  uint32_t y0, y1, hi, lo;
  threefry(a0, b0, c0, c1, y0, y1); hi = (t < 3750) ? y0 : y1;
  threefry(a1, b1, c0, c1, y0, y1); lo = (t < 3750) ? y0 : y1;
  uint32_t val = ((hi % 250u) * 46u + (lo % 250u)) % 250u;  // 46 = (2^16%250)^2 % 250
  IDX[i] = (int)val;
}

// ---------------- block reductions ----------------
__device__ __forceinline__ float block_sum(float v, float* red){
  v += __shfl_down(v,32); v += __shfl_down(v,16); v += __shfl_down(v,8);
  v += __shfl_down(v,4);  v += __shfl_down(v,2);  v += __shfl_down(v,1);
  int lane = threadIdx.x & 63, wid = threadIdx.x >> 6, nw = blockDim.x >> 6;
  __syncthreads();
  if (lane == 0) red[wid] = v;
  __syncthreads();
  float r = red[0];
  for (int i=1;i<nw;i++) r += red[i];
  return r;
}
__device__ __forceinline__ float block_max(float v, float* red){
  v = fmaxf(v, __shfl_down(v,32)); v = fmaxf(v, __shfl_down(v,16)); v = fmaxf(v, __shfl_down(v,8));
  v = fmaxf(v, __shfl_down(v,4));  v = fmaxf(v, __shfl_down(v,2));  v = fmaxf(v, __shfl_down(v,1));
  int lane = threadIdx.x & 63, wid = threadIdx.x >> 6, nw = blockDim.x >> 6;
  __syncthreads();
  if (lane == 0) red[wid] = v;
  __syncthreads();
  float r = red[0];
  for (int i=1;i<nw;i++) r = fmaxf(r, red[i]);
  return r;
}

__device__ __forceinline__ float gelu_tanh(float x){
  float t = 0.7978845608028654f * (x + 0.044715f * x * x * x);
  return 0.5f * x * (1.f + tanhf(t));
}

// ---------------- pool (max over 4) + LN + pos ----------------
__global__ __launch_bounds__(384) void pool_ln_pos(const float* __restrict__ xin,
    const float* __restrict__ pos, const float* __restrict__ w, const float* __restrict__ b,
    float* __restrict__ X){
  __shared__ float red[8];
  int bs = blockIdx.x; int bb = bs / SEQ, s = bs % SEQ; int d = threadIdx.x;
  const float* xp = xin + ((size_t)bb*1000 + (size_t)s*4)*DM + d;
  float v = fmaxf(fmaxf(xp[0], xp[DM]), fmaxf(xp[2*DM], xp[3*DM]));
  float mu = block_sum(v, red) * (1.f/DM);
  float diff = v - mu;
  float var = block_sum(diff*diff, red) * (1.f/DM);
  X[(size_t)bs*DM + d] = diff * rsqrtf(var + 1e-5f) * w[d] + b[d] + pos[(size_t)s*DM + d];
}

// ---------------- LayerNorm over last dim (384) ----------------
__global__ __launch_bounds__(384) void ln384(const float* __restrict__ in, float* __restrict__ outp,
    const float* __restrict__ w, const float* __restrict__ b){
  __shared__ float red[8];
  size_t row = blockIdx.x; int d = threadIdx.x;
  float v = in[row*DM + d];
  float mu = block_sum(v, red) * (1.f/DM);
  float diff = v - mu;
  float var = block_sum(diff*diff, red) * (1.f/DM);
  outp[row*DM + d] = diff * rsqrtf(var + 1e-5f) * w[d] + b[d];
}

// ---------------- f32 GEMM: C = A(MxK) @ W(KxN) (+bias) (+=), BK=16 ----------------
template<bool ACC, bool BIAS>
__global__ __launch_bounds__(256) void gemm128(const float* __restrict__ A, const float* __restrict__ Bm,
    const float* __restrict__ bias, float* __restrict__ C, int M, int N, int K){
  __shared__ float As[16][128];
  __shared__ float Bs[16][128];
  int bm = blockIdx.y * 128, bn = blockIdx.x * 128;
  int tid = threadIdx.x;
  int tx = tid & 15, ty = tid >> 4;
  int arow = tid >> 1, acol = (tid & 1) * 8;
  int brow = tid >> 4, bcol = (tid & 15) * 8;
  const float* Aptr = A + (size_t)(bm + arow)*K + acol;
  const float* Bptr = Bm + (size_t)brow*N + bn + bcol;
  float acc[8][8];
  #pragma unroll
  for (int i=0;i<8;i++)
    #pragma unroll
    for (int j=0;j<8;j++) acc[i][j] = 0.f;
  for (int k0=0; k0<K; k0+=16){
    float4 av0 = *reinterpret_cast<const float4*>(Aptr + k0);
    float4 av1 = *reinterpret_cast<const float4*>(Aptr + k0 + 4);
    float4 bv0 = *reinterpret_cast<const float4*>(Bptr + (size_t)k0*N);
    float4 bv1 = *reinterpret_cast<const float4*>(Bptr + (size_t)k0*N + 4);
    __syncthreads();
    As[acol+0][arow]=av0.x; As[acol+1][arow]=av0.y; As[acol+2][arow]=av0.z; As[acol+3][arow]=av0.w;
    As[acol+4][arow]=av1.x; As[acol+5][arow]=av1.y; As[acol+6][arow]=av1.z; As[acol+7][arow]=av1.w;
    *reinterpret_cast<float4*>(&Bs[brow][bcol]) = bv0;
    *reinterpret_cast<float4*>(&Bs[brow][bcol+4]) = bv1;
    __syncthreads();
    #pragma unroll
    for (int kk=0; kk<16; kk++){
      float a[8], bb[8];
      #pragma unroll
      for (int i=0;i<8;i++) a[i] = As[kk][ty*8+i];
      #pragma unroll
      for (int j=0;j<8;j++) bb[j] = Bs[kk][tx*8+j];
      #pragma unroll
      for (int i=0;i<8;i++)
        #pragma unroll
        for (int j=0;j<8;j++) acc[i][j] = fmaf(a[i], bb[j], acc[i][j]);
    }
  }
  #pragma unroll
  for (int i=0;i<8;i++){
    int r = bm + ty*8 + i;
    #pragma unroll
    for (int j=0;j<8;j++){
      int c = bn + tx*8 + j;
      float v = acc[i][j];
      if (BIAS) v += bias[c];
      size_t off = (size_t)r*N + c;
      if (ACC) C[off] += v; else C[off] = v;
    }
  }
}

// ---------------- sampled-score M = max_u(qk) - mean_u(qk) ----------------
__global__ void probe_kernel(const float* __restrict__ Q, const float* __restrict__ Kb,
                             const int* __restrict__ idx, float* __restrict__ M){
  int i = blockIdx.x*256 + threadIdx.x;
  if (i >= Bb*NH*SEQ) return;
  int l = i % SEQ; int h = (i/SEQ) % NH; int b = i / (NH*SEQ);
  const float* q = Q + ((size_t)(b*SEQ + l))*DM + h*DHd;
  float qr[DHd];
  #pragma unroll
  for (int z=0; z<DHd; z++) qr[z] = q[z];
  const int* ip = idx + l*UU;
  float mx = -FLT_MAX, sm = 0.f;
  for (int u=0; u<UU; u++){
    int j = ip[u];
    const float* kp = Kb + ((size_t)(b*SEQ + j))*DM + h*DHd;
    float d = 0.f;
    #pragma unroll
    for (int z=0; z<DHd; z++) d += qr[z]*kp[z];
    mx = fmaxf(mx, d); sm += d;
  }
  M[i] = mx - sm/(float)UU;
}

// ---------------- top-k (30 of 250) per (b,h), JAX tie-break ----------------
__global__ __launch_bounds__(64) void topk_kernel(const float* __restrict__ M, int* __restrict__ TOP){
  int bh = blockIdx.x; int lane = threadIdx.x;
  float vals[4]; int ids[4];
  #pragma unroll
  for (int r=0;r<4;r++){
    int l = r*64 + lane;
    if (l < SEQ){ vals[r] = M[(size_t)bh*SEQ + l]; ids[r] = l; }
    else        { vals[r] = -FLT_MAX; ids[r] = 1<<30; }
  }
  for (int sel=0; sel<UU; sel++){
    float bv = -FLT_MAX; int bi = 1<<30;
    #pragma unroll
    for (int r=0;r<4;r++)
      if (vals[r] > bv || (vals[r] == bv && ids[r] < bi)){ bv = vals[r]; bi = ids[r]; }
    for (int off=32; off; off>>=1){
      float ov = __shfl_xor(bv, off);
      int   oi = __shfl_xor(bi, off);
      if (ov > bv || (ov == bv && oi < bi)){ bv = ov; bi = oi; }
    }
    if (lane == 0) TOP[(size_t)bh*UU + sel] = bi;
    #pragma unroll
    for (int r=0;r<4;r++) if (ids[r] == bi) vals[r] = -FLT_MAX;
  }
}

// ---------------- fused scores+softmax+PV for one (b,h,u) ----------------
__global__ __launch_bounds__(256) void attn_ctx(const float* __restrict__ Q, const float* __restrict__ K,
    const float* __restrict__ V, const int* __restrict__ TOP, float* __restrict__ CT){
  __shared__ float red[8];
  __shared__ float qred[DHd];
  __shared__ float p[SEQ];
  __shared__ float part[5][DHd];
  int bhu = blockIdx.x;
  int u = bhu % UU; int bh = bhu / UU; int h = bh & 7; int b = bh >> 3;
  int t = threadIdx.x;
  int l0 = TOP[bh*UU + u];
  if (t < DHd) qred[t] = Q[((size_t)(b*SEQ + l0))*DM + h*DHd + t];
  __syncthreads();
  float s = -FLT_MAX;
  if (t < SEQ){
    const float* kp = K + ((size_t)(b*SEQ + t))*DM + h*DHd;
    float dacc = 0.f;
    #pragma unroll
    for (int z=0; z<DHd; z++) dacc += qred[z]*kp[z];
    s = dacc / 6.92820323027550917f;   // sqrt(48)
  }
  float mxv = block_max(s, red);
  float e = (t < SEQ) ? expf(s - mxv) : 0.f;
  if (t < SEQ) p[t] = e;
  float sum = block_sum(e, red);
  float inv = 1.f / sum;
  if (t < 240){
    int dh = t % DHd, pr = t / DHd;
    const float* vp = V + ((size_t)b*SEQ)*DM + h*DHd + dh;
    float acc = 0.f;
    int j0 = pr*50;
    for (int j=j0; j<j0+50; j++) acc += p[j] * vp[(size_t)j*DM];
    part[pr][dh] = acc;
  }
  __syncthreads();
  if (t < DHd){
    float acc = (part[0][t]+part[1][t]+part[2][t]+part[3][t]+part[4][t]) * inv;
    CT[((size_t)bh*UU + u)*DHd + t] = acc;
  }
}

// ---------------- v mean over L per (b,h,dh) ----------------
__global__ void vmean_kernel(const float* __restrict__ V, float* __restrict__ VM){
  int i = blockIdx.x*256 + threadIdx.x;
  if (i >= Bb*NH*DHd) return;
  int c = i % DM;
  int b = i / DM;
  const float* vp = V + ((size_t)b*SEQ)*DM + c;
  float s = 0.f;
  for (int l=0;l<SEQ;l++) s += vp[(size_t)l*DM];
  VM[i] = s / (float)SEQ;
}

// ---------------- ctx = broadcast(vmean), then scatter ctx_top ----------------
__global__ void fill_ctx(const float* __restrict__ VM, float* __restrict__ CTX){
  int i = blockIdx.x*256 + threadIdx.x;
  if (i >= Bb*SEQ*DM) return;
  int c = i % DM; int b = i / (SEQ*DM);
  CTX[i] = VM[(size_t)b*DM + c];
}
__global__ void scatter_ctx(const float* __restrict__ CT, const int* __restrict__ TOP,
                            float* __restrict__ CTX){
  int i = blockIdx.x*256 + threadIdx.x;
  if (i >= Bb*NH*UU*DHd) return;
  int dh = i % DHd; int u = (i/DHd) % UU; int bh = i/(DHd*UU); int h = bh & 7; int b = bh >> 3;
  int l = TOP[bh*UU + u];
  CTX[((size_t)(b*SEQ + l))*DM + h*DHd + dh] = CT[i];
}

// ---------------- conv1a: (B,L,384)->(B,L,342), groups=3, k=3, SAME, gelu ----------------
__global__ __launch_bounds__(384) void conv1a_kernel(const float* __restrict__ Hin,
    const float* __restrict__ Wc, const float* __restrict__ bc, float* __restrict__ O){
  int blk = blockIdx.x; int b = blk / 25; int l0 = (blk % 25) * 10;
  __shared__ float hrow[12][DM];
  for (int i = threadIdx.x; i < 12*DM; i += 384){
    int r = i / DM, d = i % DM; int ll = l0 + r - 1;
    hrow[r][d] = (ll >= 0 && ll < SEQ) ? Hin[((size_t)b*SEQ + ll)*DM + d] : 0.f;
  }
  __syncthreads();
  int co = threadIdx.x;
  if (co < HID){
    int g = co / 114;
    const float* wp = Wc + (size_t)co * 128 * 3;
    float acc[10];
    float bbv = bc[co];
    #pragma unroll
    for (int i=0;i<10;i++) acc[i] = bbv;
    for (int ci=0; ci<128; ci++){
      float w0 = wp[ci*3+0], w1 = wp[ci*3+1], w2 = wp[ci*3+2];
      int d = g*128 + ci;
      #pragma unroll
      for (int i=0;i<10;i++)
        acc[i] += w0*hrow[i][d] + w1*hrow[i+1][d] + w2*hrow[i+2][d];
    }
    for (int i=0;i<10;i++)
      O[((size_t)b*SEQ + l0+i)*HID + co] = gelu_tanh(acc[i]);
  }
}

// ---------------- conv1b: (B,L,342)->(B,L,384), groups=3, k=3, SAME, += into X ----------------
__global__ __launch_bounds__(384) void conv1b_kernel(const float* __restrict__ G1,
    const float* __restrict__ Wc, const float* __restrict__ bc, float* __restrict__ X){
  int blk = blockIdx.x; int b = blk / 25; int l0 = (blk % 25) * 10;
  __shared__ float hrow[12][HID];
  for (int i = threadIdx.x; i < 12*HID; i += 384){
    int r = i / HID, d = i % HID; int ll = l0 + r - 1;
    hrow[r][d] = (ll >= 0 && ll < SEQ) ? G1[((size_t)b*SEQ + ll)*HID + d] : 0.f;
  }
  __syncthreads();
  int co = threadIdx.x;
  int g = co >> 7;
  const float* wp = Wc + (size_t)co * 114 * 3;
  float acc[10];
  float bbv = bc[co];
  #pragma unroll
  for (int i=0;i<10;i++) acc[i] = bbv;
  for (int ci=0; ci<114; ci++){
    float w0 = wp[ci*3+0], w1 = wp[ci*3+1], w2 = wp[ci*3+2];
    int d = g*114 + ci;
    #pragma unroll
    for (int i=0;i<10;i++)
      acc[i] += w0*hrow[i][d] + w1*hrow[i+1][d] + w2*hrow[i+2][d];
  }
  for (int i=0;i<10;i++)
    X[((size_t)b*SEQ + l0+i)*DM + co] += acc[i];
}

// ---------------- conv2 as implicit GEMM ----------------
// Per (b,g): C[125 lo x 384 d] = W[125 x 375] @ im2col(H)[375 x 384]
// K index k = li*3 + t ; im2col[k][d] = H[b, g*125+li, d+t-1] (0-padded)
// Output: X[b, g*125+lo, d] += gelu(C + bias[g*125+lo])
__global__ __launch_bounds__(256) void conv2_gemm(const float* __restrict__ Hin,
    const float* __restrict__ Wc, const float* __restrict__ bc, float* __restrict__ X){
  __shared__ float hs[8][132];    // input rows chunk, halo cols: c -> d = bn + c - 1
  __shared__ float ws[24][128];   // weights chunk: ws[kr][lo]
  int bn = blockIdx.x * 128;      // d-tile: 0,128,256
  int g  = blockIdx.y;            // group 0/1
  int b  = blockIdx.z;
  int tid = threadIdx.x;
  int tx = tid & 15, ty = tid >> 4;
  const size_t rowOff = ((size_t)b*SEQ + g*125);
  float acc[8][8];
  #pragma unroll
  for (int i=0;i<8;i++)
    #pragma unroll
    for (int j=0;j<8;j++) acc[i][j] = 0.f;

  for (int li0 = 0; li0 < 125; li0 += 8){
    __syncthreads();
    // stage input slab: 8 rows x 130 cols (halo +-1)
    for (int i = tid; i < 8*130; i += 256){
      int r = i / 130, c = i % 130;
      int d = bn + c - 1;
      float v = 0.f;
      if (d >= 0 && d < DM && (li0 + r) < 125)
        v = Hin[(rowOff + li0 + r)*DM + d];
      hs[r][c] = v;
    }
    // stage weight slab: 24 k x 128 lo
    for (int i = tid; i < 24*128; i += 256){
      int kr = i >> 7, lo = i & 127;
      int li = li0 + kr/3, t = kr - (kr/3)*3;
      float v = 0.f;
      if (lo < 125 && li < 125)
        v = Wc[(size_t)(g*125 + lo)*375 + li*3 + t];
      ws[kr][lo] = v;
    }
    __syncthreads();
    #pragma unroll
    for (int lr = 0; lr < 8; lr++){
      float hv[10];
      #pragma unroll
      for (int c = 0; c < 10; c++) hv[c] = hs[lr][tx*8 + c];
      #pragma unroll
      for (int t = 0; t < 3; t++){
        float a[8];
        #pragma unroll
        for (int i=0;i<8;i++) a[i] = ws[lr*3+t][ty*8+i];
        #pragma unroll
        for (int i=0;i<8;i++)
          #pragma unroll
          for (int j=0;j<8;j++) acc[i][j] = fmaf(a[i], hv[j+t], acc[i][j]);
      }
    }
  }
  // epilogue: bias + gelu + residual add
  #pragma unroll
  for (int i=0;i<8;i++){
    int lo = ty*8 + i;
    if (lo < 125){
      float bbv = bc[g*125 + lo];
      float* xp = X + (rowOff + lo)*DM + bn;
      #pragma unroll
      for (int j=0;j<8;j++){
        int d = tx*8 + j;
        xp[d] += gelu_tanh(acc[i][j] + bbv);
      }
    }
  }
}

// ---------------- final: max over L -> LN(ln2) -> FC ----------------
__global__ __launch_bounds__(384) void final_kernel(const float* __restrict__ Hin,
    const float* __restrict__ w, const float* __restrict__ bparm,
    const float* __restrict__ fcw, const float* __restrict__ fcb, float* __restrict__ out){
  __shared__ float red[8];
  __shared__ float ybuf[DM];
  int b = blockIdx.x; int d = threadIdx.x;
  const float* hp = Hin + (size_t)b*SEQ*DM + d;
  float mx = -FLT_MAX;
  for (int l=0;l<SEQ;l++) mx = fmaxf(mx, hp[(size_t)l*DM]);
  float mu = block_sum(mx, red) * (1.f/DM);
  float diff = mx - mu;
  float var = block_sum(diff*diff, red) * (1.f/DM);
  float y = diff * rsqrtf(var + 1e-5f) * w[d] + bparm[d];
  ybuf[d] = y;
  __syncthreads();
  if (d < 10){
    float acc = fcb[d];
    for (int k=0;k<DM;k++) acc += ybuf[k] * fcw[k*10 + d];
    out[b*10 + d] = acc;
  }
}

// ---------------- host orchestration ----------------
extern "C" void kernel_launch(void* const* d_in, const int* in_sizes, int n_in,
                              void* d_out, int out_size, void* d_ws, size_t ws_size,
                              hipStream_t stream) {
  const float* x     = (const float*)d_in[0];
  const float* pos   = (const float*)d_in[1];
  const float* lniw  = (const float*)d_in[2];
  const float* lnib  = (const float*)d_in[3];
  const float* lnAw  = (const float*)d_in[4];
  const float* lnAb  = (const float*)d_in[5];
  const float* Wq    = (const float*)d_in[6];
  const float* bq    = (const float*)d_in[7];
  const float* Wk    = (const float*)d_in[8];
  const float* bk    = (const float*)d_in[9];
  const float* Wv    = (const float*)d_in[10];
  const float* bv    = (const float*)d_in[11];
  const float* Wo    = (const float*)d_in[12];
  const float* bo    = (const float*)d_in[13];
  const float* lnBw  = (const float*)d_in[14];
  const float* lnBb  = (const float*)d_in[15];
  const float* c1aw  = (const float*)d_in[16];
  const float* c1ab  = (const float*)d_in[17];
  const float* c1bw  = (const float*)d_in[18];
  const float* c1bb  = (const float*)d_in[19];
  const float* lnCw  = (const float*)d_in[20];
  const float* lnCb  = (const float*)d_in[21];
  const float* c2w   = (const float*)d_in[22];
  const float* c2b   = (const float*)d_in[23];
  const float* ln2w  = (const float*)d_in[24];
  const float* ln2b  = (const float*)d_in[25];
  const float* fcw   = (const float*)d_in[26];
  const float* fcb   = (const float*)d_in[27];
  float* out = (float*)d_out;

  const size_t NTOK = (size_t)Bb*SEQ;          // 32000
  const size_t ACT  = NTOK*DM;                  // 12,288,000 floats
  float* Xb  = (float*)d_ws;
  float* Hb  = Xb  + ACT;
  float* Qb  = Hb  + ACT;
  float* Kb  = Qb  + ACT;
  float* Vb  = Kb  + ACT;
  float* CTX = Vb  + ACT;                       // also reused as conv1 mid (B,L,342)
  float* CT  = CTX + ACT;                       // 128*8*30*48 = 1,474,560
  float* Mb  = CT  + (size_t)Bb*NH*UU*DHd;      // 256,000
  float* VM  = Mb  + (size_t)Bb*NH*SEQ;         // 49,152
  int*   TOP = (int*)(VM + (size_t)Bb*DM);      // 30,720 ints
  int*   IDX = TOP + (size_t)Bb*NH*UU;          // 30,000 ints

  idx_kernel<<<dim3(118), dim3(256), 0, stream>>>(IDX);
  pool_ln_pos<<<dim3(32000), dim3(384), 0, stream>>>(x, pos, lniw, lnib, Xb);

  for (int l = 0; l < 4; l++){
    const size_t wofs = (size_t)l*DM*DM;
    ln384<<<dim3(32000), dim3(384), 0, stream>>>(Xb, Hb, lnAw + l*DM, lnAb + l*DM);
    gemm128<false,true><<<dim3(3,250), dim3(256), 0, stream>>>(Hb, Wq + wofs, bq + l*DM, Qb, 32000, DM, DM);
    gemm128<false,true><<<dim3(3,250), dim3(256), 0, stream>>>(Hb, Wk + wofs, bk + l*DM, Kb, 32000, DM, DM);
    gemm128<false,true><<<dim3(3,250), dim3(256), 0, stream>>>(Hb, Wv + wofs, bv + l*DM, Vb, 32000, DM, DM);
    probe_kernel<<<dim3(1000), dim3(256), 0, stream>>>(Qb, Kb, IDX + l*7500, Mb);
    topk_kernel<<<dim3(Bb*NH), dim3(64), 0, stream>>>(Mb, TOP);
    attn_ctx<<<dim3(Bb*NH*UU), dim3(256), 0, stream>>>(Qb, Kb, Vb, TOP, CT);
    vmean_kernel<<<dim3(192), dim3(256), 0, stream>>>(Vb, VM);
    fill_ctx<<<dim3(48000), dim3(256), 0, stream>>>(VM, CTX);
    scatter_ctx<<<dim3(5760), dim3(256), 0, stream>>>(CT, TOP, CTX);
    gemm128<true,true><<<dim3(3,250), dim3(256), 0, stream>>>(CTX, Wo + wofs, bo + l*DM, Xb, 32000, DM, DM);

    ln384<<<dim3(32000), dim3(384), 0, stream>>>(Xb, Hb, lnBw + l*DM, lnBb + l*DM);
    conv1a_kernel<<<dim3(Bb*25), dim3(384), 0, stream>>>(Hb, c1aw + (size_t)l*HID*128*3, c1ab + l*HID, CTX);
    conv1b_kernel<<<dim3(Bb*25), dim3(384), 0, stream>>>(CTX, c1bw + (size_t)l*DM*114*3, c1bb + l*DM, Xb);

    ln384<<<dim3(32000), dim3(384), 0, stream>>>(Xb, Hb, lnCw + l*DM, lnCb + l*DM);
    conv2_gemm<<<dim3(3,2,Bb), dim3(256), 0, stream>>>(Hb, c2w + (size_t)l*SEQ*125*3, c2b + l*SEQ, Xb);
  }

  ln384<<<dim3(32000), dim3(384), 0, stream>>>(Xb, Hb, ln2w, ln2b);
  final_kernel<<<dim3(Bb), dim3(384), 0, stream>>>(Hb, ln2w, ln2b, fcw, fcb, out);
}

// Round 3
// 6071.914 us; speedup vs baseline: 1.8361x; 1.4787x over previous
//
#include <hip/hip_runtime.h>
#include <hip/hip_bf16.h>
#include <cfloat>
#include <cstdint>

// ---------------- constants ----------------
static constexpr int Bb   = 128;
static constexpr int SEQ  = 250;
static constexpr int DM   = 384;
static constexpr int NH   = 8;
static constexpr int DHd  = 48;
static constexpr int HID  = 342;
static constexpr int UU   = 30;   // U == u == 30

using bf16 = __hip_bfloat16;
typedef __attribute__((ext_vector_type(8))) short bf16x8;
typedef __attribute__((ext_vector_type(4))) float f32x4;

// ---------------- threefry2x32 (JAX-exact) ----------------
__device__ __forceinline__ uint32_t rotl32(uint32_t x, int n){ return (x<<n)|(x>>(32-n)); }
#define TF_R(x0,x1,r) { x0 += x1; x1 = rotl32(x1,(r)); x1 ^= x0; }
__device__ inline void threefry(uint32_t k0, uint32_t k1, uint32_t x0, uint32_t x1,
                                uint32_t &o0, uint32_t &o1){
  uint32_t ks2 = k0 ^ k1 ^ 0x1BD11BDAu;
  x0 += k0; x1 += k1;
  TF_R(x0,x1,13) TF_R(x0,x1,15) TF_R(x0,x1,26) TF_R(x0,x1,6)
  x0 += k1; x1 += ks2 + 1u;
  TF_R(x0,x1,17) TF_R(x0,x1,29) TF_R(x0,x1,16) TF_R(x0,x1,24)
  x0 += ks2; x1 += k0 + 2u;
  TF_R(x0,x1,13) TF_R(x0,x1,15) TF_R(x0,x1,26) TF_R(x0,x1,6)
  x0 += k0; x1 += k1 + 3u;
  TF_R(x0,x1,17) TF_R(x0,x1,29) TF_R(x0,x1,16) TF_R(x0,x1,24)
  x0 += k1; x1 += ks2 + 4u;
  TF_R(x0,x1,13) TF_R(x0,x1,15) TF_R(x0,x1,26) TF_R(x0,x1,6)
  x0 += ks2; x1 += k0 + 5u;
  o0 = x0; o1 = x1;
}

__global__ void idx_kernel(int* __restrict__ IDX){
  int i = blockIdx.x*256 + threadIdx.x;
  if (i >= 4*7500) return;
  int l = i / 7500;
  int t = i % 7500;
  uint32_t fk0, fk1;
  threefry(0u, 42u, 0u, (uint32_t)l, fk0, fk1);
  uint32_t a0,a1,b0,b1;
  threefry(fk0, fk1, 0u, 2u, a0, a1);
  threefry(fk0, fk1, 1u, 3u, b0, b1);
  uint32_t c0 = (t < 3750) ? (uint32_t)t          : (uint32_t)(t-3750);
  uint32_t c1 = (t < 3750) ? (uint32_t)(t+3750)   : (uint32_t)t;
  uint32_t y0, y1, hi, lo;
  threefry(a0, b0, c0, c1, y0, y1); hi = (t < 3750) ? y0 : y1;
  threefry(a1, b1, c0, c1, y0, y1); lo = (t < 3750) ? y0 : y1;
  uint32_t val = ((hi % 250u) * 46u + (lo % 250u)) % 250u;
  IDX[i] = (int)val;
}

// ---------------- block reductions ----------------
__device__ __forceinline__ float block_sum(float v, float* red){
  v += __shfl_down(v,32); v += __shfl_down(v,16); v += __shfl_down(v,8);
  v += __shfl_down(v,4);  v += __shfl_down(v,2);  v += __shfl_down(v,1);
  int lane = threadIdx.x & 63, wid = threadIdx.x >> 6, nw = blockDim.x >> 6;
  __syncthreads();
  if (lane == 0) red[wid] = v;
  __syncthreads();
  float r = red[0];
  for (int i=1;i<nw;i++) r += red[i];
  return r;
}
__device__ __forceinline__ float block_max(float v, float* red){
  v = fmaxf(v, __shfl_down(v,32)); v = fmaxf(v, __shfl_down(v,16)); v = fmaxf(v, __shfl_down(v,8));
  v = fmaxf(v, __shfl_down(v,4));  v = fmaxf(v, __shfl_down(v,2));  v = fmaxf(v, __shfl_down(v,1));
  int lane = threadIdx.x & 63, wid = threadIdx.x >> 6, nw = blockDim.x >> 6;
  __syncthreads();
  if (lane == 0) red[wid] = v;
  __syncthreads();
  float r = red[0];
  for (int i=1;i<nw;i++) r = fmaxf(r, red[i]);
  return r;
}

__device__ __forceinline__ float gelu_tanh(float x){
  float t = 0.7978845608028654f * (x + 0.044715f * x * x * x);
  return 0.5f * x * (1.f + tanhf(t));
}

// ---------------- pool (max over 4) + LN + pos ----------------
__global__ __launch_bounds__(384) void pool_ln_pos(const float* __restrict__ xin,
    const float* __restrict__ pos, const float* __restrict__ w, const float* __restrict__ b,
    float* __restrict__ X){
  __shared__ float red[8];
  int bs = blockIdx.x; int bb = bs / SEQ, s = bs % SEQ; int d = threadIdx.x;
  const float* xp = xin + ((size_t)bb*1000 + (size_t)s*4)*DM + d;
  float v = fmaxf(fmaxf(xp[0], xp[DM]), fmaxf(xp[2*DM], xp[3*DM]));
  float mu = block_sum(v, red) * (1.f/DM);
  float diff = v - mu;
  float var = block_sum(diff*diff, red) * (1.f/DM);
  X[(size_t)bs*DM + d] = diff * rsqrtf(var + 1e-5f) * w[d] + b[d] + pos[(size_t)s*DM + d];
}

// ---------------- LayerNorm, optional f32/bf16 outputs ----------------
template<bool WF32, bool WB16>
__global__ __launch_bounds__(384) void ln384x(const float* __restrict__ in,
    float* __restrict__ o32, bf16* __restrict__ o16,
    const float* __restrict__ w, const float* __restrict__ b){
  __shared__ float red[8];
  size_t row = blockIdx.x; int d = threadIdx.x;
  float v = in[row*DM + d];
  float mu = block_sum(v, red) * (1.f/DM);
  float diff = v - mu;
  float var = block_sum(diff*diff, red) * (1.f/DM);
  float y = diff * rsqrtf(var + 1e-5f) * w[d] + b[d];
  if (WF32) o32[row*DM + d] = y;
  if (WB16) o16[row*DM + d] = __float2bfloat16(y);
}

// ---------------- f32 GEMM (Q/K only): C = A @ W + bias, BK=16, float4 LDS reads ----------------
__global__ __launch_bounds__(256) void gemm128(const float* __restrict__ A, const float* __restrict__ Bm,
    const float* __restrict__ bias, float* __restrict__ C, int M, int N, int K){
  __shared__ float As[16][128];
  __shared__ float Bs[16][128];
  int bm = blockIdx.y * 128, bn = blockIdx.x * 128;
  int tid = threadIdx.x;
  int tx = tid & 15, ty = tid >> 4;
  int arow = tid >> 1, acol = (tid & 1) * 8;
  int brow = tid >> 4, bcol = (tid & 15) * 8;
  const float* Aptr = A + (size_t)(bm + arow)*K + acol;
  const float* Bptr = Bm + (size_t)brow*N + bn + bcol;
  float acc[8][8];
  #pragma unroll
  for (int i=0;i<8;i++)
    #pragma unroll
    for (int j=0;j<8;j++) acc[i][j] = 0.f;
  for (int k0=0; k0<K; k0+=16){
    float4 av0 = *reinterpret_cast<const float4*>(Aptr + k0);
    float4 av1 = *reinterpret_cast<const float4*>(Aptr + k0 + 4);
    float4 bv0 = *reinterpret_cast<const float4*>(Bptr + (size_t)k0*N);
    float4 bv1 = *reinterpret_cast<const float4*>(Bptr + (size_t)k0*N + 4);
    __syncthreads();
    As[acol+0][arow]=av0.x; As[acol+1][arow]=av0.y; As[acol+2][arow]=av0.z; As[acol+3][arow]=av0.w;
    As[acol+4][arow]=av1.x; As[acol+5][arow]=av1.y; As[acol+6][arow]=av1.z; As[acol+7][arow]=av1.w;
    *reinterpret_cast<float4*>(&Bs[brow][bcol]) = bv0;
    *reinterpret_cast<float4*>(&Bs[brow][bcol+4]) = bv1;
    __syncthreads();
    #pragma unroll
    for (int kk=0; kk<16; kk++){
      float4 a0 = *reinterpret_cast<const float4*>(&As[kk][ty*8]);
      float4 a1 = *reinterpret_cast<const float4*>(&As[kk][ty*8+4]);
      float4 b0 = *reinterpret_cast<const float4*>(&Bs[kk][tx*8]);
      float4 b1 = *reinterpret_cast<const float4*>(&Bs[kk][tx*8+4]);
      float a[8] = {a0.x,a0.y,a0.z,a0.w,a1.x,a1.y,a1.z,a1.w};
      float bb[8] = {b0.x,b0.y,b0.z,b0.w,b1.x,b1.y,b1.z,b1.w};
      #pragma unroll
      for (int i=0;i<8;i++)
        #pragma unroll
        for (int j=0;j<8;j++) acc[i][j] = fmaf(a[i], bb[j], acc[i][j]);
    }
  }
  #pragma unroll
  for (int i=0;i<8;i++){
    int r = bm + ty*8 + i;
    #pragma unroll
    for (int j=0;j<8;j++){
      int c = bn + tx*8 + j;
      C[(size_t)r*N + c] = acc[i][j] + bias[c];
    }
  }
}

// ---------------- bf16 MFMA GEMM ----------------
// C[M=32000 x N=384] = sum_tap shift(A,tap-1)[M x 384] @ W_tap[384 x 384]
// WT layout: [TAPS][n=384][k=384] bf16 (k-contiguous). Tile 128x128, BK=64, 4 waves 2x2.
// EPI: 0 = store f32 + bias ; 1 = += f32 + bias ; 2 = bf16 store gelu(acc+bias)
__device__ __forceinline__ void gload16(const void* g, void* l){
  __builtin_amdgcn_global_load_lds(
      (__attribute__((address_space(1))) void*)(g),
      (__attribute__((address_space(3))) void*)(l), 16, 0, 0);
}

template<int TAPS, int EPI>
__global__ __launch_bounds__(256) void mfma_gemm(
    const bf16* __restrict__ A, const bf16* __restrict__ WT,
    const float* __restrict__ bias, float* __restrict__ Cf, bf16* __restrict__ Cb,
    const bf16* __restrict__ zpage)
{
  __shared__ bf16 As[128*64];
  __shared__ bf16 Bs[128*64];
  const int tid = threadIdx.x;
  const int wid = tid >> 6, lane = tid & 63;
  const int wr = wid >> 1, wc = wid & 1;
  const int bm = blockIdx.y * 128;
  const int bn = blockIdx.x * 128;
  const int srow = lane >> 3;          // 0..7
  const int scol = (lane & 7) * 8;     // bf16 elements

  f32x4 acc[4][4] = {};
  const int NCH = TAPS * 6;
  for (int ck = 0; ck < NCH; ck++){
    const int tap = (TAPS == 3) ? (ck / 6) : 0;
    const int kk0 = (TAPS == 3) ? ((ck % 6) * 64) : (ck * 64);
    __syncthreads();
    // A slab: wave wid stages rows [wid*32, wid*32+32)
    #pragma unroll
    for (int s = 0; s < 4; s++){
      int row = wid*32 + s*8 + srow;
      int token = bm + row;
      const bf16* src;
      if (TAPS == 3){
        int l = token - (token/SEQ)*SEQ;
        int ls = l + tap - 1;
        bool valid = (ls >= 0) && (ls < SEQ);
        src = valid ? (A + (size_t)(token + tap - 1)*DM + kk0 + scol) : zpage;
      } else {
        src = A + (size_t)token*DM + kk0 + scol;
      }
      gload16(src, &As[(wid*32 + s*8)*64]);
    }
    // B slab
    #pragma unroll
    for (int s = 0; s < 4; s++){
      int row = wid*32 + s*8 + srow;
      const bf16* src = WT + ((size_t)(tap*DM + bn + row))*DM + kk0 + scol;
      gload16(src, &Bs[(wid*32 + s*8)*64]);
    }
    __syncthreads();
    #pragma unroll
    for (int ks = 0; ks < 2; ks++){
      bf16x8 af[4], bg[4];
      #pragma unroll
      for (int m = 0; m < 4; m++)
        af[m] = *(const bf16x8*)&As[(wr*64 + m*16 + (lane & 15))*64 + ks*32 + (lane >> 4)*8];
      #pragma unroll
      for (int n = 0; n < 4; n++)
        bg[n] = *(const bf16x8*)&Bs[(wc*64 + n*16 + (lane & 15))*64 + ks*32 + (lane >> 4)*8];
      #pragma unroll
      for (int m = 0; m < 4; m++)
        #pragma unroll
        for (int n = 0; n < 4; n++)
          acc[m][n] = __builtin_amdgcn_mfma_f32_16x16x32_bf16(af[m], bg[n], acc[m][n], 0, 0, 0);
    }
  }
  const int c_l = lane & 15, r4 = (lane >> 4) * 4;
  #pragma unroll
  for (int m = 0; m < 4; m++){
    #pragma unroll
    for (int n = 0; n < 4; n++){
      #pragma unroll
      for (int r = 0; r < 4; r++){
        int token = bm + wr*64 + m*16 + r4 + r;
        int col   = bn + wc*64 + n*16 + c_l;
        float v = acc[m][n][r] + bias[col];
        if (EPI == 0)      Cf[(size_t)token*DM + col] = v;
        else if (EPI == 1) Cf[(size_t)token*DM + col] += v;
        else               Cb[(size_t)token*DM + col] = __float2bfloat16(gelu_tanh(v));
      }
    }
  }
}

// ---------------- weight prep ----------------
__global__ void zfill(bf16* z){ z[threadIdx.x] = __float2bfloat16(0.f); }

// proj: WT[n][k] = W[k][n], 8 matrices (4x Wv, 4x Wo)
__global__ __launch_bounds__(256) void build_projT(const float* __restrict__ Wv,
    const float* __restrict__ Wo, bf16* __restrict__ WvT, bf16* __restrict__ WoT){
  __shared__ float t[32][33];
  int mat = blockIdx.z;
  const float* W = (mat < 4) ? (Wv + (size_t)mat*DM*DM) : (Wo + (size_t)(mat-4)*DM*DM);
  bf16* WT = (mat < 4) ? (WvT + (size_t)mat*DM*DM) : (WoT + (size_t)(mat-4)*DM*DM);
  int k0 = blockIdx.y*32, n0 = blockIdx.x*32;
  int tx = threadIdx.x & 31, ty = threadIdx.x >> 5;
  #pragma unroll
  for (int r = 0; r < 32; r += 8)
    t[ty + r][tx] = W[(size_t)(k0 + ty + r)*DM + n0 + tx];
  __syncthreads();
  #pragma unroll
  for (int r = 0; r < 32; r += 8)
    WT[(size_t)(n0 + ty + r)*DM + k0 + tx] = __float2bfloat16(t[tx][ty + r]);
}

// conv1a dense transposed taps + padded bias
// WdaT[((l*3+t)*384+n)*384+k] = c1a_w[l][n][k-g*128][t] for n<342, k in group block, else 0
__global__ void build_c1aT(const float* __restrict__ W, const float* __restrict__ bin,
                           bf16* __restrict__ WT, float* __restrict__ bias_pad){
  int i = blockIdx.x*256 + threadIdx.x;
  if (i < 4*DM){
    int l = i/DM, n = i%DM;
    bias_pad[i] = (n < HID) ? bin[l*HID + n] : 0.f;
  }
  if (i >= 4*3*DM*DM) return;
  int k = i % DM; int n = (i/DM) % DM; int t = (i/(DM*DM)) % 3; int l = i/(3*DM*DM);
  float v = 0.f;
  if (n < HID){
    int g = n / 114; int ci = k - g*128;
    if (ci >= 0 && ci < 128)
      v = W[(((size_t)l*HID + n)*128 + ci)*3 + t];
  }
  WT[i] = __float2bfloat16(v);
}

// conv1b: WdbT[((l*3+t)*384+n)*384+k] = c1b_w[l][n][k-g*114][t], g = n>>7
__global__ void build_c1bT(const float* __restrict__ W, bf16* __restrict__ WT){
  int i = blockIdx.x*256 + threadIdx.x;
  if (i >= 4*3*DM*DM) return;
  int k = i % DM; int n = (i/DM) % DM; int t = (i/(DM*DM)) % 3; int l = i/(3*DM*DM);
  int g = n >> 7; int ci = k - g*114;
  float v = 0.f;
  if (ci >= 0 && ci < 114)
    v = W[(((size_t)l*DM + n)*114 + ci)*3 + t];
  WT[i] = __float2bfloat16(v);
}

// ---------------- probe / topk / attn (f32, unchanged) ----------------
__global__ void probe_kernel(const float* __restrict__ Q, const float* __restrict__ Kb,
                             const int* __restrict__ idx, float* __restrict__ M){
  int i = blockIdx.x*256 + threadIdx.x;
  if (i >= Bb*NH*SEQ) return;
  int l = i % SEQ; int h = (i/SEQ) % NH; int b = i / (NH*SEQ);
  const float* q = Q + ((size_t)(b*SEQ + l))*DM + h*DHd;
  float qr[DHd];
  #pragma unroll
  for (int z=0; z<DHd; z++) qr[z] = q[z];
  const int* ip = idx + l*UU;
  float mx = -FLT_MAX, sm = 0.f;
  for (int u=0; u<UU; u++){
    int j = ip[u];
    const float* kp = Kb + ((size_t)(b*SEQ + j))*DM + h*DHd;
    float d = 0.f;
    #pragma unroll
    for (int z=0; z<DHd; z++) d += qr[z]*kp[z];
    mx = fmaxf(mx, d); sm += d;
  }
  M[i] = mx - sm/(float)UU;
}

__global__ __launch_bounds__(64) void topk_kernel(const float* __restrict__ M, int* __restrict__ TOP){
  int bh = blockIdx.x; int lane = threadIdx.x;
  float vals[4]; int ids[4];
  #pragma unroll
  for (int r=0;r<4;r++){
    int l = r*64 + lane;
    if (l < SEQ){ vals[r] = M[(size_t)bh*SEQ + l]; ids[r] = l; }
    else        { vals[r] = -FLT_MAX; ids[r] = 1<<30; }
  }
  for (int sel=0; sel<UU; sel++){
    float bv = -FLT_MAX; int bi = 1<<30;
    #pragma unroll
    for (int r=0;r<4;r++)
      if (vals[r] > bv || (vals[r] == bv && ids[r] < bi)){ bv = vals[r]; bi = ids[r]; }
    for (int off=32; off; off>>=1){
      float ov = __shfl_xor(bv, off);
      int   oi = __shfl_xor(bi, off);
      if (ov > bv || (ov == bv && oi < bi)){ bv = ov; bi = oi; }
    }
    if (lane == 0) TOP[(size_t)bh*UU + sel] = bi;
    #pragma unroll
    for (int r=0;r<4;r++) if (ids[r] == bi) vals[r] = -FLT_MAX;
  }
}

__global__ __launch_bounds__(256) void attn_ctx(const float* __restrict__ Q, const float* __restrict__ K,
    const float* __restrict__ V, const int* __restrict__ TOP, float* __restrict__ CT){
  __shared__ float red[8];
  __shared__ float qred[DHd];
  __shared__ float p[SEQ];
  __shared__ float part[5][DHd];
  int bhu = blockIdx.x;
  int u = bhu % UU; int bh = bhu / UU; int h = bh & 7; int b = bh >> 3;
  int t = threadIdx.x;
  int l0 = TOP[bh*UU + u];
  if (t < DHd) qred[t] = Q[((size_t)(b*SEQ + l0))*DM + h*DHd + t];
  __syncthreads();
  float s = -FLT_MAX;
  if (t < SEQ){
    const float* kp = K + ((size_t)(b*SEQ + t))*DM + h*DHd;
    float dacc = 0.f;
    #pragma unroll
    for (int z=0; z<DHd; z++) dacc += qred[z]*kp[z];
    s = dacc / 6.92820323027550917f;
  }
  float mxv = block_max(s, red);
  float e = (t < SEQ) ? expf(s - mxv) : 0.f;
  if (t < SEQ) p[t] = e;
  float sum = block_sum(e, red);
  float inv = 1.f / sum;
  if (t < 240){
    int dh = t % DHd, pr = t / DHd;
    const float* vp = V + ((size_t)b*SEQ)*DM + h*DHd + dh;
    float acc = 0.f;
    int j0 = pr*50;
    for (int j=j0; j<j0+50; j++) acc += p[j] * vp[(size_t)j*DM];
    part[pr][dh] = acc;
  }
  __syncthreads();
  if (t < DHd){
    float acc = (part[0][t]+part[1][t]+part[2][t]+part[3][t]+part[4][t]) * inv;
    CT[((size_t)bh*UU + u)*DHd + t] = acc;
  }
}

__global__ void vmean_kernel(const float* __restrict__ V, float* __restrict__ VM){
  int i = blockIdx.x*256 + threadIdx.x;
  if (i >= Bb*NH*DHd) return;
  int c = i % DM;
  int b = i / DM;
  const float* vp = V + ((size_t)b*SEQ)*DM + c;
  float s = 0.f;
  for (int l=0;l<SEQ;l++) s += vp[(size_t)l*DM];
  VM[i] = s / (float)SEQ;
}

__global__ void fill_ctx16(const float* __restrict__ VM, bf16* __restrict__ CTX){
  int i = blockIdx.x*256 + threadIdx.x;
  if (i >= Bb*SEQ*DM) return;
  int c = i % DM; int b = i / (SEQ*DM);
  CTX[i] = __float2bfloat16(VM[(size_t)b*DM + c]);
}
__global__ void scatter_ctx16(const float* __restrict__ CT, const int* __restrict__ TOP,
                              bf16* __restrict__ CTX){
  int i = blockIdx.x*256 + threadIdx.x;
  if (i >= Bb*NH*UU*DHd) return;
  int dh = i % DHd; int u = (i/DHd) % UU; int bh = i/(DHd*UU); int h = bh & 7; int b = bh >> 3;
  int l = TOP[bh*UU + u];
  CTX[((size_t)(b*SEQ + l))*DM + h*DHd + dh] = __float2bfloat16(CT[i]);
}

// ---------------- conv2 as implicit GEMM (unchanged) ----------------
__global__ __launch_bounds__(256) void conv2_gemm(const float* __restrict__ Hin,
    const float* __restrict__ Wc, const float* __restrict__ bc, float* __restrict__ X){
  __shared__ float hs[8][132];
  __shared__ float ws[24][128];
  int bn = blockIdx.x * 128;
  int g  = blockIdx.y;
  int b  = blockIdx.z;
  int tid = threadIdx.x;
  int tx = tid & 15, ty = tid >> 4;
  const size_t rowOff = ((size_t)b*SEQ + g*125);
  float acc[8][8];
  #pragma unroll
  for (int i=0;i<8;i++)
    #pragma unroll
    for (int j=0;j<8;j++) acc[i][j] = 0.f;

  for (int li0 = 0; li0 < 125; li0 += 8){
    __syncthreads();
    for (int i = tid; i < 8*130; i += 256){
      int r = i / 130, c = i % 130;
      int d = bn + c - 1;
      float v = 0.f;
      if (d >= 0 && d < DM && (li0 + r) < 125)
        v = Hin[(rowOff + li0 + r)*DM + d];
      hs[r][c] = v;
    }
    for (int i = tid; i < 24*128; i += 256){
      int kr = i >> 7, lo = i & 127;
      int li = li0 + kr/3, t = kr - (kr/3)*3;
      float v = 0.f;
      if (lo < 125 && li < 125)
        v = Wc[(size_t)(g*125 + lo)*375 + li*3 + t];
      ws[kr][lo] = v;
    }
    __syncthreads();
    #pragma unroll
    for (int lr = 0; lr < 8; lr++){
      float hv[10];
      #pragma unroll
      for (int c = 0; c < 10; c++) hv[c] = hs[lr][tx*8 + c];
      #pragma unroll
      for (int t = 0; t < 3; t++){
        float a[8];
        #pragma unroll
        for (int i=0;i<8;i++) a[i] = ws[lr*3+t][ty*8+i];
        #pragma unroll
        for (int i=0;i<8;i++)
          #pragma unroll
          for (int j=0;j<8;j++) acc[i][j] = fmaf(a[i], hv[j+t], acc[i][j]);
      }
    }
  }
  #pragma unroll
  for (int i=0;i<8;i++){
    int lo = ty*8 + i;
    if (lo < 125){
      float bbv = bc[g*125 + lo];
      float* xp = X + (rowOff + lo)*DM + bn;
      #pragma unroll
      for (int j=0;j<8;j++){
        int d = tx*8 + j;
        xp[d] += gelu_tanh(acc[i][j] + bbv);
      }
    }
  }
}

// ---------------- final: max over L -> LN(ln2) -> FC ----------------
__global__ __launch_bounds__(384) void final_kernel(const float* __restrict__ Hin,
    const float* __restrict__ w, const float* __restrict__ bparm,
    const float* __restrict__ fcw, const float* __restrict__ fcb, float* __restrict__ out){
  __shared__ float red[8];
  __shared__ float ybuf[DM];
  int b = blockIdx.x; int d = threadIdx.x;
  const float* hp = Hin + (size_t)b*SEQ*DM + d;
  float mx = -FLT_MAX;
  for (int l=0;l<SEQ;l++) mx = fmaxf(mx, hp[(size_t)l*DM]);
  float mu = block_sum(mx, red) * (1.f/DM);
  float diff = mx - mu;
  float var = block_sum(diff*diff, red) * (1.f/DM);
  float y = diff * rsqrtf(var + 1e-5f) * w[d] + bparm[d];
  ybuf[d] = y;
  __syncthreads();
  if (d < 10){
    float acc = fcb[d];
    for (int k=0;k<DM;k++) acc += ybuf[k] * fcw[k*10 + d];
    out[b*10 + d] = acc;
  }
}

// ---------------- host orchestration ----------------
extern "C" void kernel_launch(void* const* d_in, const int* in_sizes, int n_in,
                              void* d_out, int out_size, void* d_ws, size_t ws_size,
                              hipStream_t stream) {
  const float* x     = (const float*)d_in[0];
  const float* pos   = (const float*)d_in[1];
  const float* lniw  = (const float*)d_in[2];
  const float* lnib  = (const float*)d_in[3];
  const float* lnAw  = (const float*)d_in[4];
  const float* lnAb  = (const float*)d_in[5];
  const float* Wq    = (const float*)d_in[6];
  const float* bq    = (const float*)d_in[7];
  const float* Wk    = (const float*)d_in[8];
  const float* bk    = (const float*)d_in[9];
  const float* Wv    = (const float*)d_in[10];
  const float* bv    = (const float*)d_in[11];
  const float* Wo    = (const float*)d_in[12];
  const float* bo    = (const float*)d_in[13];
  const float* lnBw  = (const float*)d_in[14];
  const float* lnBb  = (const float*)d_in[15];
  const float* c1aw  = (const float*)d_in[16];
  const float* c1ab  = (const float*)d_in[17];
  const float* c1bw  = (const float*)d_in[18];
  const float* c1bb  = (const float*)d_in[19];
  const float* lnCw  = (const float*)d_in[20];
  const float* lnCb  = (const float*)d_in[21];
  const float* c2w   = (const float*)d_in[22];
  const float* c2b   = (const float*)d_in[23];
  const float* ln2w  = (const float*)d_in[24];
  const float* ln2b  = (const float*)d_in[25];
  const float* fcw   = (const float*)d_in[26];
  const float* fcb   = (const float*)d_in[27];
  float* out = (float*)d_out;

  const size_t ACT  = (size_t)Bb*SEQ*DM;        // 12,288,000
  float* Xb  = (float*)d_ws;
  float* Hb  = Xb  + ACT;
  float* Qb  = Hb  + ACT;
  float* Kb  = Qb  + ACT;
  float* Vb  = Kb  + ACT;
  float* CT  = Vb  + ACT;                       // 1,474,560
  float* Mb  = CT  + (size_t)Bb*NH*UU*DHd;      // 256,000
  float* VM  = Mb  + (size_t)Bb*NH*SEQ;         // 49,152
  float* biasA = VM + (size_t)Bb*DM;            // 4*384
  int*   TOP = (int*)(biasA + 4*DM);            // 30,720
  int*   IDX = TOP + (size_t)Bb*NH*UU;          // 30,000
  bf16*  Hb16 = (bf16*)(IDX + 4*7500);          // ACT bf16 (also CTX16)
  bf16*  G1   = Hb16 + ACT;                     // ACT bf16
  bf16*  WvT  = G1   + ACT;                     // 4*384*384
  bf16*  WoT  = WvT  + (size_t)4*DM*DM;
  bf16*  WaT  = WoT  + (size_t)4*DM*DM;         // 4*3*384*384
  bf16*  WbT  = WaT  + (size_t)12*DM*DM;
  bf16*  zp   = WbT  + (size_t)12*DM*DM;        // 256 zeros

  // prep
  zfill<<<dim3(1), dim3(256), 0, stream>>>(zp);
  idx_kernel<<<dim3(118), dim3(256), 0, stream>>>(IDX);
  build_projT<<<dim3(12,12,8), dim3(256), 0, stream>>>(Wv, Wo, WvT, WoT);
  build_c1aT<<<dim3(6912), dim3(256), 0, stream>>>(c1aw, c1ab, WaT, biasA);
  build_c1bT<<<dim3(6912), dim3(256), 0, stream>>>(c1bw, WbT);
  pool_ln_pos<<<dim3(32000), dim3(384), 0, stream>>>(x, pos, lniw, lnib, Xb);

  for (int l = 0; l < 4; l++){
    const size_t wofs = (size_t)l*DM*DM;
    bf16* CTX16 = Hb16;  // reuse (Hb16 dead after V-proj)
    ln384x<true,true><<<dim3(32000), dim3(384), 0, stream>>>(Xb, Hb, Hb16, lnAw + l*DM, lnAb + l*DM);
    gemm128<<<dim3(3,250), dim3(256), 0, stream>>>(Hb, Wq + wofs, bq + l*DM, Qb, 32000, DM, DM);
    gemm128<<<dim3(3,250), dim3(256), 0, stream>>>(Hb, Wk + wofs, bk + l*DM, Kb, 32000, DM, DM);
    mfma_gemm<1,0><<<dim3(3,250), dim3(256), 0, stream>>>(Hb16, WvT + wofs, bv + l*DM, Vb, (bf16*)nullptr, zp);
    probe_kernel<<<dim3(1000), dim3(256), 0, stream>>>(Qb, Kb, IDX + l*7500, Mb);
    topk_kernel<<<dim3(Bb*NH), dim3(64), 0, stream>>>(Mb, TOP);
    attn_ctx<<<dim3(Bb*NH*UU), dim3(256), 0, stream>>>(Qb, Kb, Vb, TOP, CT);
    vmean_kernel<<<dim3(192), dim3(256), 0, stream>>>(Vb, VM);
    fill_ctx16<<<dim3(48000), dim3(256), 0, stream>>>(VM, CTX16);
    scatter_ctx16<<<dim3(5760), dim3(256), 0, stream>>>(CT, TOP, CTX16);
    mfma_gemm<1,1><<<dim3(3,250), dim3(256), 0, stream>>>(CTX16, WoT + wofs, bo + l*DM, Xb, (bf16*)nullptr, zp);

    ln384x<false,true><<<dim3(32000), dim3(384), 0, stream>>>(Xb, (float*)nullptr, Hb16, lnBw + l*DM, lnBb + l*DM);
    mfma_gemm<3,2><<<dim3(3,250), dim3(256), 0, stream>>>(Hb16, WaT + (size_t)l*3*DM*DM, biasA + l*DM, (float*)nullptr, G1, zp);
    mfma_gemm<3,1><<<dim3(3,250), dim3(256), 0, stream>>>(G1, WbT + (size_t)l*3*DM*DM, c1bb + l*DM, Xb, (bf16*)nullptr, zp);

    ln384x<true,false><<<dim3(32000), dim3(384), 0, stream>>>(Xb, Hb, (bf16*)nullptr, lnCw + l*DM, lnCb + l*DM);
    conv2_gemm<<<dim3(3,2,Bb), dim3(256), 0, stream>>>(Hb, c2w + (size_t)l*SEQ*125*3, c2b + l*SEQ, Xb);
  }

  ln384x<true,false><<<dim3(32000), dim3(384), 0, stream>>>(Xb, Hb, (bf16*)nullptr, ln2w, ln2b);
  final_kernel<<<dim3(Bb), dim3(384), 0, stream>>>(Hb, ln2w, ln2b, fcw, fcb, out);
}

// Round 4
// 4786.180 us; speedup vs baseline: 2.3293x; 1.2686x over previous
//
#include <hip/hip_runtime.h>
#include <hip/hip_bf16.h>
#include <cfloat>
#include <cstdint>

// ---------------- constants ----------------
static constexpr int Bb   = 128;
static constexpr int SEQ  = 250;
static constexpr int DM   = 384;
static constexpr int NH   = 8;
static constexpr int DHd  = 48;
static constexpr int HID  = 342;
static constexpr int UU   = 30;   // U == u == 30

using bf16 = __hip_bfloat16;
typedef __attribute__((ext_vector_type(8))) short bf16x8;
typedef __attribute__((ext_vector_type(4))) float f32x4;

// ---------------- threefry2x32 (JAX-exact) ----------------
__device__ __forceinline__ uint32_t rotl32(uint32_t x, int n){ return (x<<n)|(x>>(32-n)); }
#define TF_R(x0,x1,r) { x0 += x1; x1 = rotl32(x1,(r)); x1 ^= x0; }
__device__ inline void threefry(uint32_t k0, uint32_t k1, uint32_t x0, uint32_t x1,
                                uint32_t &o0, uint32_t &o1){
  uint32_t ks2 = k0 ^ k1 ^ 0x1BD11BDAu;
  x0 += k0; x1 += k1;
  TF_R(x0,x1,13) TF_R(x0,x1,15) TF_R(x0,x1,26) TF_R(x0,x1,6)
  x0 += k1; x1 += ks2 + 1u;
  TF_R(x0,x1,17) TF_R(x0,x1,29) TF_R(x0,x1,16) TF_R(x0,x1,24)
  x0 += ks2; x1 += k0 + 2u;
  TF_R(x0,x1,13) TF_R(x0,x1,15) TF_R(x0,x1,26) TF_R(x0,x1,6)
  x0 += k0; x1 += k1 + 3u;
  TF_R(x0,x1,17) TF_R(x0,x1,29) TF_R(x0,x1,16) TF_R(x0,x1,24)
  x0 += k1; x1 += ks2 + 4u;
  TF_R(x0,x1,13) TF_R(x0,x1,15) TF_R(x0,x1,26) TF_R(x0,x1,6)
  x0 += ks2; x1 += k0 + 5u;
  o0 = x0; o1 = x1;
}

__global__ void idx_kernel(int* __restrict__ IDX){
  int i = blockIdx.x*256 + threadIdx.x;
  if (i >= 4*7500) return;
  int l = i / 7500;
  int t = i % 7500;
  uint32_t fk0, fk1;
  threefry(0u, 42u, 0u, (uint32_t)l, fk0, fk1);
  uint32_t a0,a1,b0,b1;
  threefry(fk0, fk1, 0u, 2u, a0, a1);
  threefry(fk0, fk1, 1u, 3u, b0, b1);
  uint32_t c0 = (t < 3750) ? (uint32_t)t          : (uint32_t)(t-3750);
  uint32_t c1 = (t < 3750) ? (uint32_t)(t+3750)   : (uint32_t)t;
  uint32_t y0, y1, hi, lo;
  threefry(a0, b0, c0, c1, y0, y1); hi = (t < 3750) ? y0 : y1;
  threefry(a1, b1, c0, c1, y0, y1); lo = (t < 3750) ? y0 : y1;
  uint32_t val = ((hi % 250u) * 46u + (lo % 250u)) % 250u;
  IDX[i] = (int)val;
}

// ---------------- block reductions ----------------
__device__ __forceinline__ float block_sum(float v, float* red){
  v += __shfl_down(v,32); v += __shfl_down(v,16); v += __shfl_down(v,8);
  v += __shfl_down(v,4);  v += __shfl_down(v,2);  v += __shfl_down(v,1);
  int lane = threadIdx.x & 63, wid = threadIdx.x >> 6, nw = blockDim.x >> 6;
  __syncthreads();
  if (lane == 0) red[wid] = v;
  __syncthreads();
  float r = red[0];
  for (int i=1;i<nw;i++) r += red[i];
  return r;
}
__device__ __forceinline__ float block_max(float v, float* red){
  v = fmaxf(v, __shfl_down(v,32)); v = fmaxf(v, __shfl_down(v,16)); v = fmaxf(v, __shfl_down(v,8));
  v = fmaxf(v, __shfl_down(v,4));  v = fmaxf(v, __shfl_down(v,2));  v = fmaxf(v, __shfl_down(v,1));
  int lane = threadIdx.x & 63, wid = threadIdx.x >> 6, nw = blockDim.x >> 6;
  __syncthreads();
  if (lane == 0) red[wid] = v;
  __syncthreads();
  float r = red[0];
  for (int i=1;i<nw;i++) r = fmaxf(r, red[i]);
  return r;
}

__device__ __forceinline__ float gelu_tanh(float x){
  float t = 0.7978845608028654f * (x + 0.044715f * x * x * x);
  return 0.5f * x * (1.f + tanhf(t));
}

// ---------------- pool (max over 4) + LN + pos ----------------
__global__ __launch_bounds__(384) void pool_ln_pos(const float* __restrict__ xin,
    const float* __restrict__ pos, const float* __restrict__ w, const float* __restrict__ b,
    float* __restrict__ X){
  __shared__ float red[8];
  int bs = blockIdx.x; int bb = bs / SEQ, s = bs % SEQ; int d = threadIdx.x;
  const float* xp = xin + ((size_t)bb*1000 + (size_t)s*4)*DM + d;
  float v = fmaxf(fmaxf(xp[0], xp[DM]), fmaxf(xp[2*DM], xp[3*DM]));
  float mu = block_sum(v, red) * (1.f/DM);
  float diff = v - mu;
  float var = block_sum(diff*diff, red) * (1.f/DM);
  X[(size_t)bs*DM + d] = diff * rsqrtf(var + 1e-5f) * w[d] + b[d] + pos[(size_t)s*DM + d];
}

// ---------------- LayerNorm, optional f32/bf16 outputs ----------------
template<bool WF32, bool WB16>
__global__ __launch_bounds__(384) void ln384x(const float* __restrict__ in,
    float* __restrict__ o32, bf16* __restrict__ o16,
    const float* __restrict__ w, const float* __restrict__ b){
  __shared__ float red[8];
  size_t row = blockIdx.x; int d = threadIdx.x;
  float v = in[row*DM + d];
  float mu = block_sum(v, red) * (1.f/DM);
  float diff = v - mu;
  float var = block_sum(diff*diff, red) * (1.f/DM);
  float y = diff * rsqrtf(var + 1e-5f) * w[d] + b[d];
  if (WF32) o32[row*DM + d] = y;
  if (WB16) o16[row*DM + d] = __float2bfloat16(y);
}

// LayerNorm writing split hi/lo bf16 (for f32-accurate MFMA GEMM)
__global__ __launch_bounds__(384) void ln384hl(const float* __restrict__ in,
    bf16* __restrict__ ohi, bf16* __restrict__ olo,
    const float* __restrict__ w, const float* __restrict__ b){
  __shared__ float red[8];
  size_t row = blockIdx.x; int d = threadIdx.x;
  float v = in[row*DM + d];
  float mu = block_sum(v, red) * (1.f/DM);
  float diff = v - mu;
  float var = block_sum(diff*diff, red) * (1.f/DM);
  float y = diff * rsqrtf(var + 1e-5f) * w[d] + b[d];
  bf16 h = __float2bfloat16(y);
  ohi[row*DM + d] = h;
  olo[row*DM + d] = __float2bfloat16(y - __bfloat162float(h));
}

// ---------------- bf16 MFMA GEMM ----------------
__device__ __forceinline__ void gload16(const void* g, void* l){
  __builtin_amdgcn_global_load_lds(
      (__attribute__((address_space(1))) void*)(g),
      (__attribute__((address_space(3))) void*)(l), 16, 0, 0);
}

// C[M x 384] = sum_tap shift(A,tap-1) @ W_tap ; EPI: 0=store f32+bias 1=+= f32+bias 2=bf16 gelu store
template<int TAPS, int EPI>
__global__ __launch_bounds__(256) void mfma_gemm(
    const bf16* __restrict__ A, const bf16* __restrict__ WT,
    const float* __restrict__ bias, float* __restrict__ Cf, bf16* __restrict__ Cb,
    const bf16* __restrict__ zpage)
{
  __shared__ bf16 As[128*64];
  __shared__ bf16 Bs[128*64];
  const int tid = threadIdx.x;
  const int wid = tid >> 6, lane = tid & 63;
  const int wr = wid >> 1, wc = wid & 1;
  const int bm = blockIdx.y * 128;
  const int bn = blockIdx.x * 128;
  const int srow = lane >> 3;
  const int scol = (lane & 7) * 8;

  f32x4 acc[4][4] = {};
  const int NCH = TAPS * 6;
  for (int ck = 0; ck < NCH; ck++){
    const int tap = (TAPS == 3) ? (ck / 6) : 0;
    const int kk0 = (TAPS == 3) ? ((ck % 6) * 64) : (ck * 64);
    __syncthreads();
    #pragma unroll
    for (int s = 0; s < 4; s++){
      int row = wid*32 + s*8 + srow;
      int token = bm + row;
      const bf16* src;
      if (TAPS == 3){
        int l = token - (token/SEQ)*SEQ;
        int ls = l + tap - 1;
        bool valid = (ls >= 0) && (ls < SEQ);
        src = valid ? (A + (size_t)(token + tap - 1)*DM + kk0 + scol) : zpage;
      } else {
        src = A + (size_t)token*DM + kk0 + scol;
      }
      gload16(src, &As[(wid*32 + s*8)*64]);
    }
    #pragma unroll
    for (int s = 0; s < 4; s++){
      int row = wid*32 + s*8 + srow;
      const bf16* src = WT + ((size_t)(tap*DM + bn + row))*DM + kk0 + scol;
      gload16(src, &Bs[(wid*32 + s*8)*64]);
    }
    __syncthreads();
    #pragma unroll
    for (int ks = 0; ks < 2; ks++){
      bf16x8 af[4], bg[4];
      #pragma unroll
      for (int m = 0; m < 4; m++)
        af[m] = *(const bf16x8*)&As[(wr*64 + m*16 + (lane & 15))*64 + ks*32 + (lane >> 4)*8];
      #pragma unroll
      for (int n = 0; n < 4; n++)
        bg[n] = *(const bf16x8*)&Bs[(wc*64 + n*16 + (lane & 15))*64 + ks*32 + (lane >> 4)*8];
      #pragma unroll
      for (int m = 0; m < 4; m++)
        #pragma unroll
        for (int n = 0; n < 4; n++)
          acc[m][n] = __builtin_amdgcn_mfma_f32_16x16x32_bf16(af[m], bg[n], acc[m][n], 0, 0, 0);
    }
  }
  const int c_l = lane & 15, r4 = (lane >> 4) * 4;
  #pragma unroll
  for (int m = 0; m < 4; m++){
    #pragma unroll
    for (int n = 0; n < 4; n++){
      #pragma unroll
      for (int r = 0; r < 4; r++){
        int token = bm + wr*64 + m*16 + r4 + r;
        int col   = bn + wc*64 + n*16 + c_l;
        float v = acc[m][n][r] + bias[col];
        if (EPI == 0)      Cf[(size_t)token*DM + col] = v;
        else if (EPI == 1) Cf[(size_t)token*DM + col] += v;
        else               Cb[(size_t)token*DM + col] = __float2bfloat16(gelu_tanh(v));
      }
    }
  }
}

// split-bf16 f32-accurate GEMM: C = Ahi@Whi + Ahi@Wlo + Alo@Whi + bias (f32 out)
// WT layout: [2][384][384] (hi then lo), n-major k-contiguous
__global__ __launch_bounds__(256) void mfma_qk(
    const bf16* __restrict__ Ahi, const bf16* __restrict__ Alo,
    const bf16* __restrict__ WT, const float* __restrict__ bias, float* __restrict__ C)
{
  __shared__ bf16 As[128*64];
  __shared__ bf16 Bs[128*64];
  const int tid = threadIdx.x;
  const int wid = tid >> 6, lane = tid & 63;
  const int wr = wid >> 1, wc = wid & 1;
  const int bm = blockIdx.y * 128;
  const int bn = blockIdx.x * 128;
  const int srow = lane >> 3;
  const int scol = (lane & 7) * 8;

  f32x4 acc[4][4] = {};
  for (int ck = 0; ck < 18; ck++){
    const int p   = ck / 6;              // pass: 0=hi*hi 1=hi*lo 2=lo*hi
    const int kk0 = (ck % 6) * 64;
    const bf16* Asrc = (p < 2) ? Ahi : Alo;
    const bf16* Wsrc = WT + ((p == 1) ? (size_t)DM*DM : 0);
    __syncthreads();
    #pragma unroll
    for (int s = 0; s < 4; s++){
      int row = wid*32 + s*8 + srow;
      gload16(Asrc + (size_t)(bm + row)*DM + kk0 + scol, &As[(wid*32 + s*8)*64]);
    }
    #pragma unroll
    for (int s = 0; s < 4; s++){
      int row = wid*32 + s*8 + srow;
      gload16(Wsrc + (size_t)(bn + row)*DM + kk0 + scol, &Bs[(wid*32 + s*8)*64]);
    }
    __syncthreads();
    #pragma unroll
    for (int ks = 0; ks < 2; ks++){
      bf16x8 af[4], bg[4];
      #pragma unroll
      for (int m = 0; m < 4; m++)
        af[m] = *(const bf16x8*)&As[(wr*64 + m*16 + (lane & 15))*64 + ks*32 + (lane >> 4)*8];
      #pragma unroll
      for (int n = 0; n < 4; n++)
        bg[n] = *(const bf16x8*)&Bs[(wc*64 + n*16 + (lane & 15))*64 + ks*32 + (lane >> 4)*8];
      #pragma unroll
      for (int m = 0; m < 4; m++)
        #pragma unroll
        for (int n = 0; n < 4; n++)
          acc[m][n] = __builtin_amdgcn_mfma_f32_16x16x32_bf16(af[m], bg[n], acc[m][n], 0, 0, 0);
    }
  }
  const int c_l = lane & 15, r4 = (lane >> 4) * 4;
  #pragma unroll
  for (int m = 0; m < 4; m++)
    #pragma unroll
    for (int n = 0; n < 4; n++)
      #pragma unroll
      for (int r = 0; r < 4; r++){
        int token = bm + wr*64 + m*16 + r4 + r;
        int col   = bn + wc*64 + n*16 + c_l;
        C[(size_t)token*DM + col] = acc[m][n][r] + bias[col];
      }
}

// ---------------- weight prep ----------------
__global__ void zfill(bf16* z){ z[threadIdx.x] = __float2bfloat16(0.f); }

__global__ __launch_bounds__(256) void build_projT(const float* __restrict__ Wv,
    const float* __restrict__ Wo, bf16* __restrict__ WvT, bf16* __restrict__ WoT){
  __shared__ float t[32][33];
  int mat = blockIdx.z;
  const float* W = (mat < 4) ? (Wv + (size_t)mat*DM*DM) : (Wo + (size_t)(mat-4)*DM*DM);
  bf16* WT = (mat < 4) ? (WvT + (size_t)mat*DM*DM) : (WoT + (size_t)(mat-4)*DM*DM);
  int k0 = blockIdx.y*32, n0 = blockIdx.x*32;
  int tx = threadIdx.x & 31, ty = threadIdx.x >> 5;
  #pragma unroll
  for (int r = 0; r < 32; r += 8)
    t[ty + r][tx] = W[(size_t)(k0 + ty + r)*DM + n0 + tx];
  __syncthreads();
  #pragma unroll
  for (int r = 0; r < 32; r += 8)
    WT[(size_t)(n0 + ty + r)*DM + k0 + tx] = __float2bfloat16(t[tx][ty + r]);
}

// Wq/Wk transposed split hi/lo: WT[mat][2][n][k]
__global__ __launch_bounds__(256) void build_qkhl(const float* __restrict__ Wq,
    const float* __restrict__ Wk, bf16* __restrict__ WT){
  __shared__ float t[32][33];
  int mat = blockIdx.z;
  const float* W = (mat < 4) ? (Wq + (size_t)mat*DM*DM) : (Wk + (size_t)(mat-4)*DM*DM);
  bf16* hi = WT + (size_t)mat*2*DM*DM;
  bf16* lo = hi + (size_t)DM*DM;
  int k0 = blockIdx.y*32, n0 = blockIdx.x*32;
  int tx = threadIdx.x & 31, ty = threadIdx.x >> 5;
  #pragma unroll
  for (int r = 0; r < 32; r += 8)
    t[ty + r][tx] = W[(size_t)(k0 + ty + r)*DM + n0 + tx];
  __syncthreads();
  #pragma unroll
  for (int r = 0; r < 32; r += 8){
    float w = t[tx][ty + r];
    bf16 h = __float2bfloat16(w);
    hi[(size_t)(n0 + ty + r)*DM + k0 + tx] = h;
    lo[(size_t)(n0 + ty + r)*DM + k0 + tx] = __float2bfloat16(w - __bfloat162float(h));
  }
}

__global__ void build_c1aT(const float* __restrict__ W, const float* __restrict__ bin,
                           bf16* __restrict__ WT, float* __restrict__ bias_pad){
  int i = blockIdx.x*256 + threadIdx.x;
  if (i < 4*DM){
    int l = i/DM, n = i%DM;
    bias_pad[i] = (n < HID) ? bin[l*HID + n] : 0.f;
  }
  if (i >= 4*3*DM*DM) return;
  int k = i % DM; int n = (i/DM) % DM; int t = (i/(DM*DM)) % 3; int l = i/(3*DM*DM);
  float v = 0.f;
  if (n < HID){
    int g = n / 114; int ci = k - g*128;
    if (ci >= 0 && ci < 128)
      v = W[(((size_t)l*HID + n)*128 + ci)*3 + t];
  }
  WT[i] = __float2bfloat16(v);
}

__global__ void build_c1bT(const float* __restrict__ W, bf16* __restrict__ WT){
  int i = blockIdx.x*256 + threadIdx.x;
  if (i >= 4*3*DM*DM) return;
  int k = i % DM; int n = (i/DM) % DM; int t = (i/(DM*DM)) % 3; int l = i/(3*DM*DM);
  int g = n >> 7; int ci = k - g*114;
  float v = 0.f;
  if (ci >= 0 && ci < 114)
    v = W[(((size_t)l*DM + n)*114 + ci)*3 + t];
  WT[i] = __float2bfloat16(v);
}

// ---------------- fused probe + top-k: one block per (b,h) ----------------
// K tile staged in LDS (pad 49 -> odd stride, random-row gathers spread banks).
// Each thread owns query row l: M[l] = max_u(qk) - mean_u(qk); then 30-iter block argmax.
__global__ __launch_bounds__(256) void probe_topk(const float* __restrict__ Q,
    const float* __restrict__ K, const int* __restrict__ idx, int* __restrict__ TOP){
  __shared__ float Ksh[SEQ*49];
  __shared__ float s_redv[4];
  __shared__ int   s_redi[4];
  __shared__ int   s_win;
  int bh = blockIdx.x; int h = bh & 7; int b = bh >> 3;
  int tid = threadIdx.x;
  for (int i = tid; i < SEQ*DHd; i += 256){
    int r = i / DHd, c = i - r*DHd;
    Ksh[r*49 + c] = K[((size_t)(b*SEQ + r))*DM + h*DHd + c];
  }
  __syncthreads();
  int l = tid;
  float Mv = -FLT_MAX;
  if (l < SEQ){
    float qr[DHd];
    const float* qp = Q + ((size_t)(b*SEQ + l))*DM + h*DHd;
    #pragma unroll
    for (int z = 0; z < DHd; z++) qr[z] = qp[z];
    const int* ip = idx + l*UU;
    float mx = -FLT_MAX, sm = 0.f;
    for (int u = 0; u < UU; u++){
      int base = ip[u]*49;
      float d = 0.f;
      #pragma unroll
      for (int z = 0; z < DHd; z++) d += qr[z]*Ksh[base + z];
      mx = fmaxf(mx, d); sm += d;
    }
    Mv = mx - sm*(1.f/UU);
  }
  int myid = (l < SEQ) ? l : (1<<30);
  int lane = tid & 63, wid = tid >> 6;
  for (int sel = 0; sel < UU; sel++){
    float bv = Mv; int bi = myid;
    #pragma unroll
    for (int off = 32; off; off >>= 1){
      float ov = __shfl_xor(bv, off);
      int   oi = __shfl_xor(bi, off);
      if (ov > bv || (ov == bv && oi < bi)){ bv = ov; bi = oi; }
    }
    if (lane == 0){ s_redv[wid] = bv; s_redi[wid] = bi; }
    __syncthreads();
    if (tid == 0){
      float wv = s_redv[0]; int wi = s_redi[0];
      #pragma unroll
      for (int q = 1; q < 4; q++)
        if (s_redv[q] > wv || (s_redv[q] == wv && s_redi[q] < wi)){ wv = s_redv[q]; wi = s_redi[q]; }
      TOP[(size_t)bh*UU + sel] = wi;
      s_win = wi;
    }
    __syncthreads();
    if (myid == s_win) Mv = -FLT_MAX;
  }
}

// ---------------- fused scores+softmax+PV for one (b,h,u) ----------------
__global__ __launch_bounds__(256) void attn_ctx(const float* __restrict__ Q, const float* __restrict__ K,
    const float* __restrict__ V, const int* __restrict__ TOP, float* __restrict__ CT){
  __shared__ float red[8];
  __shared__ float qred[DHd];
  __shared__ float p[SEQ];
  __shared__ float part[5][DHd];
  int bhu = blockIdx.x;
  int u = bhu % UU; int bh = bhu / UU; int h = bh & 7; int b = bh >> 3;
  int t = threadIdx.x;
  int l0 = TOP[bh*UU + u];
  if (t < DHd) qred[t] = Q[((size_t)(b*SEQ + l0))*DM + h*DHd + t];
  __syncthreads();
  float s = -FLT_MAX;
  if (t < SEQ){
    const float* kp = K + ((size_t)(b*SEQ + t))*DM + h*DHd;
    float dacc = 0.f;
    #pragma unroll
    for (int z=0; z<DHd; z++) dacc += qred[z]*kp[z];
    s = dacc / 6.92820323027550917f;
  }
  float mxv = block_max(s, red);
  float e = (t < SEQ) ? expf(s - mxv) : 0.f;
  if (t < SEQ) p[t] = e;
  float sum = block_sum(e, red);
  float inv = 1.f / sum;
  if (t < 240){
    int dh = t % DHd, pr = t / DHd;
    const float* vp = V + ((size_t)b*SEQ)*DM + h*DHd + dh;
    float acc = 0.f;
    int j0 = pr*50;
    for (int j=j0; j<j0+50; j++) acc += p[j] * vp[(size_t)j*DM];
    part[pr][dh] = acc;
  }
  __syncthreads();
  if (t < DHd){
    float acc = (part[0][t]+part[1][t]+part[2][t]+part[3][t]+part[4][t]) * inv;
    CT[((size_t)bh*UU + u)*DHd + t] = acc;
  }
}

__global__ void vmean_kernel(const float* __restrict__ V, float* __restrict__ VM){
  int i = blockIdx.x*256 + threadIdx.x;
  if (i >= Bb*NH*DHd) return;
  int c = i % DM;
  int b = i / DM;
  const float* vp = V + ((size_t)b*SEQ)*DM + c;
  float s = 0.f;
  for (int l=0;l<SEQ;l++) s += vp[(size_t)l*DM];
  VM[i] = s / (float)SEQ;
}

__global__ void fill_ctx16(const float* __restrict__ VM, bf16* __restrict__ CTX){
  int i = blockIdx.x*256 + threadIdx.x;
  if (i >= Bb*SEQ*DM) return;
  int c = i % DM; int b = i / (SEQ*DM);
  CTX[i] = __float2bfloat16(VM[(size_t)b*DM + c]);
}
__global__ void scatter_ctx16(const float* __restrict__ CT, const int* __restrict__ TOP,
                              bf16* __restrict__ CTX){
  int i = blockIdx.x*256 + threadIdx.x;
  if (i >= Bb*NH*UU*DHd) return;
  int dh = i % DHd; int u = (i/DHd) % UU; int bh = i/(DHd*UU); int h = bh & 7; int b = bh >> 3;
  int l = TOP[bh*UU + u];
  CTX[((size_t)(b*SEQ + l))*DM + h*DHd + dh] = __float2bfloat16(CT[i]);
}

// ---------------- conv2 as implicit GEMM ----------------
__global__ __launch_bounds__(256) void conv2_gemm(const float* __restrict__ Hin,
    const float* __restrict__ Wc, const float* __restrict__ bc, float* __restrict__ X){
  __shared__ float hs[8][132];
  __shared__ float ws[24][128];
  int bn = blockIdx.x * 128;
  int g  = blockIdx.y;
  int b  = blockIdx.z;
  int tid = threadIdx.x;
  int tx = tid & 15, ty = tid >> 4;
  const size_t rowOff = ((size_t)b*SEQ + g*125);
  float acc[8][8];
  #pragma unroll
  for (int i=0;i<8;i++)
    #pragma unroll
    for (int j=0;j<8;j++) acc[i][j] = 0.f;

  for (int li0 = 0; li0 < 125; li0 += 8){
    __syncthreads();
    for (int i = tid; i < 8*130; i += 256){
      int r = i / 130, c = i % 130;
      int d = bn + c - 1;
      float v = 0.f;
      if (d >= 0 && d < DM && (li0 + r) < 125)
        v = Hin[(rowOff + li0 + r)*DM + d];
      hs[r][c] = v;
    }
    for (int i = tid; i < 24*128; i += 256){
      int kr = i >> 7, lo = i & 127;
      int li = li0 + kr/3, t = kr - (kr/3)*3;
      float v = 0.f;
      if (lo < 125 && li < 125)
        v = Wc[(size_t)(g*125 + lo)*375 + li*3 + t];
      ws[kr][lo] = v;
    }
    __syncthreads();
    #pragma unroll
    for (int lr = 0; lr < 8; lr++){
      float hv[10];
      #pragma unroll
      for (int c = 0; c < 10; c++) hv[c] = hs[lr][tx*8 + c];
      #pragma unroll
      for (int t = 0; t < 3; t++){
        float a[8];
        #pragma unroll
        for (int i=0;i<8;i++) a[i] = ws[lr*3+t][ty*8+i];
        #pragma unroll
        for (int i=0;i<8;i++)
          #pragma unroll
          for (int j=0;j<8;j++) acc[i][j] = fmaf(a[i], hv[j+t], acc[i][j]);
      }
    }
  }
  #pragma unroll
  for (int i=0;i<8;i++){
    int lo = ty*8 + i;
    if (lo < 125){
      float bbv = bc[g*125 + lo];
      float* xp = X + (rowOff + lo)*DM + bn;
      #pragma unroll
      for (int j=0;j<8;j++){
        int d = tx*8 + j;
        xp[d] += gelu_tanh(acc[i][j] + bbv);
      }
    }
  }
}

// ---------------- final: max over L -> LN(ln2) -> FC ----------------
__global__ __launch_bounds__(384) void final_kernel(const float* __restrict__ Hin,
    const float* __restrict__ w, const float* __restrict__ bparm,
    const float* __restrict__ fcw, const float* __restrict__ fcb, float* __restrict__ out){
  __shared__ float red[8];
  __shared__ float ybuf[DM];
  int b = blockIdx.x; int d = threadIdx.x;
  const float* hp = Hin + (size_t)b*SEQ*DM + d;
  float mx = -FLT_MAX;
  for (int l=0;l<SEQ;l++) mx = fmaxf(mx, hp[(size_t)l*DM]);
  float mu = block_sum(mx, red) * (1.f/DM);
  float diff = mx - mu;
  float var = block_sum(diff*diff, red) * (1.f/DM);
  float y = diff * rsqrtf(var + 1e-5f) * w[d] + bparm[d];
  ybuf[d] = y;
  __syncthreads();
  if (d < 10){
    float acc = fcb[d];
    for (int k=0;k<DM;k++) acc += ybuf[k] * fcw[k*10 + d];
    out[b*10 + d] = acc;
  }
}

// ---------------- host orchestration ----------------
extern "C" void kernel_launch(void* const* d_in, const int* in_sizes, int n_in,
                              void* d_out, int out_size, void* d_ws, size_t ws_size,
                              hipStream_t stream) {
  const float* x     = (const float*)d_in[0];
  const float* pos   = (const float*)d_in[1];
  const float* lniw  = (const float*)d_in[2];
  const float* lnib  = (const float*)d_in[3];
  const float* lnAw  = (const float*)d_in[4];
  const float* lnAb  = (const float*)d_in[5];
  const float* Wq    = (const float*)d_in[6];
  const float* bq    = (const float*)d_in[7];
  const float* Wk    = (const float*)d_in[8];
  const float* bk    = (const float*)d_in[9];
  const float* Wv    = (const float*)d_in[10];
  const float* bv    = (const float*)d_in[11];
  const float* Wo    = (const float*)d_in[12];
  const float* bo    = (const float*)d_in[13];
  const float* lnBw  = (const float*)d_in[14];
  const float* lnBb  = (const float*)d_in[15];
  const float* c1aw  = (const float*)d_in[16];
  const float* c1ab  = (const float*)d_in[17];
  const float* c1bw  = (const float*)d_in[18];
  const float* c1bb  = (const float*)d_in[19];
  const float* lnCw  = (const float*)d_in[20];
  const float* lnCb  = (const float*)d_in[21];
  const float* c2w   = (const float*)d_in[22];
  const float* c2b   = (const float*)d_in[23];
  const float* ln2w  = (const float*)d_in[24];
  const float* ln2b  = (const float*)d_in[25];
  const float* fcw   = (const float*)d_in[26];
  const float* fcb   = (const float*)d_in[27];
  float* out = (float*)d_out;

  const size_t ACT  = (size_t)Bb*SEQ*DM;        // 12,288,000
  float* Xb  = (float*)d_ws;
  float* Hb  = Xb  + ACT;                       // f32 for LN-C/final; aliased as Alo bf16 early
  float* Qb  = Hb  + ACT;
  float* Kb  = Qb  + ACT;
  float* Vb  = Kb  + ACT;
  float* CT  = Vb  + ACT;
  float* VM  = CT  + (size_t)Bb*NH*UU*DHd;
  float* biasA = VM + (size_t)Bb*DM;
  int*   TOP = (int*)(biasA + 4*DM);
  int*   IDX = TOP + (size_t)Bb*NH*UU;
  bf16*  Hb16 = (bf16*)(IDX + 4*7500);          // Ahi / CTX16 / conv input
  bf16*  G1   = Hb16 + ACT;
  bf16*  WvT  = G1   + ACT;
  bf16*  WoT  = WvT  + (size_t)4*DM*DM;
  bf16*  WaT  = WoT  + (size_t)4*DM*DM;
  bf16*  WbT  = WaT  + (size_t)12*DM*DM;
  bf16*  WqkT = WbT  + (size_t)12*DM*DM;        // [8][2][384][384]
  bf16*  zp   = WqkT + (size_t)16*DM*DM;

  zfill<<<dim3(1), dim3(256), 0, stream>>>(zp);
  idx_kernel<<<dim3(118), dim3(256), 0, stream>>>(IDX);
  build_projT<<<dim3(12,12,8), dim3(256), 0, stream>>>(Wv, Wo, WvT, WoT);
  build_qkhl<<<dim3(12,12,8), dim3(256), 0, stream>>>(Wq, Wk, WqkT);
  build_c1aT<<<dim3(6912), dim3(256), 0, stream>>>(c1aw, c1ab, WaT, biasA);
  build_c1bT<<<dim3(6912), dim3(256), 0, stream>>>(c1bw, WbT);
  pool_ln_pos<<<dim3(32000), dim3(384), 0, stream>>>(x, pos, lniw, lnib, Xb);

  for (int l = 0; l < 4; l++){
    const size_t wofs = (size_t)l*DM*DM;
    bf16* Alo16 = (bf16*)Hb;          // alias: Hb f32 unused until LN-C
    bf16* CTX16 = Hb16;               // reuse after V-proj
    ln384hl<<<dim3(32000), dim3(384), 0, stream>>>(Xb, Hb16, Alo16, lnAw + l*DM, lnAb + l*DM);
    mfma_qk<<<dim3(3,250), dim3(256), 0, stream>>>(Hb16, Alo16, WqkT + (size_t)l*2*DM*DM, bq + l*DM, Qb);
    mfma_qk<<<dim3(3,250), dim3(256), 0, stream>>>(Hb16, Alo16, WqkT + (size_t)(4+l)*2*DM*DM, bk + l*DM, Kb);
    mfma_gemm<1,0><<<dim3(3,250), dim3(256), 0, stream>>>(Hb16, WvT + wofs, bv + l*DM, Vb, (bf16*)nullptr, zp);
    probe_topk<<<dim3(Bb*NH), dim3(256), 0, stream>>>(Qb, Kb, IDX + l*7500, TOP);
    attn_ctx<<<dim3(Bb*NH*UU), dim3(256), 0, stream>>>(Qb, Kb, Vb, TOP, CT);
    vmean_kernel<<<dim3(192), dim3(256), 0, stream>>>(Vb, VM);
    fill_ctx16<<<dim3(48000), dim3(256), 0, stream>>>(VM, CTX16);
    scatter_ctx16<<<dim3(5760), dim3(256), 0, stream>>>(CT, TOP, CTX16);
    mfma_gemm<1,1><<<dim3(3,250), dim3(256), 0, stream>>>(CTX16, WoT + wofs, bo + l*DM, Xb, (bf16*)nullptr, zp);

    ln384x<false,true><<<dim3(32000), dim3(384), 0, stream>>>(Xb, (float*)nullptr, Hb16, lnBw + l*DM, lnBb + l*DM);
    mfma_gemm<3,2><<<dim3(3,250), dim3(256), 0, stream>>>(Hb16, WaT + (size_t)l*3*DM*DM, biasA + l*DM, (float*)nullptr, G1, zp);
    mfma_gemm<3,1><<<dim3(3,250), dim3(256), 0, stream>>>(G1, WbT + (size_t)l*3*DM*DM, c1bb + l*DM, Xb, (bf16*)nullptr, zp);

    ln384x<true,false><<<dim3(32000), dim3(384), 0, stream>>>(Xb, Hb, (bf16*)nullptr, lnCw + l*DM, lnCb + l*DM);
    conv2_gemm<<<dim3(3,2,Bb), dim3(256), 0, stream>>>(Hb, c2w + (size_t)l*SEQ*125*3, c2b + l*SEQ, Xb);
  }

  ln384x<true,false><<<dim3(32000), dim3(384), 0, stream>>>(Xb, Hb, (bf16*)nullptr, ln2w, ln2b);
  final_kernel<<<dim3(Bb), dim3(384), 0, stream>>>(Hb, ln2w, ln2b, fcw, fcb, out);
}

// Round 5
// 4719.492 us; speedup vs baseline: 2.3622x; 1.0141x over previous
//
#include <hip/hip_runtime.h>
#include <hip/hip_bf16.h>
#include <cfloat>
#include <cstdint>

// ---------------- constants ----------------
static constexpr int Bb   = 128;
static constexpr int SEQ  = 250;
static constexpr int DM   = 384;
static constexpr int NH   = 8;
static constexpr int DHd  = 48;
static constexpr int HID  = 342;
static constexpr int UU   = 30;   // U == u == 30

using bf16 = __hip_bfloat16;
typedef __attribute__((ext_vector_type(8))) short bf16x8;
typedef __attribute__((ext_vector_type(4))) float f32x4;

// ---------------- threefry2x32 (JAX-exact) ----------------
__device__ __forceinline__ uint32_t rotl32(uint32_t x, int n){ return (x<<n)|(x>>(32-n)); }
#define TF_R(x0,x1,r) { x0 += x1; x1 = rotl32(x1,(r)); x1 ^= x0; }
__device__ inline void threefry(uint32_t k0, uint32_t k1, uint32_t x0, uint32_t x1,
                                uint32_t &o0, uint32_t &o1){
  uint32_t ks2 = k0 ^ k1 ^ 0x1BD11BDAu;
  x0 += k0; x1 += k1;
  TF_R(x0,x1,13) TF_R(x0,x1,15) TF_R(x0,x1,26) TF_R(x0,x1,6)
  x0 += k1; x1 += ks2 + 1u;
  TF_R(x0,x1,17) TF_R(x0,x1,29) TF_R(x0,x1,16) TF_R(x0,x1,24)
  x0 += ks2; x1 += k0 + 2u;
  TF_R(x0,x1,13) TF_R(x0,x1,15) TF_R(x0,x1,26) TF_R(x0,x1,6)
  x0 += k0; x1 += k1 + 3u;
  TF_R(x0,x1,17) TF_R(x0,x1,29) TF_R(x0,x1,16) TF_R(x0,x1,24)
  x0 += k1; x1 += ks2 + 4u;
  TF_R(x0,x1,13) TF_R(x0,x1,15) TF_R(x0,x1,26) TF_R(x0,x1,6)
  x0 += ks2; x1 += k0 + 5u;
  o0 = x0; o1 = x1;
}

__global__ void idx_kernel(int* __restrict__ IDX){
  int i = blockIdx.x*256 + threadIdx.x;
  if (i >= 4*7500) return;
  int l = i / 7500;
  int t = i % 7500;
  uint32_t fk0, fk1;
  threefry(0u, 42u, 0u, (uint32_t)l, fk0, fk1);
  uint32_t a0,a1,b0,b1;
  threefry(fk0, fk1, 0u, 2u, a0, a1);
  threefry(fk0, fk1, 1u, 3u, b0, b1);
  uint32_t c0 = (t < 3750) ? (uint32_t)t          : (uint32_t)(t-3750);
  uint32_t c1 = (t < 3750) ? (uint32_t)(t+3750)   : (uint32_t)t;
  uint32_t y0, y1, hi, lo;
  threefry(a0, b0, c0, c1, y0, y1); hi = (t < 3750) ? y0 : y1;
  threefry(a1, b1, c0, c1, y0, y1); lo = (t < 3750) ? y0 : y1;
  uint32_t val = ((hi % 250u) * 46u + (lo % 250u)) % 250u;
  IDX[i] = (int)val;
}

// ---------------- block reductions ----------------
__device__ __forceinline__ float block_sum(float v, float* red){
  v += __shfl_down(v,32); v += __shfl_down(v,16); v += __shfl_down(v,8);
  v += __shfl_down(v,4);  v += __shfl_down(v,2);  v += __shfl_down(v,1);
  int lane = threadIdx.x & 63, wid = threadIdx.x >> 6, nw = blockDim.x >> 6;
  __syncthreads();
  if (lane == 0) red[wid] = v;
  __syncthreads();
  float r = red[0];
  for (int i=1;i<nw;i++) r += red[i];
  return r;
}
__device__ __forceinline__ float block_max(float v, float* red){
  v = fmaxf(v, __shfl_down(v,32)); v = fmaxf(v, __shfl_down(v,16)); v = fmaxf(v, __shfl_down(v,8));
  v = fmaxf(v, __shfl_down(v,4));  v = fmaxf(v, __shfl_down(v,2));  v = fmaxf(v, __shfl_down(v,1));
  int lane = threadIdx.x & 63, wid = threadIdx.x >> 6, nw = blockDim.x >> 6;
  __syncthreads();
  if (lane == 0) red[wid] = v;
  __syncthreads();
  float r = red[0];
  for (int i=1;i<nw;i++) r = fmaxf(r, red[i]);
  return r;
}

__device__ __forceinline__ float gelu_tanh(float x){
  float t = 0.7978845608028654f * (x + 0.044715f * x * x * x);
  return 0.5f * x * (1.f + tanhf(t));
}

// ---------------- pool (max over 4) + LN + pos ----------------
__global__ __launch_bounds__(384) void pool_ln_pos(const float* __restrict__ xin,
    const float* __restrict__ pos, const float* __restrict__ w, const float* __restrict__ b,
    float* __restrict__ X){
  __shared__ float red[8];
  int bs = blockIdx.x; int bb = bs / SEQ, s = bs % SEQ; int d = threadIdx.x;
  const float* xp = xin + ((size_t)bb*1000 + (size_t)s*4)*DM + d;
  float v = fmaxf(fmaxf(xp[0], xp[DM]), fmaxf(xp[2*DM], xp[3*DM]));
  float mu = block_sum(v, red) * (1.f/DM);
  float diff = v - mu;
  float var = block_sum(diff*diff, red) * (1.f/DM);
  X[(size_t)bs*DM + d] = diff * rsqrtf(var + 1e-5f) * w[d] + b[d] + pos[(size_t)s*DM + d];
}

// ---------------- LayerNorm, optional f32/bf16 outputs ----------------
template<bool WF32, bool WB16>
__global__ __launch_bounds__(384) void ln384x(const float* __restrict__ in,
    float* __restrict__ o32, bf16* __restrict__ o16,
    const float* __restrict__ w, const float* __restrict__ b){
  __shared__ float red[8];
  size_t row = blockIdx.x; int d = threadIdx.x;
  float v = in[row*DM + d];
  float mu = block_sum(v, red) * (1.f/DM);
  float diff = v - mu;
  float var = block_sum(diff*diff, red) * (1.f/DM);
  float y = diff * rsqrtf(var + 1e-5f) * w[d] + b[d];
  if (WF32) o32[row*DM + d] = y;
  if (WB16) o16[row*DM + d] = __float2bfloat16(y);
}

// LayerNorm writing split hi/lo bf16 (for f32-accurate MFMA GEMM)
__global__ __launch_bounds__(384) void ln384hl(const float* __restrict__ in,
    bf16* __restrict__ ohi, bf16* __restrict__ olo,
    const float* __restrict__ w, const float* __restrict__ b){
  __shared__ float red[8];
  size_t row = blockIdx.x; int d = threadIdx.x;
  float v = in[row*DM + d];
  float mu = block_sum(v, red) * (1.f/DM);
  float diff = v - mu;
  float var = block_sum(diff*diff, red) * (1.f/DM);
  float y = diff * rsqrtf(var + 1e-5f) * w[d] + b[d];
  bf16 h = __float2bfloat16(y);
  ohi[row*DM + d] = h;
  olo[row*DM + d] = __float2bfloat16(y - __bfloat162float(h));
}

// ---------------- bf16 MFMA GEMM ----------------
__device__ __forceinline__ void gload16(const void* g, void* l){
  __builtin_amdgcn_global_load_lds(
      (__attribute__((address_space(1))) void*)(g),
      (__attribute__((address_space(3))) void*)(l), 16, 0, 0);
}

// C[M x 384] = sum_tap shift(A,tap-1) @ W_tap ; EPI: 0=store f32+bias 1=+= f32+bias 2=bf16 gelu store
template<int TAPS, int EPI>
__global__ __launch_bounds__(256) void mfma_gemm(
    const bf16* __restrict__ A, const bf16* __restrict__ WT,
    const float* __restrict__ bias, float* __restrict__ Cf, bf16* __restrict__ Cb,
    const bf16* __restrict__ zpage)
{
  __shared__ bf16 As[128*64];
  __shared__ bf16 Bs[128*64];
  const int tid = threadIdx.x;
  const int wid = tid >> 6, lane = tid & 63;
  const int wr = wid >> 1, wc = wid & 1;
  const int bm = blockIdx.y * 128;
  const int bn = blockIdx.x * 128;
  const int srow = lane >> 3;
  const int scol = (lane & 7) * 8;

  f32x4 acc[4][4] = {};
  const int NCH = TAPS * 6;
  for (int ck = 0; ck < NCH; ck++){
    const int tap = (TAPS == 3) ? (ck / 6) : 0;
    const int kk0 = (TAPS == 3) ? ((ck % 6) * 64) : (ck * 64);
    __syncthreads();
    #pragma unroll
    for (int s = 0; s < 4; s++){
      int row = wid*32 + s*8 + srow;
      int token = bm + row;
      const bf16* src;
      if (TAPS == 3){
        int l = token - (token/SEQ)*SEQ;
        int ls = l + tap - 1;
        bool valid = (ls >= 0) && (ls < SEQ);
        src = valid ? (A + (size_t)(token + tap - 1)*DM + kk0 + scol) : zpage;
      } else {
        src = A + (size_t)token*DM + kk0 + scol;
      }
      gload16(src, &As[(wid*32 + s*8)*64]);
    }
    #pragma unroll
    for (int s = 0; s < 4; s++){
      int row = wid*32 + s*8 + srow;
      const bf16* src = WT + ((size_t)(tap*DM + bn + row))*DM + kk0 + scol;
      gload16(src, &Bs[(wid*32 + s*8)*64]);
    }
    __syncthreads();
    #pragma unroll
    for (int ks = 0; ks < 2; ks++){
      bf16x8 af[4], bg[4];
      #pragma unroll
      for (int m = 0; m < 4; m++)
        af[m] = *(const bf16x8*)&As[(wr*64 + m*16 + (lane & 15))*64 + ks*32 + (lane >> 4)*8];
      #pragma unroll
      for (int n = 0; n < 4; n++)
        bg[n] = *(const bf16x8*)&Bs[(wc*64 + n*16 + (lane & 15))*64 + ks*32 + (lane >> 4)*8];
      #pragma unroll
      for (int m = 0; m < 4; m++)
        #pragma unroll
        for (int n = 0; n < 4; n++)
          acc[m][n] = __builtin_amdgcn_mfma_f32_16x16x32_bf16(af[m], bg[n], acc[m][n], 0, 0, 0);
    }
  }
  const int c_l = lane & 15, r4 = (lane >> 4) * 4;
  #pragma unroll
  for (int m = 0; m < 4; m++){
    #pragma unroll
    for (int n = 0; n < 4; n++){
      #pragma unroll
      for (int r = 0; r < 4; r++){
        int token = bm + wr*64 + m*16 + r4 + r;
        int col   = bn + wc*64 + n*16 + c_l;
        float v = acc[m][n][r] + bias[col];
        if (EPI == 0)      Cf[(size_t)token*DM + col] = v;
        else if (EPI == 1) Cf[(size_t)token*DM + col] += v;
        else               Cb[(size_t)token*DM + col] = __float2bfloat16(gelu_tanh(v));
      }
    }
  }
}

// split-bf16 f32-accurate GEMM: C = Ahi@Whi + Ahi@Wlo + Alo@Whi + bias (f32 out)
__global__ __launch_bounds__(256) void mfma_qk(
    const bf16* __restrict__ Ahi, const bf16* __restrict__ Alo,
    const bf16* __restrict__ WT, const float* __restrict__ bias, float* __restrict__ C)
{
  __shared__ bf16 As[128*64];
  __shared__ bf16 Bs[128*64];
  const int tid = threadIdx.x;
  const int wid = tid >> 6, lane = tid & 63;
  const int wr = wid >> 1, wc = wid & 1;
  const int bm = blockIdx.y * 128;
  const int bn = blockIdx.x * 128;
  const int srow = lane >> 3;
  const int scol = (lane & 7) * 8;

  f32x4 acc[4][4] = {};
  for (int ck = 0; ck < 18; ck++){
    const int p   = ck / 6;              // pass: 0=hi*hi 1=hi*lo 2=lo*hi
    const int kk0 = (ck % 6) * 64;
    const bf16* Asrc = (p < 2) ? Ahi : Alo;
    const bf16* Wsrc = WT + ((p == 1) ? (size_t)DM*DM : 0);
    __syncthreads();
    #pragma unroll
    for (int s = 0; s < 4; s++){
      int row = wid*32 + s*8 + srow;
      gload16(Asrc + (size_t)(bm + row)*DM + kk0 + scol, &As[(wid*32 + s*8)*64]);
    }
    #pragma unroll
    for (int s = 0; s < 4; s++){
      int row = wid*32 + s*8 + srow;
      gload16(Wsrc + (size_t)(bn + row)*DM + kk0 + scol, &Bs[(wid*32 + s*8)*64]);
    }
    __syncthreads();
    #pragma unroll
    for (int ks = 0; ks < 2; ks++){
      bf16x8 af[4], bg[4];
      #pragma unroll
      for (int m = 0; m < 4; m++)
        af[m] = *(const bf16x8*)&As[(wr*64 + m*16 + (lane & 15))*64 + ks*32 + (lane >> 4)*8];
      #pragma unroll
      for (int n = 0; n < 4; n++)
        bg[n] = *(const bf16x8*)&Bs[(wc*64 + n*16 + (lane & 15))*64 + ks*32 + (lane >> 4)*8];
      #pragma unroll
      for (int m = 0; m < 4; m++)
        #pragma unroll
        for (int n = 0; n < 4; n++)
          acc[m][n] = __builtin_amdgcn_mfma_f32_16x16x32_bf16(af[m], bg[n], acc[m][n], 0, 0, 0);
    }
  }
  const int c_l = lane & 15, r4 = (lane >> 4) * 4;
  #pragma unroll
  for (int m = 0; m < 4; m++)
    #pragma unroll
    for (int n = 0; n < 4; n++)
      #pragma unroll
      for (int r = 0; r < 4; r++){
        int token = bm + wr*64 + m*16 + r4 + r;
        int col   = bn + wc*64 + n*16 + c_l;
        C[(size_t)token*DM + col] = acc[m][n][r] + bias[col];
      }
}

// ---------------- weight prep ----------------
__global__ void zfill(bf16* z){ z[threadIdx.x] = __float2bfloat16(0.f); }

__global__ __launch_bounds__(256) void build_projT(const float* __restrict__ Wv,
    const float* __restrict__ Wo, bf16* __restrict__ WvT, bf16* __restrict__ WoT){
  __shared__ float t[32][33];
  int mat = blockIdx.z;
  const float* W = (mat < 4) ? (Wv + (size_t)mat*DM*DM) : (Wo + (size_t)(mat-4)*DM*DM);
  bf16* WT = (mat < 4) ? (WvT + (size_t)mat*DM*DM) : (WoT + (size_t)(mat-4)*DM*DM);
  int k0 = blockIdx.y*32, n0 = blockIdx.x*32;
  int tx = threadIdx.x & 31, ty = threadIdx.x >> 5;
  #pragma unroll
  for (int r = 0; r < 32; r += 8)
    t[ty + r][tx] = W[(size_t)(k0 + ty + r)*DM + n0 + tx];
  __syncthreads();
  #pragma unroll
  for (int r = 0; r < 32; r += 8)
    WT[(size_t)(n0 + ty + r)*DM + k0 + tx] = __float2bfloat16(t[tx][ty + r]);
}

// Wq/Wk transposed split hi/lo: WT[mat][2][n][k]
__global__ __launch_bounds__(256) void build_qkhl(const float* __restrict__ Wq,
    const float* __restrict__ Wk, bf16* __restrict__ WT){
  __shared__ float t[32][33];
  int mat = blockIdx.z;
  const float* W = (mat < 4) ? (Wq + (size_t)mat*DM*DM) : (Wk + (size_t)(mat-4)*DM*DM);
  bf16* hi = WT + (size_t)mat*2*DM*DM;
  bf16* lo = hi + (size_t)DM*DM;
  int k0 = blockIdx.y*32, n0 = blockIdx.x*32;
  int tx = threadIdx.x & 31, ty = threadIdx.x >> 5;
  #pragma unroll
  for (int r = 0; r < 32; r += 8)
    t[ty + r][tx] = W[(size_t)(k0 + ty + r)*DM + n0 + tx];
  __syncthreads();
  #pragma unroll
  for (int r = 0; r < 32; r += 8){
    float w = t[tx][ty + r];
    bf16 h = __float2bfloat16(w);
    hi[(size_t)(n0 + ty + r)*DM + k0 + tx] = h;
    lo[(size_t)(n0 + ty + r)*DM + k0 + tx] = __float2bfloat16(w - __bfloat162float(h));
  }
}

__global__ void build_c1aT(const float* __restrict__ W, const float* __restrict__ bin,
                           bf16* __restrict__ WT, float* __restrict__ bias_pad){
  int i = blockIdx.x*256 + threadIdx.x;
  if (i < 4*DM){
    int l = i/DM, n = i%DM;
    bias_pad[i] = (n < HID) ? bin[l*HID + n] : 0.f;
  }
  if (i >= 4*3*DM*DM) return;
  int k = i % DM; int n = (i/DM) % DM; int t = (i/(DM*DM)) % 3; int l = i/(3*DM*DM);
  float v = 0.f;
  if (n < HID){
    int g = n / 114; int ci = k - g*128;
    if (ci >= 0 && ci < 128)
      v = W[(((size_t)l*HID + n)*128 + ci)*3 + t];
  }
  WT[i] = __float2bfloat16(v);
}

__global__ void build_c1bT(const float* __restrict__ W, bf16* __restrict__ WT){
  int i = blockIdx.x*256 + threadIdx.x;
  if (i >= 4*3*DM*DM) return;
  int k = i % DM; int n = (i/DM) % DM; int t = (i/(DM*DM)) % 3; int l = i/(3*DM*DM);
  int g = n >> 7; int ci = k - g*114;
  float v = 0.f;
  if (ci >= 0 && ci < 114)
    v = W[(((size_t)l*DM + n)*114 + ci)*3 + t];
  WT[i] = __float2bfloat16(v);
}

// ---------------- fused probe + top-k: one block per (b,h) ----------------
__global__ __launch_bounds__(256) void probe_topk(const float* __restrict__ Q,
    const float* __restrict__ K, const int* __restrict__ idx, int* __restrict__ TOP){
  __shared__ float Ksh[SEQ*49];
  __shared__ float s_redv[4];
  __shared__ int   s_redi[4];
  __shared__ int   s_win;
  int bh = blockIdx.x; int h = bh & 7; int b = bh >> 3;
  int tid = threadIdx.x;
  for (int i = tid; i < SEQ*DHd; i += 256){
    int r = i / DHd, c = i - r*DHd;
    Ksh[r*49 + c] = K[((size_t)(b*SEQ + r))*DM + h*DHd + c];
  }
  __syncthreads();
  int l = tid;
  float Mv = -FLT_MAX;
  if (l < SEQ){
    float qr[DHd];
    const float* qp = Q + ((size_t)(b*SEQ + l))*DM + h*DHd;
    #pragma unroll
    for (int z = 0; z < DHd; z++) qr[z] = qp[z];
    const int* ip = idx + l*UU;
    float mx = -FLT_MAX, sm = 0.f;
    for (int u = 0; u < UU; u++){
      int base = ip[u]*49;
      float d = 0.f;
      #pragma unroll
      for (int z = 0; z < DHd; z++) d += qr[z]*Ksh[base + z];
      mx = fmaxf(mx, d); sm += d;
    }
    Mv = mx - sm*(1.f/UU);
  }
  int myid = (l < SEQ) ? l : (1<<30);
  int lane = tid & 63, wid = tid >> 6;
  for (int sel = 0; sel < UU; sel++){
    float bv = Mv; int bi = myid;
    #pragma unroll
    for (int off = 32; off; off >>= 1){
      float ov = __shfl_xor(bv, off);
      int   oi = __shfl_xor(bi, off);
      if (ov > bv || (ov == bv && oi < bi)){ bv = ov; bi = oi; }
    }
    if (lane == 0){ s_redv[wid] = bv; s_redi[wid] = bi; }
    __syncthreads();
    if (tid == 0){
      float wv = s_redv[0]; int wi = s_redi[0];
      #pragma unroll
      for (int q = 1; q < 4; q++)
        if (s_redv[q] > wv || (s_redv[q] == wv && s_redi[q] < wi)){ wv = s_redv[q]; wi = s_redi[q]; }
      TOP[(size_t)bh*UU + sel] = wi;
      s_win = wi;
    }
    __syncthreads();
    if (myid == s_win) Mv = -FLT_MAX;
  }
}

// ---------------- fused attention context per (b,h) ----------------
// K staged in LDS; u's processed in pairs (V row reads shared by 2 P vectors);
// vmean fused; writes CTX16 (bf16) rows directly: top rows = attention, rest = vmean.
__global__ __launch_bounds__(256) void attn_ctx2(const float* __restrict__ Q,
    const float* __restrict__ K, const float* __restrict__ V,
    const int* __restrict__ TOP, bf16* __restrict__ CTX){
  __shared__ float Ksh[SEQ*49];       // 49000 B
  __shared__ float qsh[2][DHd];
  __shared__ float psh[2][SEQ];
  __shared__ float part[2][5][DHd];
  __shared__ float vmean[DHd];
  __shared__ float red[8];
  __shared__ int   mark[SEQ];
  int bh = blockIdx.x; int h = bh & 7; int b = bh >> 3;
  int tid = threadIdx.x;
  const size_t base = (size_t)b*SEQ*DM + h*DHd;
  // stage K, init mark
  for (int i = tid; i < SEQ*DHd; i += 256){
    int r = i / DHd, c = i - r*DHd;
    Ksh[r*49 + c] = K[base + (size_t)r*DM + c];
  }
  for (int i = tid; i < SEQ; i += 256) mark[i] = -1;
  __syncthreads();
  if (tid < UU) mark[TOP[(size_t)bh*UU + tid]] = tid;
  // vmean
  {
    if (tid < 240){
      int dh = tid % DHd, pr = tid / DHd;
      float s = 0.f;
      for (int j = pr*50; j < pr*50+50; j++) s += V[base + (size_t)j*DM + dh];
      part[0][pr][dh] = s;
    }
    __syncthreads();
    if (tid < DHd)
      vmean[tid] = (part[0][0][tid]+part[0][1][tid]+part[0][2][tid]+part[0][3][tid]+part[0][4][tid]) * (1.f/SEQ);
  }
  // u pairs
  for (int u0 = 0; u0 < UU; u0 += 2){
    __syncthreads();
    if (tid < 2*DHd){
      int uu = tid / DHd, z = tid % DHd;
      int l0 = TOP[(size_t)bh*UU + u0 + uu];
      qsh[uu][z] = Q[(size_t)(b*SEQ + l0)*DM + h*DHd + z];
    }
    __syncthreads();
    float s0 = -FLT_MAX, s1 = -FLT_MAX;
    if (tid < SEQ){
      float d0 = 0.f, d1 = 0.f;
      #pragma unroll
      for (int z = 0; z < DHd; z++){
        float kv = Ksh[tid*49 + z];
        d0 += qsh[0][z]*kv; d1 += qsh[1][z]*kv;
      }
      s0 = d0 * 0.14433756729740643f;   // 1/sqrt(48)
      s1 = d1 * 0.14433756729740643f;
    }
    float m0 = block_max(s0, red);
    float m1 = block_max(s1, red);
    float e0 = (tid < SEQ) ? expf(s0 - m0) : 0.f;
    float e1 = (tid < SEQ) ? expf(s1 - m1) : 0.f;
    if (tid < SEQ){ psh[0][tid] = e0; psh[1][tid] = e1; }
    float sum0 = block_sum(e0, red);
    float sum1 = block_sum(e1, red);
    float inv0 = 1.f/sum0, inv1 = 1.f/sum1;
    __syncthreads();
    if (tid < 240){
      int dh = tid % DHd, pr = tid / DHd;
      float a0 = 0.f, a1 = 0.f;
      for (int j = pr*50; j < pr*50+50; j++){
        float vv = V[base + (size_t)j*DM + dh];
        a0 += psh[0][j]*vv; a1 += psh[1][j]*vv;
      }
      part[0][pr][dh] = a0; part[1][pr][dh] = a1;
    }
    __syncthreads();
    if (tid < 2*DHd){
      int uu = tid / DHd, dh = tid % DHd;
      float inv = uu ? inv1 : inv0;
      float acc = (part[uu][0][dh]+part[uu][1][dh]+part[uu][2][dh]+part[uu][3][dh]+part[uu][4][dh]) * inv;
      int l0 = TOP[(size_t)bh*UU + u0 + uu];
      CTX[(size_t)(b*SEQ + l0)*DM + h*DHd + dh] = __float2bfloat16(acc);
    }
  }
  __syncthreads();
  // fill non-top rows with vmean
  for (int i = tid; i < SEQ*DHd; i += 256){
    int l = i / DHd, dh = i - l*DHd;
    if (mark[l] < 0)
      CTX[(size_t)(b*SEQ + l)*DM + h*DHd + dh] = __float2bfloat16(vmean[dh]);
  }
}

// ---------------- conv2 implicit GEMM, conflict-free mapping, BN=64 ----------------
__global__ __launch_bounds__(256) void conv2_gemm(const float* __restrict__ Hin,
    const float* __restrict__ Wc, const float* __restrict__ bc, float* __restrict__ X){
  __shared__ float hs[8][66];     // cols map d = bn + c - 1
  __shared__ float ws[24][128];
  int bn = blockIdx.x * 64;       // 6 d-tiles
  int g  = blockIdx.y;
  int b  = blockIdx.z;
  int tid = threadIdx.x;
  int tx = tid & 15, ty = tid >> 4;
  const size_t rowOff = ((size_t)b*SEQ + g*125);
  float acc[8][4];
  #pragma unroll
  for (int i=0;i<8;i++)
    #pragma unroll
    for (int j=0;j<4;j++) acc[i][j] = 0.f;

  for (int li0 = 0; li0 < 125; li0 += 8){
    __syncthreads();
    for (int i = tid; i < 8*66; i += 256){
      int r = i / 66, c = i - r*66;
      int d = bn + c - 1;
      float v = 0.f;
      if (d >= 0 && d < DM && (li0 + r) < 125)
        v = Hin[(rowOff + li0 + r)*DM + d];
      hs[r][c] = v;
    }
    for (int i = tid; i < 24*128; i += 256){
      int kr = i >> 7, lo = i & 127;
      int li = li0 + kr/3, t = kr - (kr/3)*3;
      float v = 0.f;
      if (lo < 125 && li < 125)
        v = Wc[(size_t)(g*125 + lo)*375 + li*3 + t];
      ws[kr][lo] = v;
    }
    __syncthreads();
    #pragma unroll
    for (int lr = 0; lr < 8; lr++){
      float w0[8], w1[8], w2[8];
      #pragma unroll
      for (int i=0;i<8;i++){
        w0[i] = ws[lr*3+0][ty*8+i];
        w1[i] = ws[lr*3+1][ty*8+i];
        w2[i] = ws[lr*3+2][ty*8+i];
      }
      #pragma unroll
      for (int j=0;j<4;j++){
        float h0 = hs[lr][tx + 16*j];
        float h1 = hs[lr][tx + 16*j + 1];
        float h2 = hs[lr][tx + 16*j + 2];
        #pragma unroll
        for (int i=0;i<8;i++)
          acc[i][j] = fmaf(w0[i], h0, fmaf(w1[i], h1, fmaf(w2[i], h2, acc[i][j])));
      }
    }
  }
  #pragma unroll
  for (int i=0;i<8;i++){
    int lo = ty*8 + i;
    if (lo < 125){
      float bbv = bc[g*125 + lo];
      float* xp = X + (rowOff + lo)*DM + bn;
      #pragma unroll
      for (int j=0;j<4;j++){
        int d = tx + 16*j;
        xp[d] += gelu_tanh(acc[i][j] + bbv);
      }
    }
  }
}

// ---------------- final: max over L -> LN(ln2) -> FC ----------------
__global__ __launch_bounds__(384) void final_kernel(const float* __restrict__ Hin,
    const float* __restrict__ w, const float* __restrict__ bparm,
    const float* __restrict__ fcw, const float* __restrict__ fcb, float* __restrict__ out){
  __shared__ float red[8];
  __shared__ float ybuf[DM];
  int b = blockIdx.x; int d = threadIdx.x;
  const float* hp = Hin + (size_t)b*SEQ*DM + d;
  float mx = -FLT_MAX;
  for (int l=0;l<SEQ;l++) mx = fmaxf(mx, hp[(size_t)l*DM]);
  float mu = block_sum(mx, red) * (1.f/DM);
  float diff = mx - mu;
  float var = block_sum(diff*diff, red) * (1.f/DM);
  float y = diff * rsqrtf(var + 1e-5f) * w[d] + bparm[d];
  ybuf[d] = y;
  __syncthreads();
  if (d < 10){
    float acc = fcb[d];
    for (int k=0;k<DM;k++) acc += ybuf[k] * fcw[k*10 + d];
    out[b*10 + d] = acc;
  }
}

// ---------------- host orchestration ----------------
extern "C" void kernel_launch(void* const* d_in, const int* in_sizes, int n_in,
                              void* d_out, int out_size, void* d_ws, size_t ws_size,
                              hipStream_t stream) {
  const float* x     = (const float*)d_in[0];
  const float* pos   = (const float*)d_in[1];
  const float* lniw  = (const float*)d_in[2];
  const float* lnib  = (const float*)d_in[3];
  const float* lnAw  = (const float*)d_in[4];
  const float* lnAb  = (const float*)d_in[5];
  const float* Wq    = (const float*)d_in[6];
  const float* bq    = (const float*)d_in[7];
  const float* Wk    = (const float*)d_in[8];
  const float* bk    = (const float*)d_in[9];
  const float* Wv    = (const float*)d_in[10];
  const float* bv    = (const float*)d_in[11];
  const float* Wo    = (const float*)d_in[12];
  const float* bo    = (const float*)d_in[13];
  const float* lnBw  = (const float*)d_in[14];
  const float* lnBb  = (const float*)d_in[15];
  const float* c1aw  = (const float*)d_in[16];
  const float* c1ab  = (const float*)d_in[17];
  const float* c1bw  = (const float*)d_in[18];
  const float* c1bb  = (const float*)d_in[19];
  const float* lnCw  = (const float*)d_in[20];
  const float* lnCb  = (const float*)d_in[21];
  const float* c2w   = (const float*)d_in[22];
  const float* c2b   = (const float*)d_in[23];
  const float* ln2w  = (const float*)d_in[24];
  const float* ln2b  = (const float*)d_in[25];
  const float* fcw   = (const float*)d_in[26];
  const float* fcb   = (const float*)d_in[27];
  float* out = (float*)d_out;

  const size_t ACT  = (size_t)Bb*SEQ*DM;        // 12,288,000
  float* Xb  = (float*)d_ws;
  float* Hb  = Xb  + ACT;                       // f32 for LN-C/final; aliased as Alo bf16 early
  float* Qb  = Hb  + ACT;
  float* Kb  = Qb  + ACT;
  float* Vb  = Kb  + ACT;
  float* biasA = Vb + ACT;
  int*   TOP = (int*)(biasA + 4*DM);
  int*   IDX = TOP + (size_t)Bb*NH*UU;
  bf16*  Hb16 = (bf16*)(IDX + 4*7500);          // Ahi / CTX16 / conv input
  bf16*  G1   = Hb16 + ACT;
  bf16*  WvT  = G1   + ACT;
  bf16*  WoT  = WvT  + (size_t)4*DM*DM;
  bf16*  WaT  = WoT  + (size_t)4*DM*DM;
  bf16*  WbT  = WaT  + (size_t)12*DM*DM;
  bf16*  WqkT = WbT  + (size_t)12*DM*DM;        // [8][2][384][384]
  bf16*  zp   = WqkT + (size_t)16*DM*DM;

  zfill<<<dim3(1), dim3(256), 0, stream>>>(zp);
  idx_kernel<<<dim3(118), dim3(256), 0, stream>>>(IDX);
  build_projT<<<dim3(12,12,8), dim3(256), 0, stream>>>(Wv, Wo, WvT, WoT);
  build_qkhl<<<dim3(12,12,8), dim3(256), 0, stream>>>(Wq, Wk, WqkT);
  build_c1aT<<<dim3(6912), dim3(256), 0, stream>>>(c1aw, c1ab, WaT, biasA);
  build_c1bT<<<dim3(6912), dim3(256), 0, stream>>>(c1bw, WbT);
  pool_ln_pos<<<dim3(32000), dim3(384), 0, stream>>>(x, pos, lniw, lnib, Xb);

  for (int l = 0; l < 4; l++){
    const size_t wofs = (size_t)l*DM*DM;
    bf16* Alo16 = (bf16*)Hb;          // alias: Hb f32 unused until LN-C
    bf16* CTX16 = Hb16;               // reuse after V-proj
    ln384hl<<<dim3(32000), dim3(384), 0, stream>>>(Xb, Hb16, Alo16, lnAw + l*DM, lnAb + l*DM);
    mfma_qk<<<dim3(3,250), dim3(256), 0, stream>>>(Hb16, Alo16, WqkT + (size_t)l*2*DM*DM, bq + l*DM, Qb);
    mfma_qk<<<dim3(3,250), dim3(256), 0, stream>>>(Hb16, Alo16, WqkT + (size_t)(4+l)*2*DM*DM, bk + l*DM, Kb);
    mfma_gemm<1,0><<<dim3(3,250), dim3(256), 0, stream>>>(Hb16, WvT + wofs, bv + l*DM, Vb, (bf16*)nullptr, zp);
    probe_topk<<<dim3(Bb*NH), dim3(256), 0, stream>>>(Qb, Kb, IDX + l*7500, TOP);
    attn_ctx2<<<dim3(Bb*NH), dim3(256), 0, stream>>>(Qb, Kb, Vb, TOP, CTX16);
    mfma_gemm<1,1><<<dim3(3,250), dim3(256), 0, stream>>>(CTX16, WoT + wofs, bo + l*DM, Xb, (bf16*)nullptr, zp);

    ln384x<false,true><<<dim3(32000), dim3(384), 0, stream>>>(Xb, (float*)nullptr, Hb16, lnBw + l*DM, lnBb + l*DM);
    mfma_gemm<3,2><<<dim3(3,250), dim3(256), 0, stream>>>(Hb16, WaT + (size_t)l*3*DM*DM, biasA + l*DM, (float*)nullptr, G1, zp);
    mfma_gemm<3,1><<<dim3(3,250), dim3(256), 0, stream>>>(G1, WbT + (size_t)l*3*DM*DM, c1bb + l*DM, Xb, (bf16*)nullptr, zp);

    ln384x<true,false><<<dim3(32000), dim3(384), 0, stream>>>(Xb, Hb, (bf16*)nullptr, lnCw + l*DM, lnCb + l*DM);
    conv2_gemm<<<dim3(6,2,Bb), dim3(256), 0, stream>>>(Hb, c2w + (size_t)l*SEQ*125*3, c2b + l*SEQ, Xb);
  }

  ln384x<true,false><<<dim3(32000), dim3(384), 0, stream>>>(Xb, Hb, (bf16*)nullptr, ln2w, ln2b);
  final_kernel<<<dim3(Bb), dim3(384), 0, stream>>>(Hb, ln2w, ln2b, fcw, fcb, out);
}

// Round 6
// 4018.844 us; speedup vs baseline: 2.7741x; 1.1743x over previous
//
#include <hip/hip_runtime.h>
#include <hip/hip_bf16.h>
#include <cfloat>
#include <cstdint>

// ---------------- constants ----------------
static constexpr int Bb   = 128;
static constexpr int SEQ  = 250;
static constexpr int DM   = 384;
static constexpr int NH   = 8;
static constexpr int DHd  = 48;
static constexpr int HID  = 342;
static constexpr int UU   = 30;   // U == u == 30

using bf16 = __hip_bfloat16;
typedef __attribute__((ext_vector_type(8))) short bf16x8;
typedef __attribute__((ext_vector_type(4))) float f32x4;

// ---------------- threefry2x32 (JAX-exact) ----------------
__device__ __forceinline__ uint32_t rotl32(uint32_t x, int n){ return (x<<n)|(x>>(32-n)); }
#define TF_R(x0,x1,r) { x0 += x1; x1 = rotl32(x1,(r)); x1 ^= x0; }
__device__ inline void threefry(uint32_t k0, uint32_t k1, uint32_t x0, uint32_t x1,
                                uint32_t &o0, uint32_t &o1){
  uint32_t ks2 = k0 ^ k1 ^ 0x1BD11BDAu;
  x0 += k0; x1 += k1;
  TF_R(x0,x1,13) TF_R(x0,x1,15) TF_R(x0,x1,26) TF_R(x0,x1,6)
  x0 += k1; x1 += ks2 + 1u;
  TF_R(x0,x1,17) TF_R(x0,x1,29) TF_R(x0,x1,16) TF_R(x0,x1,24)
  x0 += ks2; x1 += k0 + 2u;
  TF_R(x0,x1,13) TF_R(x0,x1,15) TF_R(x0,x1,26) TF_R(x0,x1,6)
  x0 += k0; x1 += k1 + 3u;
  TF_R(x0,x1,17) TF_R(x0,x1,29) TF_R(x0,x1,16) TF_R(x0,x1,24)
  x0 += k1; x1 += ks2 + 4u;
  TF_R(x0,x1,13) TF_R(x0,x1,15) TF_R(x0,x1,26) TF_R(x0,x1,6)
  x0 += ks2; x1 += k0 + 5u;
  o0 = x0; o1 = x1;
}

__global__ void idx_kernel(int* __restrict__ IDX){
  int i = blockIdx.x*256 + threadIdx.x;
  if (i >= 4*7500) return;
  int l = i / 7500;
  int t = i % 7500;
  uint32_t fk0, fk1;
  threefry(0u, 42u, 0u, (uint32_t)l, fk0, fk1);
  uint32_t a0,a1,b0,b1;
  threefry(fk0, fk1, 0u, 2u, a0, a1);
  threefry(fk0, fk1, 1u, 3u, b0, b1);
  uint32_t c0 = (t < 3750) ? (uint32_t)t          : (uint32_t)(t-3750);
  uint32_t c1 = (t < 3750) ? (uint32_t)(t+3750)   : (uint32_t)t;
  uint32_t y0, y1, hi, lo;
  threefry(a0, b0, c0, c1, y0, y1); hi = (t < 3750) ? y0 : y1;
  threefry(a1, b1, c0, c1, y0, y1); lo = (t < 3750) ? y0 : y1;
  uint32_t val = ((hi % 250u) * 46u + (lo % 250u)) % 250u;
  IDX[i] = (int)val;
}

// ---------------- block reductions ----------------
__device__ __forceinline__ float block_sum(float v, float* red){
  v += __shfl_down(v,32); v += __shfl_down(v,16); v += __shfl_down(v,8);
  v += __shfl_down(v,4);  v += __shfl_down(v,2);  v += __shfl_down(v,1);
  int lane = threadIdx.x & 63, wid = threadIdx.x >> 6, nw = blockDim.x >> 6;
  __syncthreads();
  if (lane == 0) red[wid] = v;
  __syncthreads();
  float r = red[0];
  for (int i=1;i<nw;i++) r += red[i];
  return r;
}
__device__ __forceinline__ float block_max(float v, float* red){
  v = fmaxf(v, __shfl_down(v,32)); v = fmaxf(v, __shfl_down(v,16)); v = fmaxf(v, __shfl_down(v,8));
  v = fmaxf(v, __shfl_down(v,4));  v = fmaxf(v, __shfl_down(v,2));  v = fmaxf(v, __shfl_down(v,1));
  int lane = threadIdx.x & 63, wid = threadIdx.x >> 6, nw = blockDim.x >> 6;
  __syncthreads();
  if (lane == 0) red[wid] = v;
  __syncthreads();
  float r = red[0];
  for (int i=1;i<nw;i++) r = fmaxf(r, red[i]);
  return r;
}

__device__ __forceinline__ float gelu_tanh(float x){
  float t = 0.7978845608028654f * (x + 0.044715f * x * x * x);
  return 0.5f * x * (1.f + tanhf(t));
}

// ---------------- pool (max over 4) + LN + pos ----------------
__global__ __launch_bounds__(384) void pool_ln_pos(const float* __restrict__ xin,
    const float* __restrict__ pos, const float* __restrict__ w, const float* __restrict__ b,
    float* __restrict__ X){
  __shared__ float red[8];
  int bs = blockIdx.x; int bb = bs / SEQ, s = bs % SEQ; int d = threadIdx.x;
  const float* xp = xin + ((size_t)bb*1000 + (size_t)s*4)*DM + d;
  float v = fmaxf(fmaxf(xp[0], xp[DM]), fmaxf(xp[2*DM], xp[3*DM]));
  float mu = block_sum(v, red) * (1.f/DM);
  float diff = v - mu;
  float var = block_sum(diff*diff, red) * (1.f/DM);
  X[(size_t)bs*DM + d] = diff * rsqrtf(var + 1e-5f) * w[d] + b[d] + pos[(size_t)s*DM + d];
}

// ---------------- LayerNorm, optional f32/bf16 outputs ----------------
template<bool WF32, bool WB16>
__global__ __launch_bounds__(384) void ln384x(const float* __restrict__ in,
    float* __restrict__ o32, bf16* __restrict__ o16,
    const float* __restrict__ w, const float* __restrict__ b){
  __shared__ float red[8];
  size_t row = blockIdx.x; int d = threadIdx.x;
  float v = in[row*DM + d];
  float mu = block_sum(v, red) * (1.f/DM);
  float diff = v - mu;
  float var = block_sum(diff*diff, red) * (1.f/DM);
  float y = diff * rsqrtf(var + 1e-5f) * w[d] + b[d];
  if (WF32) o32[row*DM + d] = y;
  if (WB16) o16[row*DM + d] = __float2bfloat16(y);
}

// LayerNorm writing split hi/lo bf16 (for f32-accurate MFMA GEMM)
__global__ __launch_bounds__(384) void ln384hl(const float* __restrict__ in,
    bf16* __restrict__ ohi, bf16* __restrict__ olo,
    const float* __restrict__ w, const float* __restrict__ b){
  __shared__ float red[8];
  size_t row = blockIdx.x; int d = threadIdx.x;
  float v = in[row*DM + d];
  float mu = block_sum(v, red) * (1.f/DM);
  float diff = v - mu;
  float var = block_sum(diff*diff, red) * (1.f/DM);
  float y = diff * rsqrtf(var + 1e-5f) * w[d] + b[d];
  bf16 h = __float2bfloat16(y);
  ohi[row*DM + d] = h;
  olo[row*DM + d] = __float2bfloat16(y - __bfloat162float(h));
}

// ---------------- bf16 MFMA GEMM ----------------
__device__ __forceinline__ void gload16(const void* g, void* l){
  __builtin_amdgcn_global_load_lds(
      (__attribute__((address_space(1))) void*)(g),
      (__attribute__((address_space(3))) void*)(l), 16, 0, 0);
}

// C[M x 384] = sum_tap shift(A,tap-1) @ W_tap ; EPI: 0=store f32+bias 1=+= f32+bias 2=bf16 gelu store
template<int TAPS, int EPI>
__global__ __launch_bounds__(256) void mfma_gemm(
    const bf16* __restrict__ A, const bf16* __restrict__ WT,
    const float* __restrict__ bias, float* __restrict__ Cf, bf16* __restrict__ Cb,
    const bf16* __restrict__ zpage)
{
  __shared__ bf16 As[128*64];
  __shared__ bf16 Bs[128*64];
  const int tid = threadIdx.x;
  const int wid = tid >> 6, lane = tid & 63;
  const int wr = wid >> 1, wc = wid & 1;
  const int bm = blockIdx.y * 128;
  const int bn = blockIdx.x * 128;
  const int srow = lane >> 3;
  const int scol = (lane & 7) * 8;

  f32x4 acc[4][4] = {};
  const int NCH = TAPS * 6;
  for (int ck = 0; ck < NCH; ck++){
    const int tap = (TAPS == 3) ? (ck / 6) : 0;
    const int kk0 = (TAPS == 3) ? ((ck % 6) * 64) : (ck * 64);
    __syncthreads();
    #pragma unroll
    for (int s = 0; s < 4; s++){
      int row = wid*32 + s*8 + srow;
      int token = bm + row;
      const bf16* src;
      if (TAPS == 3){
        int l = token - (token/SEQ)*SEQ;
        int ls = l + tap - 1;
        bool valid = (ls >= 0) && (ls < SEQ);
        src = valid ? (A + (size_t)(token + tap - 1)*DM + kk0 + scol) : zpage;
      } else {
        src = A + (size_t)token*DM + kk0 + scol;
      }
      gload16(src, &As[(wid*32 + s*8)*64]);
    }
    #pragma unroll
    for (int s = 0; s < 4; s++){
      int row = wid*32 + s*8 + srow;
      const bf16* src = WT + ((size_t)(tap*DM + bn + row))*DM + kk0 + scol;
      gload16(src, &Bs[(wid*32 + s*8)*64]);
    }
    __syncthreads();
    #pragma unroll
    for (int ks = 0; ks < 2; ks++){
      bf16x8 af[4], bg[4];
      #pragma unroll
      for (int m = 0; m < 4; m++)
        af[m] = *(const bf16x8*)&As[(wr*64 + m*16 + (lane & 15))*64 + ks*32 + (lane >> 4)*8];
      #pragma unroll
      for (int n = 0; n < 4; n++)
        bg[n] = *(const bf16x8*)&Bs[(wc*64 + n*16 + (lane & 15))*64 + ks*32 + (lane >> 4)*8];
      #pragma unroll
      for (int m = 0; m < 4; m++)
        #pragma unroll
        for (int n = 0; n < 4; n++)
          acc[m][n] = __builtin_amdgcn_mfma_f32_16x16x32_bf16(af[m], bg[n], acc[m][n], 0, 0, 0);
    }
  }
  const int c_l = lane & 15, r4 = (lane >> 4) * 4;
  #pragma unroll
  for (int m = 0; m < 4; m++){
    #pragma unroll
    for (int n = 0; n < 4; n++){
      #pragma unroll
      for (int r = 0; r < 4; r++){
        int token = bm + wr*64 + m*16 + r4 + r;
        int col   = bn + wc*64 + n*16 + c_l;
        float v = acc[m][n][r] + bias[col];
        if (EPI == 0)      Cf[(size_t)token*DM + col] = v;
        else if (EPI == 1) Cf[(size_t)token*DM + col] += v;
        else               Cb[(size_t)token*DM + col] = __float2bfloat16(gelu_tanh(v));
      }
    }
  }
}

// split-bf16 f32-accurate GEMM: C = Ahi@Whi + Ahi@Wlo + Alo@Whi + bias (f32 out)
__global__ __launch_bounds__(256) void mfma_qk(
    const bf16* __restrict__ Ahi, const bf16* __restrict__ Alo,
    const bf16* __restrict__ WT, const float* __restrict__ bias, float* __restrict__ C)
{
  __shared__ bf16 As[128*64];
  __shared__ bf16 Bs[128*64];
  const int tid = threadIdx.x;
  const int wid = tid >> 6, lane = tid & 63;
  const int wr = wid >> 1, wc = wid & 1;
  const int bm = blockIdx.y * 128;
  const int bn = blockIdx.x * 128;
  const int srow = lane >> 3;
  const int scol = (lane & 7) * 8;

  f32x4 acc[4][4] = {};
  for (int ck = 0; ck < 18; ck++){
    const int p   = ck / 6;              // pass: 0=hi*hi 1=hi*lo 2=lo*hi
    const int kk0 = (ck % 6) * 64;
    const bf16* Asrc = (p < 2) ? Ahi : Alo;
    const bf16* Wsrc = WT + ((p == 1) ? (size_t)DM*DM : 0);
    __syncthreads();
    #pragma unroll
    for (int s = 0; s < 4; s++){
      int row = wid*32 + s*8 + srow;
      gload16(Asrc + (size_t)(bm + row)*DM + kk0 + scol, &As[(wid*32 + s*8)*64]);
    }
    #pragma unroll
    for (int s = 0; s < 4; s++){
      int row = wid*32 + s*8 + srow;
      gload16(Wsrc + (size_t)(bn + row)*DM + kk0 + scol, &Bs[(wid*32 + s*8)*64]);
    }
    __syncthreads();
    #pragma unroll
    for (int ks = 0; ks < 2; ks++){
      bf16x8 af[4], bg[4];
      #pragma unroll
      for (int m = 0; m < 4; m++)
        af[m] = *(const bf16x8*)&As[(wr*64 + m*16 + (lane & 15))*64 + ks*32 + (lane >> 4)*8];
      #pragma unroll
      for (int n = 0; n < 4; n++)
        bg[n] = *(const bf16x8*)&Bs[(wc*64 + n*16 + (lane & 15))*64 + ks*32 + (lane >> 4)*8];
      #pragma unroll
      for (int m = 0; m < 4; m++)
        #pragma unroll
        for (int n = 0; n < 4; n++)
          acc[m][n] = __builtin_amdgcn_mfma_f32_16x16x32_bf16(af[m], bg[n], acc[m][n], 0, 0, 0);
    }
  }
  const int c_l = lane & 15, r4 = (lane >> 4) * 4;
  #pragma unroll
  for (int m = 0; m < 4; m++)
    #pragma unroll
    for (int n = 0; n < 4; n++)
      #pragma unroll
      for (int r = 0; r < 4; r++){
        int token = bm + wr*64 + m*16 + r4 + r;
        int col   = bn + wc*64 + n*16 + c_l;
        C[(size_t)token*DM + col] = acc[m][n][r] + bias[col];
      }
}

// ---------------- conv2 as MFMA: C[lo][d] = sum_t (W_t @ H)[lo][d+t-1] ----------------
// A = W2T[g][tap][128 lo][128 li] (prebuilt, zero-padded); B rows = HT[b][d+tap-1][g][128 li]
__global__ __launch_bounds__(256) void conv2_mfma(
    const bf16* __restrict__ HT, const bf16* __restrict__ W2T,
    const float* __restrict__ bias, float* __restrict__ X,
    const bf16* __restrict__ zpage)
{
  __shared__ bf16 As[128*64];
  __shared__ bf16 Bs[128*64];
  const int tid = threadIdx.x;
  const int wid = tid >> 6, lane = tid & 63;
  const int wr = wid >> 1, wc = wid & 1;
  const int bn = blockIdx.x * 128;   // d tile (0,128,256)
  const int g  = blockIdx.y;
  const int b  = blockIdx.z;
  const int srow = lane >> 3;
  const int scol = (lane & 7) * 8;
  const bf16* Wbase = W2T + (size_t)g*3*128*128;

  f32x4 acc[4][4] = {};
  for (int ck = 0; ck < 6; ck++){
    const int tap = ck >> 1;
    const int kk0 = (ck & 1) * 64;
    __syncthreads();
    #pragma unroll
    for (int s = 0; s < 4; s++){
      int row = wid*32 + s*8 + srow;
      gload16(Wbase + ((size_t)tap*128 + row)*128 + kk0 + scol, &As[(wid*32 + s*8)*64]);
    }
    #pragma unroll
    for (int s = 0; s < 4; s++){
      int row = wid*32 + s*8 + srow;
      int sd = bn + row + tap - 1;
      const bf16* src = (sd >= 0 && sd < DM)
        ? (HT + (((size_t)b*DM + sd)*2 + g)*128 + kk0 + scol) : zpage;
      gload16(src, &Bs[(wid*32 + s*8)*64]);
    }
    __syncthreads();
    #pragma unroll
    for (int ks = 0; ks < 2; ks++){
      bf16x8 af[4], bg[4];
      #pragma unroll
      for (int m = 0; m < 4; m++)
        af[m] = *(const bf16x8*)&As[(wr*64 + m*16 + (lane & 15))*64 + ks*32 + (lane >> 4)*8];
      #pragma unroll
      for (int n = 0; n < 4; n++)
        bg[n] = *(const bf16x8*)&Bs[(wc*64 + n*16 + (lane & 15))*64 + ks*32 + (lane >> 4)*8];
      #pragma unroll
      for (int m = 0; m < 4; m++)
        #pragma unroll
        for (int n = 0; n < 4; n++)
          acc[m][n] = __builtin_amdgcn_mfma_f32_16x16x32_bf16(af[m], bg[n], acc[m][n], 0, 0, 0);
    }
  }
  const int c_l = lane & 15, r4 = (lane >> 4) * 4;
  #pragma unroll
  for (int m = 0; m < 4; m++){
    #pragma unroll
    for (int n = 0; n < 4; n++){
      #pragma unroll
      for (int r = 0; r < 4; r++){
        int lo = wr*64 + m*16 + r4 + r;
        if (lo < 125){
          int d = bn + wc*64 + n*16 + c_l;
          float v = acc[m][n][r] + bias[g*125 + lo];
          X[((size_t)b*SEQ + g*125 + lo)*DM + d] += gelu_tanh(v);
        }
      }
    }
  }
}

// ---------------- transpose H[b][l][d] bf16 -> HT[b][d][g*128+li] bf16 (pad zero) ----------------
__global__ __launch_bounds__(256) void transpose_ht(const bf16* __restrict__ H,
                                                    bf16* __restrict__ HT){
  __shared__ bf16 t[68][66];
  int d0 = blockIdx.x * 64;
  int p0 = blockIdx.y * 64;
  int b  = blockIdx.z;
  int tid = threadIdx.x;
  int l0 = p0 - 3;
  for (int i = tid; i < 68*64; i += 256){
    int r = i >> 6, c = i & 63;
    int l = l0 + r;
    bf16 v = __float2bfloat16(0.f);
    if (l >= 0 && l < SEQ) v = H[((size_t)b*SEQ + l)*DM + d0 + c];
    t[r][c] = v;
  }
  __syncthreads();
  for (int i = tid; i < 64*64; i += 256){
    int rr = i >> 6, cc = i & 63;
    int p = p0 + cc;
    int gg = p >> 7, li = p & 127;
    int l = gg*125 + li;
    bf16 v = __float2bfloat16(0.f);
    if (li < 125 && l < SEQ) v = t[l - l0][rr];
    HT[((size_t)b*DM + d0 + rr)*256 + p] = v;
  }
}

// ---------------- weight prep ----------------
__global__ void zfill(bf16* z){ z[threadIdx.x] = __float2bfloat16(0.f); }

__global__ __launch_bounds__(256) void build_projT(const float* __restrict__ Wv,
    const float* __restrict__ Wo, bf16* __restrict__ WvT, bf16* __restrict__ WoT){
  __shared__ float t[32][33];
  int mat = blockIdx.z;
  const float* W = (mat < 4) ? (Wv + (size_t)mat*DM*DM) : (Wo + (size_t)(mat-4)*DM*DM);
  bf16* WT = (mat < 4) ? (WvT + (size_t)mat*DM*DM) : (WoT + (size_t)(mat-4)*DM*DM);
  int k0 = blockIdx.y*32, n0 = blockIdx.x*32;
  int tx = threadIdx.x & 31, ty = threadIdx.x >> 5;
  #pragma unroll
  for (int r = 0; r < 32; r += 8)
    t[ty + r][tx] = W[(size_t)(k0 + ty + r)*DM + n0 + tx];
  __syncthreads();
  #pragma unroll
  for (int r = 0; r < 32; r += 8)
    WT[(size_t)(n0 + ty + r)*DM + k0 + tx] = __float2bfloat16(t[tx][ty + r]);
}

// Wq/Wk transposed split hi/lo: WT[mat][2][n][k]
__global__ __launch_bounds__(256) void build_qkhl(const float* __restrict__ Wq,
    const float* __restrict__ Wk, bf16* __restrict__ WT){
  __shared__ float t[32][33];
  int mat = blockIdx.z;
  const float* W = (mat < 4) ? (Wq + (size_t)mat*DM*DM) : (Wk + (size_t)(mat-4)*DM*DM);
  bf16* hi = WT + (size_t)mat*2*DM*DM;
  bf16* lo = hi + (size_t)DM*DM;
  int k0 = blockIdx.y*32, n0 = blockIdx.x*32;
  int tx = threadIdx.x & 31, ty = threadIdx.x >> 5;
  #pragma unroll
  for (int r = 0; r < 32; r += 8)
    t[ty + r][tx] = W[(size_t)(k0 + ty + r)*DM + n0 + tx];
  __syncthreads();
  #pragma unroll
  for (int r = 0; r < 32; r += 8){
    float w = t[tx][ty + r];
    bf16 h = __float2bfloat16(w);
    hi[(size_t)(n0 + ty + r)*DM + k0 + tx] = h;
    lo[(size_t)(n0 + ty + r)*DM + k0 + tx] = __float2bfloat16(w - __bfloat162float(h));
  }
}

__global__ void build_c1aT(const float* __restrict__ W, const float* __restrict__ bin,
                           bf16* __restrict__ WT, float* __restrict__ bias_pad){
  int i = blockIdx.x*256 + threadIdx.x;
  if (i < 4*DM){
    int l = i/DM, n = i%DM;
    bias_pad[i] = (n < HID) ? bin[l*HID + n] : 0.f;
  }
  if (i >= 4*3*DM*DM) return;
  int k = i % DM; int n = (i/DM) % DM; int t = (i/(DM*DM)) % 3; int l = i/(3*DM*DM);
  float v = 0.f;
  if (n < HID){
    int g = n / 114; int ci = k - g*128;
    if (ci >= 0 && ci < 128)
      v = W[(((size_t)l*HID + n)*128 + ci)*3 + t];
  }
  WT[i] = __float2bfloat16(v);
}

__global__ void build_c1bT(const float* __restrict__ W, bf16* __restrict__ WT){
  int i = blockIdx.x*256 + threadIdx.x;
  if (i >= 4*3*DM*DM) return;
  int k = i % DM; int n = (i/DM) % DM; int t = (i/(DM*DM)) % 3; int l = i/(3*DM*DM);
  int g = n >> 7; int ci = k - g*114;
  float v = 0.f;
  if (ci >= 0 && ci < 114)
    v = W[(((size_t)l*DM + n)*114 + ci)*3 + t];
  WT[i] = __float2bfloat16(v);
}

// conv2 weights: W2T[l][g][tap][lo(128)][li(128)] = c2_w[l][g*125+lo][li][tap], zero-padded
__global__ void build_c2T(const float* __restrict__ W, bf16* __restrict__ WT){
  int i = blockIdx.x*256 + threadIdx.x;
  if (i >= 4*2*3*128*128) return;
  int li = i & 127;
  int lo = (i >> 7) & 127;
  int t  = (i / 16384) % 3;
  int g  = (i / 49152) % 2;
  int l  = i / 98304;
  float v = 0.f;
  if (lo < 125 && li < 125)
    v = W[(((size_t)l*SEQ + g*125 + lo)*125 + li)*3 + t];
  WT[i] = __float2bfloat16(v);
}

// ---------------- fused probe + top-k: one block per (b,h) ----------------
__global__ __launch_bounds__(256) void probe_topk(const float* __restrict__ Q,
    const float* __restrict__ K, const int* __restrict__ idx, int* __restrict__ TOP){
  __shared__ float Ksh[SEQ*49];
  __shared__ float s_redv[4];
  __shared__ int   s_redi[4];
  __shared__ int   s_win;
  int bh = blockIdx.x; int h = bh & 7; int b = bh >> 3;
  int tid = threadIdx.x;
  for (int i = tid; i < SEQ*DHd; i += 256){
    int r = i / DHd, c = i - r*DHd;
    Ksh[r*49 + c] = K[((size_t)(b*SEQ + r))*DM + h*DHd + c];
  }
  __syncthreads();
  int l = tid;
  float Mv = -FLT_MAX;
  if (l < SEQ){
    float qr[DHd];
    const float* qp = Q + ((size_t)(b*SEQ + l))*DM + h*DHd;
    #pragma unroll
    for (int z = 0; z < DHd; z++) qr[z] = qp[z];
    const int* ip = idx + l*UU;
    float mx = -FLT_MAX, sm = 0.f;
    for (int u = 0; u < UU; u++){
      int base = ip[u]*49;
      float d = 0.f;
      #pragma unroll
      for (int z = 0; z < DHd; z++) d += qr[z]*Ksh[base + z];
      mx = fmaxf(mx, d); sm += d;
    }
    Mv = mx - sm*(1.f/UU);
  }
  int myid = (l < SEQ) ? l : (1<<30);
  int lane = tid & 63, wid = tid >> 6;
  for (int sel = 0; sel < UU; sel++){
    float bv = Mv; int bi = myid;
    #pragma unroll
    for (int off = 32; off; off >>= 1){
      float ov = __shfl_xor(bv, off);
      int   oi = __shfl_xor(bi, off);
      if (ov > bv || (ov == bv && oi < bi)){ bv = ov; bi = oi; }
    }
    if (lane == 0){ s_redv[wid] = bv; s_redi[wid] = bi; }
    __syncthreads();
    if (tid == 0){
      float wv = s_redv[0]; int wi = s_redi[0];
      #pragma unroll
      for (int q = 1; q < 4; q++)
        if (s_redv[q] > wv || (s_redv[q] == wv && s_redi[q] < wi)){ wv = s_redv[q]; wi = s_redi[q]; }
      TOP[(size_t)bh*UU + sel] = wi;
      s_win = wi;
    }
    __syncthreads();
    if (myid == s_win) Mv = -FLT_MAX;
  }
}

// ---------------- fused attention context per (b,h) ----------------
__global__ __launch_bounds__(256) void attn_ctx2(const float* __restrict__ Q,
    const float* __restrict__ K, const float* __restrict__ V,
    const int* __restrict__ TOP, bf16* __restrict__ CTX){
  __shared__ float Ksh[SEQ*49];
  __shared__ float qsh[2][DHd];
  __shared__ float psh[2][SEQ];
  __shared__ float part[2][5][DHd];
  __shared__ float vmean[DHd];
  __shared__ float red[8];
  __shared__ int   mark[SEQ];
  int bh = blockIdx.x; int h = bh & 7; int b = bh >> 3;
  int tid = threadIdx.x;
  const size_t base = (size_t)b*SEQ*DM + h*DHd;
  for (int i = tid; i < SEQ*DHd; i += 256){
    int r = i / DHd, c = i - r*DHd;
    Ksh[r*49 + c] = K[base + (size_t)r*DM + c];
  }
  for (int i = tid; i < SEQ; i += 256) mark[i] = -1;
  __syncthreads();
  if (tid < UU) mark[TOP[(size_t)bh*UU + tid]] = tid;
  {
    if (tid < 240){
      int dh = tid % DHd, pr = tid / DHd;
      float s = 0.f;
      for (int j = pr*50; j < pr*50+50; j++) s += V[base + (size_t)j*DM + dh];
      part[0][pr][dh] = s;
    }
    __syncthreads();
    if (tid < DHd)
      vmean[tid] = (part[0][0][tid]+part[0][1][tid]+part[0][2][tid]+part[0][3][tid]+part[0][4][tid]) * (1.f/SEQ);
  }
  for (int u0 = 0; u0 < UU; u0 += 2){
    __syncthreads();
    if (tid < 2*DHd){
      int uu = tid / DHd, z = tid % DHd;
      int l0 = TOP[(size_t)bh*UU + u0 + uu];
      qsh[uu][z] = Q[(size_t)(b*SEQ + l0)*DM + h*DHd + z];
    }
    __syncthreads();
    float s0 = -FLT_MAX, s1 = -FLT_MAX;
    if (tid < SEQ){
      float d0 = 0.f, d1 = 0.f;
      #pragma unroll
      for (int z = 0; z < DHd; z++){
        float kv = Ksh[tid*49 + z];
        d0 += qsh[0][z]*kv; d1 += qsh[1][z]*kv;
      }
      s0 = d0 * 0.14433756729740643f;   // 1/sqrt(48)
      s1 = d1 * 0.14433756729740643f;
    }
    float m0 = block_max(s0, red);
    float m1 = block_max(s1, red);
    float e0 = (tid < SEQ) ? expf(s0 - m0) : 0.f;
    float e1 = (tid < SEQ) ? expf(s1 - m1) : 0.f;
    if (tid < SEQ){ psh[0][tid] = e0; psh[1][tid] = e1; }
    float sum0 = block_sum(e0, red);
    float sum1 = block_sum(e1, red);
    float inv0 = 1.f/sum0, inv1 = 1.f/sum1;
    __syncthreads();
    if (tid < 240){
      int dh = tid % DHd, pr = tid / DHd;
      float a0 = 0.f, a1 = 0.f;
      for (int j = pr*50; j < pr*50+50; j++){
        float vv = V[base + (size_t)j*DM + dh];
        a0 += psh[0][j]*vv; a1 += psh[1][j]*vv;
      }
      part[0][pr][dh] = a0; part[1][pr][dh] = a1;
    }
    __syncthreads();
    if (tid < 2*DHd){
      int uu = tid / DHd, dh = tid % DHd;
      float inv = uu ? inv1 : inv0;
      float acc = (part[uu][0][dh]+part[uu][1][dh]+part[uu][2][dh]+part[uu][3][dh]+part[uu][4][dh]) * inv;
      int l0 = TOP[(size_t)bh*UU + u0 + uu];
      CTX[(size_t)(b*SEQ + l0)*DM + h*DHd + dh] = __float2bfloat16(acc);
    }
  }
  __syncthreads();
  for (int i = tid; i < SEQ*DHd; i += 256){
    int l = i / DHd, dh = i - l*DHd;
    if (mark[l] < 0)
      CTX[(size_t)(b*SEQ + l)*DM + h*DHd + dh] = __float2bfloat16(vmean[dh]);
  }
}

// ---------------- final: max over L -> LN(ln2) -> FC ----------------
__global__ __launch_bounds__(384) void final_kernel(const float* __restrict__ Hin,
    const float* __restrict__ w, const float* __restrict__ bparm,
    const float* __restrict__ fcw, const float* __restrict__ fcb, float* __restrict__ out){
  __shared__ float red[8];
  __shared__ float ybuf[DM];
  int b = blockIdx.x; int d = threadIdx.x;
  const float* hp = Hin + (size_t)b*SEQ*DM + d;
  float mx = -FLT_MAX;
  for (int l=0;l<SEQ;l++) mx = fmaxf(mx, hp[(size_t)l*DM]);
  float mu = block_sum(mx, red) * (1.f/DM);
  float diff = mx - mu;
  float var = block_sum(diff*diff, red) * (1.f/DM);
  float y = diff * rsqrtf(var + 1e-5f) * w[d] + bparm[d];
  ybuf[d] = y;
  __syncthreads();
  if (d < 10){
    float acc = fcb[d];
    for (int k=0;k<DM;k++) acc += ybuf[k] * fcw[k*10 + d];
    out[b*10 + d] = acc;
  }
}

// ---------------- host orchestration ----------------
extern "C" void kernel_launch(void* const* d_in, const int* in_sizes, int n_in,
                              void* d_out, int out_size, void* d_ws, size_t ws_size,
                              hipStream_t stream) {
  const float* x     = (const float*)d_in[0];
  const float* pos   = (const float*)d_in[1];
  const float* lniw  = (const float*)d_in[2];
  const float* lnib  = (const float*)d_in[3];
  const float* lnAw  = (const float*)d_in[4];
  const float* lnAb  = (const float*)d_in[5];
  const float* Wq    = (const float*)d_in[6];
  const float* bq    = (const float*)d_in[7];
  const float* Wk    = (const float*)d_in[8];
  const float* bk    = (const float*)d_in[9];
  const float* Wv    = (const float*)d_in[10];
  const float* bv    = (const float*)d_in[11];
  const float* Wo    = (const float*)d_in[12];
  const float* bo    = (const float*)d_in[13];
  const float* lnBw  = (const float*)d_in[14];
  const float* lnBb  = (const float*)d_in[15];
  const float* c1aw  = (const float*)d_in[16];
  const float* c1ab  = (const float*)d_in[17];
  const float* c1bw  = (const float*)d_in[18];
  const float* c1bb  = (const float*)d_in[19];
  const float* lnCw  = (const float*)d_in[20];
  const float* lnCb  = (const float*)d_in[21];
  const float* c2w   = (const float*)d_in[22];
  const float* c2b   = (const float*)d_in[23];
  const float* ln2w  = (const float*)d_in[24];
  const float* ln2b  = (const float*)d_in[25];
  const float* fcw   = (const float*)d_in[26];
  const float* fcb   = (const float*)d_in[27];
  float* out = (float*)d_out;

  const size_t ACT  = (size_t)Bb*SEQ*DM;        // 12,288,000
  float* Xb  = (float*)d_ws;
  float* Hb  = Xb  + ACT;                       // f32 for final LN; aliased as Alo bf16 early
  float* Qb  = Hb  + ACT;                       // also aliased as HT bf16 in conv2 phase
  float* Kb  = Qb  + ACT;
  float* Vb  = Kb  + ACT;
  float* biasA = Vb + ACT;
  int*   TOP = (int*)(biasA + 4*DM);
  int*   IDX = TOP + (size_t)Bb*NH*UU;
  bf16*  Hb16 = (bf16*)(IDX + 4*7500);          // Ahi / CTX16 / conv input
  bf16*  G1   = Hb16 + ACT;
  bf16*  WvT  = G1   + ACT;
  bf16*  WoT  = WvT  + (size_t)4*DM*DM;
  bf16*  WaT  = WoT  + (size_t)4*DM*DM;
  bf16*  WbT  = WaT  + (size_t)12*DM*DM;
  bf16*  WqkT = WbT  + (size_t)12*DM*DM;        // [8][2][384][384]
  bf16*  W2T  = WqkT + (size_t)16*DM*DM;        // [4][2][3][128][128]
  bf16*  zp   = W2T  + (size_t)4*2*3*128*128;

  zfill<<<dim3(1), dim3(256), 0, stream>>>(zp);
  idx_kernel<<<dim3(118), dim3(256), 0, stream>>>(IDX);
  build_projT<<<dim3(12,12,8), dim3(256), 0, stream>>>(Wv, Wo, WvT, WoT);
  build_qkhl<<<dim3(12,12,8), dim3(256), 0, stream>>>(Wq, Wk, WqkT);
  build_c1aT<<<dim3(6912), dim3(256), 0, stream>>>(c1aw, c1ab, WaT, biasA);
  build_c1bT<<<dim3(6912), dim3(256), 0, stream>>>(c1bw, WbT);
  build_c2T<<<dim3(1536), dim3(256), 0, stream>>>(c2w, W2T);
  pool_ln_pos<<<dim3(32000), dim3(384), 0, stream>>>(x, pos, lniw, lnib, Xb);

  for (int l = 0; l < 4; l++){
    const size_t wofs = (size_t)l*DM*DM;
    bf16* Alo16 = (bf16*)Hb;          // alias: Hb f32 unused until final LN
    bf16* CTX16 = Hb16;               // reuse after V-proj
    bf16* HTb   = (bf16*)Qb;          // alias: Qb dead after attention
    ln384hl<<<dim3(32000), dim3(384), 0, stream>>>(Xb, Hb16, Alo16, lnAw + l*DM, lnAb + l*DM);
    mfma_qk<<<dim3(3,250), dim3(256), 0, stream>>>(Hb16, Alo16, WqkT + (size_t)l*2*DM*DM, bq + l*DM, Qb);
    mfma_qk<<<dim3(3,250), dim3(256), 0, stream>>>(Hb16, Alo16, WqkT + (size_t)(4+l)*2*DM*DM, bk + l*DM, Kb);
    mfma_gemm<1,0><<<dim3(3,250), dim3(256), 0, stream>>>(Hb16, WvT + wofs, bv + l*DM, Vb, (bf16*)nullptr, zp);
    probe_topk<<<dim3(Bb*NH), dim3(256), 0, stream>>>(Qb, Kb, IDX + l*7500, TOP);
    attn_ctx2<<<dim3(Bb*NH), dim3(256), 0, stream>>>(Qb, Kb, Vb, TOP, CTX16);
    mfma_gemm<1,1><<<dim3(3,250), dim3(256), 0, stream>>>(CTX16, WoT + wofs, bo + l*DM, Xb, (bf16*)nullptr, zp);

    ln384x<false,true><<<dim3(32000), dim3(384), 0, stream>>>(Xb, (float*)nullptr, Hb16, lnBw + l*DM, lnBb + l*DM);
    mfma_gemm<3,2><<<dim3(3,250), dim3(256), 0, stream>>>(Hb16, WaT + (size_t)l*3*DM*DM, biasA + l*DM, (float*)nullptr, G1, zp);
    mfma_gemm<3,1><<<dim3(3,250), dim3(256), 0, stream>>>(G1, WbT + (size_t)l*3*DM*DM, c1bb + l*DM, Xb, (bf16*)nullptr, zp);

    ln384x<false,true><<<dim3(32000), dim3(384), 0, stream>>>(Xb, (float*)nullptr, Hb16, lnCw + l*DM, lnCb + l*DM);
    transpose_ht<<<dim3(6,4,Bb), dim3(256), 0, stream>>>(Hb16, HTb);
    conv2_mfma<<<dim3(3,2,Bb), dim3(256), 0, stream>>>(HTb, W2T + (size_t)l*2*3*128*128, c2b + l*SEQ, Xb, zp);
  }

  ln384x<true,false><<<dim3(32000), dim3(384), 0, stream>>>(Xb, Hb, (bf16*)nullptr, ln2w, ln2b);
  final_kernel<<<dim3(Bb), dim3(384), 0, stream>>>(Hb, ln2w, ln2b, fcw, fcb, out);
}

// Round 7
// 3747.184 us; speedup vs baseline: 2.9752x; 1.0725x over previous
//
#include <hip/hip_runtime.h>
#include <hip/hip_bf16.h>
#include <cfloat>
#include <cstdint>

// ---------------- constants ----------------
static constexpr int Bb   = 128;
static constexpr int SEQ  = 250;
static constexpr int DM   = 384;
static constexpr int NH   = 8;
static constexpr int DHd  = 48;
static constexpr int HID  = 342;
static constexpr int UU   = 30;   // U == u == 30

using bf16 = __hip_bfloat16;
typedef __attribute__((ext_vector_type(8))) short bf16x8;
typedef __attribute__((ext_vector_type(4))) float f32x4;

// ---------------- threefry2x32 (JAX-exact) ----------------
__device__ __forceinline__ uint32_t rotl32(uint32_t x, int n){ return (x<<n)|(x>>(32-n)); }
#define TF_R(x0,x1,r) { x0 += x1; x1 = rotl32(x1,(r)); x1 ^= x0; }
__device__ inline void threefry(uint32_t k0, uint32_t k1, uint32_t x0, uint32_t x1,
                                uint32_t &o0, uint32_t &o1){
  uint32_t ks2 = k0 ^ k1 ^ 0x1BD11BDAu;
  x0 += k0; x1 += k1;
  TF_R(x0,x1,13) TF_R(x0,x1,15) TF_R(x0,x1,26) TF_R(x0,x1,6)
  x0 += k1; x1 += ks2 + 1u;
  TF_R(x0,x1,17) TF_R(x0,x1,29) TF_R(x0,x1,16) TF_R(x0,x1,24)
  x0 += ks2; x1 += k0 + 2u;
  TF_R(x0,x1,13) TF_R(x0,x1,15) TF_R(x0,x1,26) TF_R(x0,x1,6)
  x0 += k0; x1 += k1 + 3u;
  TF_R(x0,x1,17) TF_R(x0,x1,29) TF_R(x0,x1,16) TF_R(x0,x1,24)
  x0 += k1; x1 += ks2 + 4u;
  TF_R(x0,x1,13) TF_R(x0,x1,15) TF_R(x0,x1,26) TF_R(x0,x1,6)
  x0 += ks2; x1 += k0 + 5u;
  o0 = x0; o1 = x1;
}

__global__ void idx_kernel(int* __restrict__ IDX){
  int i = blockIdx.x*256 + threadIdx.x;
  if (i >= 4*7500) return;
  int l = i / 7500;
  int t = i % 7500;
  uint32_t fk0, fk1;
  threefry(0u, 42u, 0u, (uint32_t)l, fk0, fk1);
  uint32_t a0,a1,b0,b1;
  threefry(fk0, fk1, 0u, 2u, a0, a1);
  threefry(fk0, fk1, 1u, 3u, b0, b1);
  uint32_t c0 = (t < 3750) ? (uint32_t)t          : (uint32_t)(t-3750);
  uint32_t c1 = (t < 3750) ? (uint32_t)(t+3750)   : (uint32_t)t;
  uint32_t y0, y1, hi, lo;
  threefry(a0, b0, c0, c1, y0, y1); hi = (t < 3750) ? y0 : y1;
  threefry(a1, b1, c0, c1, y0, y1); lo = (t < 3750) ? y0 : y1;
  uint32_t val = ((hi % 250u) * 46u + (lo % 250u)) % 250u;
  IDX[i] = (int)val;
}

// ---------------- block reductions ----------------
__device__ __forceinline__ float block_sum(float v, float* red){
  v += __shfl_down(v,32); v += __shfl_down(v,16); v += __shfl_down(v,8);
  v += __shfl_down(v,4);  v += __shfl_down(v,2);  v += __shfl_down(v,1);
  int lane = threadIdx.x & 63, wid = threadIdx.x >> 6, nw = blockDim.x >> 6;
  __syncthreads();
  if (lane == 0) red[wid] = v;
  __syncthreads();
  float r = red[0];
  for (int i=1;i<nw;i++) r += red[i];
  return r;
}
__device__ __forceinline__ float block_max(float v, float* red){
  v = fmaxf(v, __shfl_down(v,32)); v = fmaxf(v, __shfl_down(v,16)); v = fmaxf(v, __shfl_down(v,8));
  v = fmaxf(v, __shfl_down(v,4));  v = fmaxf(v, __shfl_down(v,2));  v = fmaxf(v, __shfl_down(v,1));
  int lane = threadIdx.x & 63, wid = threadIdx.x >> 6, nw = blockDim.x >> 6;
  __syncthreads();
  if (lane == 0) red[wid] = v;
  __syncthreads();
  float r = red[0];
  for (int i=1;i<nw;i++) r = fmaxf(r, red[i]);
  return r;
}

__device__ __forceinline__ float gelu_tanh(float x){
  float t = 0.7978845608028654f * (x + 0.044715f * x * x * x);
  return 0.5f * x * (1.f + tanhf(t));
}

// ---------------- pool (max over 4) + LN + pos ----------------
__global__ __launch_bounds__(384) void pool_ln_pos(const float* __restrict__ xin,
    const float* __restrict__ pos, const float* __restrict__ w, const float* __restrict__ b,
    float* __restrict__ X){
  __shared__ float red[8];
  int bs = blockIdx.x; int bb = bs / SEQ, s = bs % SEQ; int d = threadIdx.x;
  const float* xp = xin + ((size_t)bb*1000 + (size_t)s*4)*DM + d;
  float v = fmaxf(fmaxf(xp[0], xp[DM]), fmaxf(xp[2*DM], xp[3*DM]));
  float mu = block_sum(v, red) * (1.f/DM);
  float diff = v - mu;
  float var = block_sum(diff*diff, red) * (1.f/DM);
  X[(size_t)bs*DM + d] = diff * rsqrtf(var + 1e-5f) * w[d] + b[d] + pos[(size_t)s*DM + d];
}

// ---------------- LayerNorm, optional f32/bf16 outputs ----------------
template<bool WF32, bool WB16>
__global__ __launch_bounds__(384) void ln384x(const float* __restrict__ in,
    float* __restrict__ o32, bf16* __restrict__ o16,
    const float* __restrict__ w, const float* __restrict__ b){
  __shared__ float red[8];
  size_t row = blockIdx.x; int d = threadIdx.x;
  float v = in[row*DM + d];
  float mu = block_sum(v, red) * (1.f/DM);
  float diff = v - mu;
  float var = block_sum(diff*diff, red) * (1.f/DM);
  float y = diff * rsqrtf(var + 1e-5f) * w[d] + b[d];
  if (WF32) o32[row*DM + d] = y;
  if (WB16) o16[row*DM + d] = __float2bfloat16(y);
}

// LayerNorm writing split hi/lo bf16 (for f32-accurate MFMA GEMM)
__global__ __launch_bounds__(384) void ln384hl(const float* __restrict__ in,
    bf16* __restrict__ ohi, bf16* __restrict__ olo,
    const float* __restrict__ w, const float* __restrict__ b){
  __shared__ float red[8];
  size_t row = blockIdx.x; int d = threadIdx.x;
  float v = in[row*DM + d];
  float mu = block_sum(v, red) * (1.f/DM);
  float diff = v - mu;
  float var = block_sum(diff*diff, red) * (1.f/DM);
  float y = diff * rsqrtf(var + 1e-5f) * w[d] + b[d];
  bf16 h = __float2bfloat16(y);
  ohi[row*DM + d] = h;
  olo[row*DM + d] = __float2bfloat16(y - __bfloat162float(h));
}

// ---------------- bf16 MFMA GEMM ----------------
__device__ __forceinline__ void gload16(const void* g, void* l){
  __builtin_amdgcn_global_load_lds(
      (__attribute__((address_space(1))) void*)(g),
      (__attribute__((address_space(3))) void*)(l), 16, 0, 0);
}

// C[M x 384] = sum_tap shift(A,tap-1) @ W_tap ; EPI: 0=store f32+bias 1=+= f32+bias 2=bf16 gelu store
template<int TAPS, int EPI>
__global__ __launch_bounds__(256) void mfma_gemm(
    const bf16* __restrict__ A, const bf16* __restrict__ WT,
    const float* __restrict__ bias, float* __restrict__ Cf, bf16* __restrict__ Cb,
    const bf16* __restrict__ zpage)
{
  __shared__ bf16 As[128*64];
  __shared__ bf16 Bs[128*64];
  const int tid = threadIdx.x;
  const int wid = tid >> 6, lane = tid & 63;
  const int wr = wid >> 1, wc = wid & 1;
  const int bm = blockIdx.y * 128;
  const int bn = blockIdx.x * 128;
  const int srow = lane >> 3;
  const int scol = (lane & 7) * 8;

  f32x4 acc[4][4] = {};
  const int NCH = TAPS * 6;
  for (int ck = 0; ck < NCH; ck++){
    const int tap = (TAPS == 3) ? (ck / 6) : 0;
    const int kk0 = (TAPS == 3) ? ((ck % 6) * 64) : (ck * 64);
    __syncthreads();
    #pragma unroll
    for (int s = 0; s < 4; s++){
      int row = wid*32 + s*8 + srow;
      int token = bm + row;
      const bf16* src;
      if (TAPS == 3){
        int l = token - (token/SEQ)*SEQ;
        int ls = l + tap - 1;
        bool valid = (ls >= 0) && (ls < SEQ);
        src = valid ? (A + (size_t)(token + tap - 1)*DM + kk0 + scol) : zpage;
      } else {
        src = A + (size_t)token*DM + kk0 + scol;
      }
      gload16(src, &As[(wid*32 + s*8)*64]);
    }
    #pragma unroll
    for (int s = 0; s < 4; s++){
      int row = wid*32 + s*8 + srow;
      const bf16* src = WT + ((size_t)(tap*DM + bn + row))*DM + kk0 + scol;
      gload16(src, &Bs[(wid*32 + s*8)*64]);
    }
    __syncthreads();
    #pragma unroll
    for (int ks = 0; ks < 2; ks++){
      bf16x8 af[4], bg[4];
      #pragma unroll
      for (int m = 0; m < 4; m++)
        af[m] = *(const bf16x8*)&As[(wr*64 + m*16 + (lane & 15))*64 + ks*32 + (lane >> 4)*8];
      #pragma unroll
      for (int n = 0; n < 4; n++)
        bg[n] = *(const bf16x8*)&Bs[(wc*64 + n*16 + (lane & 15))*64 + ks*32 + (lane >> 4)*8];
      #pragma unroll
      for (int m = 0; m < 4; m++)
        #pragma unroll
        for (int n = 0; n < 4; n++)
          acc[m][n] = __builtin_amdgcn_mfma_f32_16x16x32_bf16(af[m], bg[n], acc[m][n], 0, 0, 0);
    }
  }
  const int c_l = lane & 15, r4 = (lane >> 4) * 4;
  #pragma unroll
  for (int m = 0; m < 4; m++){
    #pragma unroll
    for (int n = 0; n < 4; n++){
      #pragma unroll
      for (int r = 0; r < 4; r++){
        int token = bm + wr*64 + m*16 + r4 + r;
        int col   = bn + wc*64 + n*16 + c_l;
        float v = acc[m][n][r] + bias[col];
        if (EPI == 0)      Cf[(size_t)token*DM + col] = v;
        else if (EPI == 1) Cf[(size_t)token*DM + col] += v;
        else               Cb[(size_t)token*DM + col] = __float2bfloat16(gelu_tanh(v));
      }
    }
  }
}

// split-bf16 f32-accurate GEMM: C = Ahi@Whi + Ahi@Wlo + Alo@Whi + bias (f32 out)
__global__ __launch_bounds__(256) void mfma_qk(
    const bf16* __restrict__ Ahi, const bf16* __restrict__ Alo,
    const bf16* __restrict__ WT, const float* __restrict__ bias, float* __restrict__ C)
{
  __shared__ bf16 As[128*64];
  __shared__ bf16 Bs[128*64];
  const int tid = threadIdx.x;
  const int wid = tid >> 6, lane = tid & 63;
  const int wr = wid >> 1, wc = wid & 1;
  const int bm = blockIdx.y * 128;
  const int bn = blockIdx.x * 128;
  const int srow = lane >> 3;
  const int scol = (lane & 7) * 8;

  f32x4 acc[4][4] = {};
  for (int ck = 0; ck < 18; ck++){
    const int p   = ck / 6;              // pass: 0=hi*hi 1=hi*lo 2=lo*hi
    const int kk0 = (ck % 6) * 64;
    const bf16* Asrc = (p < 2) ? Ahi : Alo;
    const bf16* Wsrc = WT + ((p == 1) ? (size_t)DM*DM : 0);
    __syncthreads();
    #pragma unroll
    for (int s = 0; s < 4; s++){
      int row = wid*32 + s*8 + srow;
      gload16(Asrc + (size_t)(bm + row)*DM + kk0 + scol, &As[(wid*32 + s*8)*64]);
    }
    #pragma unroll
    for (int s = 0; s < 4; s++){
      int row = wid*32 + s*8 + srow;
      gload16(Wsrc + (size_t)(bn + row)*DM + kk0 + scol, &Bs[(wid*32 + s*8)*64]);
    }
    __syncthreads();
    #pragma unroll
    for (int ks = 0; ks < 2; ks++){
      bf16x8 af[4], bg[4];
      #pragma unroll
      for (int m = 0; m < 4; m++)
        af[m] = *(const bf16x8*)&As[(wr*64 + m*16 + (lane & 15))*64 + ks*32 + (lane >> 4)*8];
      #pragma unroll
      for (int n = 0; n < 4; n++)
        bg[n] = *(const bf16x8*)&Bs[(wc*64 + n*16 + (lane & 15))*64 + ks*32 + (lane >> 4)*8];
      #pragma unroll
      for (int m = 0; m < 4; m++)
        #pragma unroll
        for (int n = 0; n < 4; n++)
          acc[m][n] = __builtin_amdgcn_mfma_f32_16x16x32_bf16(af[m], bg[n], acc[m][n], 0, 0, 0);
    }
  }
  const int c_l = lane & 15, r4 = (lane >> 4) * 4;
  #pragma unroll
  for (int m = 0; m < 4; m++)
    #pragma unroll
    for (int n = 0; n < 4; n++)
      #pragma unroll
      for (int r = 0; r < 4; r++){
        int token = bm + wr*64 + m*16 + r4 + r;
        int col   = bn + wc*64 + n*16 + c_l;
        C[(size_t)token*DM + col] = acc[m][n][r] + bias[col];
      }
}

// ---------------- conv2 as MFMA ----------------
__global__ __launch_bounds__(256) void conv2_mfma(
    const bf16* __restrict__ HT, const bf16* __restrict__ W2T,
    const float* __restrict__ bias, float* __restrict__ X,
    const bf16* __restrict__ zpage)
{
  __shared__ bf16 As[128*64];
  __shared__ bf16 Bs[128*64];
  const int tid = threadIdx.x;
  const int wid = tid >> 6, lane = tid & 63;
  const int wr = wid >> 1, wc = wid & 1;
  const int bn = blockIdx.x * 128;
  const int g  = blockIdx.y;
  const int b  = blockIdx.z;
  const int srow = lane >> 3;
  const int scol = (lane & 7) * 8;
  const bf16* Wbase = W2T + (size_t)g*3*128*128;

  f32x4 acc[4][4] = {};
  for (int ck = 0; ck < 6; ck++){
    const int tap = ck >> 1;
    const int kk0 = (ck & 1) * 64;
    __syncthreads();
    #pragma unroll
    for (int s = 0; s < 4; s++){
      int row = wid*32 + s*8 + srow;
      gload16(Wbase + ((size_t)tap*128 + row)*128 + kk0 + scol, &As[(wid*32 + s*8)*64]);
    }
    #pragma unroll
    for (int s = 0; s < 4; s++){
      int row = wid*32 + s*8 + srow;
      int sd = bn + row + tap - 1;
      const bf16* src = (sd >= 0 && sd < DM)
        ? (HT + (((size_t)b*DM + sd)*2 + g)*128 + kk0 + scol) : zpage;
      gload16(src, &Bs[(wid*32 + s*8)*64]);
    }
    __syncthreads();
    #pragma unroll
    for (int ks = 0; ks < 2; ks++){
      bf16x8 af[4], bg[4];
      #pragma unroll
      for (int m = 0; m < 4; m++)
        af[m] = *(const bf16x8*)&As[(wr*64 + m*16 + (lane & 15))*64 + ks*32 + (lane >> 4)*8];
      #pragma unroll
      for (int n = 0; n < 4; n++)
        bg[n] = *(const bf16x8*)&Bs[(wc*64 + n*16 + (lane & 15))*64 + ks*32 + (lane >> 4)*8];
      #pragma unroll
      for (int m = 0; m < 4; m++)
        #pragma unroll
        for (int n = 0; n < 4; n++)
          acc[m][n] = __builtin_amdgcn_mfma_f32_16x16x32_bf16(af[m], bg[n], acc[m][n], 0, 0, 0);
    }
  }
  const int c_l = lane & 15, r4 = (lane >> 4) * 4;
  #pragma unroll
  for (int m = 0; m < 4; m++){
    #pragma unroll
    for (int n = 0; n < 4; n++){
      #pragma unroll
      for (int r = 0; r < 4; r++){
        int lo = wr*64 + m*16 + r4 + r;
        if (lo < 125){
          int d = bn + wc*64 + n*16 + c_l;
          float v = acc[m][n][r] + bias[g*125 + lo];
          X[((size_t)b*SEQ + g*125 + lo)*DM + d] += gelu_tanh(v);
        }
      }
    }
  }
}

// ---------------- transpose H[b][l][d] bf16 -> HT[b][d][g*128+li] bf16 ----------------
__global__ __launch_bounds__(256) void transpose_ht(const bf16* __restrict__ H,
                                                    bf16* __restrict__ HT){
  __shared__ bf16 t[68][66];
  int d0 = blockIdx.x * 64;
  int p0 = blockIdx.y * 64;
  int b  = blockIdx.z;
  int tid = threadIdx.x;
  int l0 = p0 - 3;
  for (int i = tid; i < 68*64; i += 256){
    int r = i >> 6, c = i & 63;
    int l = l0 + r;
    bf16 v = __float2bfloat16(0.f);
    if (l >= 0 && l < SEQ) v = H[((size_t)b*SEQ + l)*DM + d0 + c];
    t[r][c] = v;
  }
  __syncthreads();
  for (int i = tid; i < 64*64; i += 256){
    int rr = i >> 6, cc = i & 63;
    int p = p0 + cc;
    int gg = p >> 7, li = p & 127;
    int l = gg*125 + li;
    bf16 v = __float2bfloat16(0.f);
    if (li < 125 && l < SEQ) v = t[l - l0][rr];
    HT[((size_t)b*DM + d0 + rr)*256 + p] = v;
  }
}

// ---------------- weight prep ----------------
__global__ void zfill(bf16* z){ z[threadIdx.x] = __float2bfloat16(0.f); }

__global__ __launch_bounds__(256) void build_projT(const float* __restrict__ Wv,
    const float* __restrict__ Wo, bf16* __restrict__ WvT, bf16* __restrict__ WoT){
  __shared__ float t[32][33];
  int mat = blockIdx.z;
  const float* W = (mat < 4) ? (Wv + (size_t)mat*DM*DM) : (Wo + (size_t)(mat-4)*DM*DM);
  bf16* WT = (mat < 4) ? (WvT + (size_t)mat*DM*DM) : (WoT + (size_t)(mat-4)*DM*DM);
  int k0 = blockIdx.y*32, n0 = blockIdx.x*32;
  int tx = threadIdx.x & 31, ty = threadIdx.x >> 5;
  #pragma unroll
  for (int r = 0; r < 32; r += 8)
    t[ty + r][tx] = W[(size_t)(k0 + ty + r)*DM + n0 + tx];
  __syncthreads();
  #pragma unroll
  for (int r = 0; r < 32; r += 8)
    WT[(size_t)(n0 + ty + r)*DM + k0 + tx] = __float2bfloat16(t[tx][ty + r]);
}

__global__ __launch_bounds__(256) void build_qkhl(const float* __restrict__ Wq,
    const float* __restrict__ Wk, bf16* __restrict__ WT){
  __shared__ float t[32][33];
  int mat = blockIdx.z;
  const float* W = (mat < 4) ? (Wq + (size_t)mat*DM*DM) : (Wk + (size_t)(mat-4)*DM*DM);
  bf16* hi = WT + (size_t)mat*2*DM*DM;
  bf16* lo = hi + (size_t)DM*DM;
  int k0 = blockIdx.y*32, n0 = blockIdx.x*32;
  int tx = threadIdx.x & 31, ty = threadIdx.x >> 5;
  #pragma unroll
  for (int r = 0; r < 32; r += 8)
    t[ty + r][tx] = W[(size_t)(k0 + ty + r)*DM + n0 + tx];
  __syncthreads();
  #pragma unroll
  for (int r = 0; r < 32; r += 8){
    float w = t[tx][ty + r];
    bf16 h = __float2bfloat16(w);
    hi[(size_t)(n0 + ty + r)*DM + k0 + tx] = h;
    lo[(size_t)(n0 + ty + r)*DM + k0 + tx] = __float2bfloat16(w - __bfloat162float(h));
  }
}

__global__ void build_c1aT(const float* __restrict__ W, const float* __restrict__ bin,
                           bf16* __restrict__ WT, float* __restrict__ bias_pad){
  int i = blockIdx.x*256 + threadIdx.x;
  if (i < 4*DM){
    int l = i/DM, n = i%DM;
    bias_pad[i] = (n < HID) ? bin[l*HID + n] : 0.f;
  }
  if (i >= 4*3*DM*DM) return;
  int k = i % DM; int n = (i/DM) % DM; int t = (i/(DM*DM)) % 3; int l = i/(3*DM*DM);
  float v = 0.f;
  if (n < HID){
    int g = n / 114; int ci = k - g*128;
    if (ci >= 0 && ci < 128)
      v = W[(((size_t)l*HID + n)*128 + ci)*3 + t];
  }
  WT[i] = __float2bfloat16(v);
}

__global__ void build_c1bT(const float* __restrict__ W, bf16* __restrict__ WT){
  int i = blockIdx.x*256 + threadIdx.x;
  if (i >= 4*3*DM*DM) return;
  int k = i % DM; int n = (i/DM) % DM; int t = (i/(DM*DM)) % 3; int l = i/(3*DM*DM);
  int g = n >> 7; int ci = k - g*114;
  float v = 0.f;
  if (ci >= 0 && ci < 114)
    v = W[(((size_t)l*DM + n)*114 + ci)*3 + t];
  WT[i] = __float2bfloat16(v);
}

__global__ void build_c2T(const float* __restrict__ W, bf16* __restrict__ WT){
  int i = blockIdx.x*256 + threadIdx.x;
  if (i >= 4*2*3*128*128) return;
  int li = i & 127;
  int lo = (i >> 7) & 127;
  int t  = (i / 16384) % 3;
  int g  = (i / 49152) % 2;
  int l  = i / 98304;
  float v = 0.f;
  if (lo < 125 && li < 125)
    v = W[(((size_t)l*SEQ + g*125 + lo)*125 + li)*3 + t];
  WT[i] = __float2bfloat16(v);
}

// ---------------- fused probe + top-k: one block per (b,h) ----------------
__global__ __launch_bounds__(256) void probe_topk(const float* __restrict__ Q,
    const float* __restrict__ K, const int* __restrict__ idx, int* __restrict__ TOP){
  __shared__ float Ksh[SEQ*49];
  __shared__ float s_redv[4];
  __shared__ int   s_redi[4];
  __shared__ int   s_win;
  int bh = blockIdx.x; int h = bh & 7; int b = bh >> 3;
  int tid = threadIdx.x;
  for (int i = tid; i < SEQ*DHd; i += 256){
    int r = i / DHd, c = i - r*DHd;
    Ksh[r*49 + c] = K[((size_t)(b*SEQ + r))*DM + h*DHd + c];
  }
  __syncthreads();
  int l = tid;
  float Mv = -FLT_MAX;
  if (l < SEQ){
    float qr[DHd];
    const float* qp = Q + ((size_t)(b*SEQ + l))*DM + h*DHd;
    #pragma unroll
    for (int z = 0; z < DHd; z++) qr[z] = qp[z];
    const int* ip = idx + l*UU;
    float mx = -FLT_MAX, sm = 0.f;
    for (int u = 0; u < UU; u++){
      int base = ip[u]*49;
      float d = 0.f;
      #pragma unroll
      for (int z = 0; z < DHd; z++) d += qr[z]*Ksh[base + z];
      mx = fmaxf(mx, d); sm += d;
    }
    Mv = mx - sm*(1.f/UU);
  }
  int myid = (l < SEQ) ? l : (1<<30);
  int lane = tid & 63, wid = tid >> 6;
  for (int sel = 0; sel < UU; sel++){
    float bv = Mv; int bi = myid;
    #pragma unroll
    for (int off = 32; off; off >>= 1){
      float ov = __shfl_xor(bv, off);
      int   oi = __shfl_xor(bi, off);
      if (ov > bv || (ov == bv && oi < bi)){ bv = ov; bi = oi; }
    }
    if (lane == 0){ s_redv[wid] = bv; s_redi[wid] = bi; }
    __syncthreads();
    if (tid == 0){
      float wv = s_redv[0]; int wi = s_redi[0];
      #pragma unroll
      for (int q = 1; q < 4; q++)
        if (s_redv[q] > wv || (s_redv[q] == wv && s_redi[q] < wi)){ wv = s_redv[q]; wi = s_redi[q]; }
      TOP[(size_t)bh*UU + sel] = wi;
      s_win = wi;
    }
    __syncthreads();
    if (myid == s_win) Mv = -FLT_MAX;
  }
}

// ---------------- fused attention context per (b,h), u-groups of 10 ----------------
static constexpr int UG = 10;   // u's per pass (30 = 3 passes)
__global__ __launch_bounds__(256) void attn_ctx2(const float* __restrict__ Q,
    const float* __restrict__ K, const float* __restrict__ V,
    const int* __restrict__ TOP, bf16* __restrict__ CTX){
  __shared__ float Ksh[SEQ*49];       // 49000 B
  __shared__ float qsh[UG][DHd];      // 1920 B (pre-scaled by 1/sqrt(48))
  __shared__ float psh[UG][SEQ];      // 10000 B
  __shared__ float invsh[UG];
  __shared__ float part[UG][5][DHd];  // 9600 B
  __shared__ float vmean[DHd];
  __shared__ float red[8];
  __shared__ int   mark[SEQ];
  int bh = blockIdx.x; int h = bh & 7; int b = bh >> 3;
  int tid = threadIdx.x;
  const size_t base = (size_t)b*SEQ*DM + h*DHd;
  // stage K, init mark
  for (int i = tid; i < SEQ*DHd; i += 256){
    int r = i / DHd, c = i - r*DHd;
    Ksh[r*49 + c] = K[base + (size_t)r*DM + c];
  }
  for (int i = tid; i < SEQ; i += 256) mark[i] = -1;
  __syncthreads();
  if (tid < UU) mark[TOP[(size_t)bh*UU + tid]] = tid;
  // vmean (uses part[0])
  {
    if (tid < 240){
      int dh = tid % DHd, pr = tid / DHd;
      float s = 0.f;
      for (int j = pr*50; j < pr*50+50; j++) s += V[base + (size_t)j*DM + dh];
      part[0][pr][dh] = s;
    }
    __syncthreads();
    if (tid < DHd)
      vmean[tid] = (part[0][0][tid]+part[0][1][tid]+part[0][2][tid]+part[0][3][tid]+part[0][4][tid]) * (1.f/SEQ);
    __syncthreads();
  }
  // 3 passes of 10 u's
  for (int u0 = 0; u0 < UU; u0 += UG){
    for (int i = tid; i < UG*DHd; i += 256){
      int uu = i / DHd, z = i - uu*DHd;
      int l0 = TOP[(size_t)bh*UU + u0 + uu];
      qsh[uu][z] = Q[(size_t)(b*SEQ + l0)*DM + h*DHd + z] * 0.14433756729740643f;  // 1/sqrt(48)
    }
    __syncthreads();
    // scores: thread j computes 10 dots from LDS K
    float s[UG];
    #pragma unroll
    for (int u = 0; u < UG; u++) s[u] = -FLT_MAX;
    if (tid < SEQ){
      #pragma unroll
      for (int u = 0; u < UG; u++) s[u] = 0.f;
      for (int z = 0; z < DHd; z++){
        float kv = Ksh[tid*49 + z];
        #pragma unroll
        for (int u = 0; u < UG; u++) s[u] = fmaf(qsh[u][z], kv, s[u]);
      }
    }
    // per-u softmax
    #pragma unroll
    for (int u = 0; u < UG; u++){
      float mx = block_max(s[u], red);
      float e = (tid < SEQ) ? expf(s[u] - mx) : 0.f;
      if (tid < SEQ) psh[u][tid] = e;
      float sm = block_sum(e, red);
      if (tid == 0) invsh[u] = 1.f / sm;
    }
    __syncthreads();
    // PV: thread (dh,pr) reads each V element once, 10 FMAs from broadcast psh
    if (tid < 240){
      int dh = tid % DHd, pr = tid / DHd;
      float a[UG];
      #pragma unroll
      for (int u = 0; u < UG; u++) a[u] = 0.f;
      for (int j = pr*50; j < pr*50+50; j++){
        float vv = V[base + (size_t)j*DM + dh];
        #pragma unroll
        for (int u = 0; u < UG; u++) a[u] = fmaf(psh[u][j], vv, a[u]);
      }
      #pragma unroll
      for (int u = 0; u < UG; u++) part[u][pr][dh] = a[u];
    }
    __syncthreads();
    // reduce partials + write CTX rows (480 outputs -> 2 rounds of 240)
    for (int i = tid; i < UG*DHd; i += 256){
      int uu = i / DHd, dh = i - uu*DHd;
      float acc = (part[uu][0][dh]+part[uu][1][dh]+part[uu][2][dh]+part[uu][3][dh]+part[uu][4][dh]) * invsh[uu];
      int l0 = TOP[(size_t)bh*UU + u0 + uu];
      CTX[(size_t)(b*SEQ + l0)*DM + h*DHd + dh] = __float2bfloat16(acc);
    }
    __syncthreads();
  }
  // fill non-top rows with vmean
  for (int i = tid; i < SEQ*DHd; i += 256){
    int l = i / DHd, dh = i - l*DHd;
    if (mark[l] < 0)
      CTX[(size_t)(b*SEQ + l)*DM + h*DHd + dh] = __float2bfloat16(vmean[dh]);
  }
}

// ---------------- final: max over L -> LN(ln2) -> FC ----------------
__global__ __launch_bounds__(384) void final_kernel(const float* __restrict__ Hin,
    const float* __restrict__ w, const float* __restrict__ bparm,
    const float* __restrict__ fcw, const float* __restrict__ fcb, float* __restrict__ out){
  __shared__ float red[8];
  __shared__ float ybuf[DM];
  int b = blockIdx.x; int d = threadIdx.x;
  const float* hp = Hin + (size_t)b*SEQ*DM + d;
  float mx = -FLT_MAX;
  for (int l=0;l<SEQ;l++) mx = fmaxf(mx, hp[(size_t)l*DM]);
  float mu = block_sum(mx, red) * (1.f/DM);
  float diff = mx - mu;
  float var = block_sum(diff*diff, red) * (1.f/DM);
  float y = diff * rsqrtf(var + 1e-5f) * w[d] + bparm[d];
  ybuf[d] = y;
  __syncthreads();
  if (d < 10){
    float acc = fcb[d];
    for (int k=0;k<DM;k++) acc += ybuf[k] * fcw[k*10 + d];
    out[b*10 + d] = acc;
  }
}

// ---------------- host orchestration ----------------
extern "C" void kernel_launch(void* const* d_in, const int* in_sizes, int n_in,
                              void* d_out, int out_size, void* d_ws, size_t ws_size,
                              hipStream_t stream) {
  const float* x     = (const float*)d_in[0];
  const float* pos   = (const float*)d_in[1];
  const float* lniw  = (const float*)d_in[2];
  const float* lnib  = (const float*)d_in[3];
  const float* lnAw  = (const float*)d_in[4];
  const float* lnAb  = (const float*)d_in[5];
  const float* Wq    = (const float*)d_in[6];
  const float* bq    = (const float*)d_in[7];
  const float* Wk    = (const float*)d_in[8];
  const float* bk    = (const float*)d_in[9];
  const float* Wv    = (const float*)d_in[10];
  const float* bv    = (const float*)d_in[11];
  const float* Wo    = (const float*)d_in[12];
  const float* bo    = (const float*)d_in[13];
  const float* lnBw  = (const float*)d_in[14];
  const float* lnBb  = (const float*)d_in[15];
  const float* c1aw  = (const float*)d_in[16];
  const float* c1ab  = (const float*)d_in[17];
  const float* c1bw  = (const float*)d_in[18];
  const float* c1bb  = (const float*)d_in[19];
  const float* lnCw  = (const float*)d_in[20];
  const float* lnCb  = (const float*)d_in[21];
  const float* c2w   = (const float*)d_in[22];
  const float* c2b   = (const float*)d_in[23];
  const float* ln2w  = (const float*)d_in[24];
  const float* ln2b  = (const float*)d_in[25];
  const float* fcw   = (const float*)d_in[26];
  const float* fcb   = (const float*)d_in[27];
  float* out = (float*)d_out;

  const size_t ACT  = (size_t)Bb*SEQ*DM;        // 12,288,000
  float* Xb  = (float*)d_ws;
  float* Hb  = Xb  + ACT;                       // f32 for final LN; aliased as Alo bf16 early
  float* Qb  = Hb  + ACT;                       // aliased as HT bf16 in conv2 phase
  float* Kb  = Qb  + ACT;
  float* Vb  = Kb  + ACT;
  float* biasA = Vb + ACT;
  int*   TOP = (int*)(biasA + 4*DM);
  int*   IDX = TOP + (size_t)Bb*NH*UU;
  bf16*  Hb16 = (bf16*)(IDX + 4*7500);          // Ahi / CTX16 / conv input
  bf16*  G1   = Hb16 + ACT;
  bf16*  WvT  = G1   + ACT;
  bf16*  WoT  = WvT  + (size_t)4*DM*DM;
  bf16*  WaT  = WoT  + (size_t)4*DM*DM;
  bf16*  WbT  = WaT  + (size_t)12*DM*DM;
  bf16*  WqkT = WbT  + (size_t)12*DM*DM;        // [8][2][384][384]
  bf16*  W2T  = WqkT + (size_t)16*DM*DM;        // [4][2][3][128][128]
  bf16*  zp   = W2T  + (size_t)4*2*3*128*128;

  zfill<<<dim3(1), dim3(256), 0, stream>>>(zp);
  idx_kernel<<<dim3(118), dim3(256), 0, stream>>>(IDX);
  build_projT<<<dim3(12,12,8), dim3(256), 0, stream>>>(Wv, Wo, WvT, WoT);
  build_qkhl<<<dim3(12,12,8), dim3(256), 0, stream>>>(Wq, Wk, WqkT);
  build_c1aT<<<dim3(6912), dim3(256), 0, stream>>>(c1aw, c1ab, WaT, biasA);
  build_c1bT<<<dim3(6912), dim3(256), 0, stream>>>(c1bw, WbT);
  build_c2T<<<dim3(1536), dim3(256), 0, stream>>>(c2w, W2T);
  pool_ln_pos<<<dim3(32000), dim3(384), 0, stream>>>(x, pos, lniw, lnib, Xb);

  for (int l = 0; l < 4; l++){
    const size_t wofs = (size_t)l*DM*DM;
    bf16* Alo16 = (bf16*)Hb;          // alias: Hb f32 unused until final LN
    bf16* CTX16 = Hb16;               // reuse after V-proj
    bf16* HTb   = (bf16*)Qb;          // alias: Qb dead after attention
    ln384hl<<<dim3(32000), dim3(384), 0, stream>>>(Xb, Hb16, Alo16, lnAw + l*DM, lnAb + l*DM);
    mfma_qk<<<dim3(3,250), dim3(256), 0, stream>>>(Hb16, Alo16, WqkT + (size_t)l*2*DM*DM, bq + l*DM, Qb);
    mfma_qk<<<dim3(3,250), dim3(256), 0, stream>>>(Hb16, Alo16, WqkT + (size_t)(4+l)*2*DM*DM, bk + l*DM, Kb);
    mfma_gemm<1,0><<<dim3(3,250), dim3(256), 0, stream>>>(Hb16, WvT + wofs, bv + l*DM, Vb, (bf16*)nullptr, zp);
    probe_topk<<<dim3(Bb*NH), dim3(256), 0, stream>>>(Qb, Kb, IDX + l*7500, TOP);
    attn_ctx2<<<dim3(Bb*NH), dim3(256), 0, stream>>>(Qb, Kb, Vb, TOP, CTX16);
    mfma_gemm<1,1><<<dim3(3,250), dim3(256), 0, stream>>>(CTX16, WoT + wofs, bo + l*DM, Xb, (bf16*)nullptr, zp);

    ln384x<false,true><<<dim3(32000), dim3(384), 0, stream>>>(Xb, (float*)nullptr, Hb16, lnBw + l*DM, lnBb + l*DM);
    mfma_gemm<3,2><<<dim3(3,250), dim3(256), 0, stream>>>(Hb16, WaT + (size_t)l*3*DM*DM, biasA + l*DM, (float*)nullptr, G1, zp);
    mfma_gemm<3,1><<<dim3(3,250), dim3(256), 0, stream>>>(G1, WbT + (size_t)l*3*DM*DM, c1bb + l*DM, Xb, (bf16*)nullptr, zp);

    ln384x<false,true><<<dim3(32000), dim3(384), 0, stream>>>(Xb, (float*)nullptr, Hb16, lnCw + l*DM, lnCb + l*DM);
    transpose_ht<<<dim3(6,4,Bb), dim3(256), 0, stream>>>(Hb16, HTb);
    conv2_mfma<<<dim3(3,2,Bb), dim3(256), 0, stream>>>(HTb, W2T + (size_t)l*2*3*128*128, c2b + l*SEQ, Xb, zp);
  }

  ln384x<true,false><<<dim3(32000), dim3(384), 0, stream>>>(Xb, Hb, (bf16*)nullptr, ln2w, ln2b);
  final_kernel<<<dim3(Bb), dim3(384), 0, stream>>>(Hb, ln2w, ln2b, fcw, fcb, out);
}

// Round 8
// 3698.503 us; speedup vs baseline: 3.0143x; 1.0132x over previous
//
#include <hip/hip_runtime.h>
#include <hip/hip_bf16.h>
#include <cfloat>
#include <cstdint>

// ---------------- constants ----------------
static constexpr int Bb   = 128;
static constexpr int SEQ  = 250;
static constexpr int DM   = 384;
static constexpr int NH   = 8;
static constexpr int DHd  = 48;
static constexpr int HID  = 342;
static constexpr int UU   = 30;   // U == u == 30

using bf16 = __hip_bfloat16;
typedef __attribute__((ext_vector_type(8))) short bf16x8;
typedef __attribute__((ext_vector_type(4))) float f32x4;

// ---------------- threefry2x32 (JAX-exact) ----------------
__device__ __forceinline__ uint32_t rotl32(uint32_t x, int n){ return (x<<n)|(x>>(32-n)); }
#define TF_R(x0,x1,r) { x0 += x1; x1 = rotl32(x1,(r)); x1 ^= x0; }
__device__ inline void threefry(uint32_t k0, uint32_t k1, uint32_t x0, uint32_t x1,
                                uint32_t &o0, uint32_t &o1){
  uint32_t ks2 = k0 ^ k1 ^ 0x1BD11BDAu;
  x0 += k0; x1 += k1;
  TF_R(x0,x1,13) TF_R(x0,x1,15) TF_R(x0,x1,26) TF_R(x0,x1,6)
  x0 += k1; x1 += ks2 + 1u;
  TF_R(x0,x1,17) TF_R(x0,x1,29) TF_R(x0,x1,16) TF_R(x0,x1,24)
  x0 += ks2; x1 += k0 + 2u;
  TF_R(x0,x1,13) TF_R(x0,x1,15) TF_R(x0,x1,26) TF_R(x0,x1,6)
  x0 += k0; x1 += k1 + 3u;
  TF_R(x0,x1,17) TF_R(x0,x1,29) TF_R(x0,x1,16) TF_R(x0,x1,24)
  x0 += k1; x1 += ks2 + 4u;
  TF_R(x0,x1,13) TF_R(x0,x1,15) TF_R(x0,x1,26) TF_R(x0,x1,6)
  x0 += ks2; x1 += k0 + 5u;
  o0 = x0; o1 = x1;
}

__global__ void idx_kernel(int* __restrict__ IDX){
  int i = blockIdx.x*256 + threadIdx.x;
  if (i >= 4*7500) return;
  int l = i / 7500;
  int t = i % 7500;
  uint32_t fk0, fk1;
  threefry(0u, 42u, 0u, (uint32_t)l, fk0, fk1);
  uint32_t a0,a1,b0,b1;
  threefry(fk0, fk1, 0u, 2u, a0, a1);
  threefry(fk0, fk1, 1u, 3u, b0, b1);
  uint32_t c0 = (t < 3750) ? (uint32_t)t          : (uint32_t)(t-3750);
  uint32_t c1 = (t < 3750) ? (uint32_t)(t+3750)   : (uint32_t)t;
  uint32_t y0, y1, hi, lo;
  threefry(a0, b0, c0, c1, y0, y1); hi = (t < 3750) ? y0 : y1;
  threefry(a1, b1, c0, c1, y0, y1); lo = (t < 3750) ? y0 : y1;
  uint32_t val = ((hi % 250u) * 46u + (lo % 250u)) % 250u;
  IDX[i] = (int)val;
}

// ---------------- block reductions ----------------
__device__ __forceinline__ float block_sum(float v, float* red){
  v += __shfl_down(v,32); v += __shfl_down(v,16); v += __shfl_down(v,8);
  v += __shfl_down(v,4);  v += __shfl_down(v,2);  v += __shfl_down(v,1);
  int lane = threadIdx.x & 63, wid = threadIdx.x >> 6, nw = blockDim.x >> 6;
  __syncthreads();
  if (lane == 0) red[wid] = v;
  __syncthreads();
  float r = red[0];
  for (int i=1;i<nw;i++) r += red[i];
  return r;
}
__device__ __forceinline__ float block_max(float v, float* red){
  v = fmaxf(v, __shfl_down(v,32)); v = fmaxf(v, __shfl_down(v,16)); v = fmaxf(v, __shfl_down(v,8));
  v = fmaxf(v, __shfl_down(v,4));  v = fmaxf(v, __shfl_down(v,2));  v = fmaxf(v, __shfl_down(v,1));
  int lane = threadIdx.x & 63, wid = threadIdx.x >> 6, nw = blockDim.x >> 6;
  __syncthreads();
  if (lane == 0) red[wid] = v;
  __syncthreads();
  float r = red[0];
  for (int i=1;i<nw;i++) r = fmaxf(r, red[i]);
  return r;
}

__device__ __forceinline__ float gelu_tanh(float x){
  float t = 0.7978845608028654f * (x + 0.044715f * x * x * x);
  return 0.5f * x * (1.f + tanhf(t));
}

// ---------------- pool (max over 4) + LN + pos ----------------
__global__ __launch_bounds__(384) void pool_ln_pos(const float* __restrict__ xin,
    const float* __restrict__ pos, const float* __restrict__ w, const float* __restrict__ b,
    float* __restrict__ X){
  __shared__ float red[8];
  int bs = blockIdx.x; int bb = bs / SEQ, s = bs % SEQ; int d = threadIdx.x;
  const float* xp = xin + ((size_t)bb*1000 + (size_t)s*4)*DM + d;
  float v = fmaxf(fmaxf(xp[0], xp[DM]), fmaxf(xp[2*DM], xp[3*DM]));
  float mu = block_sum(v, red) * (1.f/DM);
  float diff = v - mu;
  float var = block_sum(diff*diff, red) * (1.f/DM);
  X[(size_t)bs*DM + d] = diff * rsqrtf(var + 1e-5f) * w[d] + b[d] + pos[(size_t)s*DM + d];
}

// ---------------- LayerNorm, optional f32/bf16 outputs ----------------
template<bool WF32, bool WB16>
__global__ __launch_bounds__(384) void ln384x(const float* __restrict__ in,
    float* __restrict__ o32, bf16* __restrict__ o16,
    const float* __restrict__ w, const float* __restrict__ b){
  __shared__ float red[8];
  size_t row = blockIdx.x; int d = threadIdx.x;
  float v = in[row*DM + d];
  float mu = block_sum(v, red) * (1.f/DM);
  float diff = v - mu;
  float var = block_sum(diff*diff, red) * (1.f/DM);
  float y = diff * rsqrtf(var + 1e-5f) * w[d] + b[d];
  if (WF32) o32[row*DM + d] = y;
  if (WB16) o16[row*DM + d] = __float2bfloat16(y);
}

// LayerNorm writing split hi/lo bf16 (for f32-accurate MFMA GEMM)
__global__ __launch_bounds__(384) void ln384hl(const float* __restrict__ in,
    bf16* __restrict__ ohi, bf16* __restrict__ olo,
    const float* __restrict__ w, const float* __restrict__ b){
  __shared__ float red[8];
  size_t row = blockIdx.x; int d = threadIdx.x;
  float v = in[row*DM + d];
  float mu = block_sum(v, red) * (1.f/DM);
  float diff = v - mu;
  float var = block_sum(diff*diff, red) * (1.f/DM);
  float y = diff * rsqrtf(var + 1e-5f) * w[d] + b[d];
  bf16 h = __float2bfloat16(y);
  ohi[row*DM + d] = h;
  olo[row*DM + d] = __float2bfloat16(y - __bfloat162float(h));
}

// ---------------- bf16 MFMA GEMM ----------------
__device__ __forceinline__ void gload16(const void* g, void* l){
  __builtin_amdgcn_global_load_lds(
      (__attribute__((address_space(1))) void*)(g),
      (__attribute__((address_space(3))) void*)(l), 16, 0, 0);
}

// C[M x 384] = sum_tap shift(A,tap-1) @ W_tap ; EPI: 0=store f32+bias 1=+= f32+bias 2=bf16 gelu store
template<int TAPS, int EPI>
__global__ __launch_bounds__(256) void mfma_gemm(
    const bf16* __restrict__ A, const bf16* __restrict__ WT,
    const float* __restrict__ bias, float* __restrict__ Cf, bf16* __restrict__ Cb,
    const bf16* __restrict__ zpage)
{
  __shared__ bf16 As[128*64];
  __shared__ bf16 Bs[128*64];
  const int tid = threadIdx.x;
  const int wid = tid >> 6, lane = tid & 63;
  const int wr = wid >> 1, wc = wid & 1;
  const int bm = blockIdx.y * 128;
  const int bn = blockIdx.x * 128;
  const int srow = lane >> 3;
  const int scol = (lane & 7) * 8;

  f32x4 acc[4][4] = {};
  const int NCH = TAPS * 6;
  for (int ck = 0; ck < NCH; ck++){
    const int tap = (TAPS == 3) ? (ck / 6) : 0;
    const int kk0 = (TAPS == 3) ? ((ck % 6) * 64) : (ck * 64);
    __syncthreads();
    #pragma unroll
    for (int s = 0; s < 4; s++){
      int row = wid*32 + s*8 + srow;
      int token = bm + row;
      const bf16* src;
      if (TAPS == 3){
        int l = token - (token/SEQ)*SEQ;
        int ls = l + tap - 1;
        bool valid = (ls >= 0) && (ls < SEQ);
        src = valid ? (A + (size_t)(token + tap - 1)*DM + kk0 + scol) : zpage;
      } else {
        src = A + (size_t)token*DM + kk0 + scol;
      }
      gload16(src, &As[(wid*32 + s*8)*64]);
    }
    #pragma unroll
    for (int s = 0; s < 4; s++){
      int row = wid*32 + s*8 + srow;
      const bf16* src = WT + ((size_t)(tap*DM + bn + row))*DM + kk0 + scol;
      gload16(src, &Bs[(wid*32 + s*8)*64]);
    }
    __syncthreads();
    #pragma unroll
    for (int ks = 0; ks < 2; ks++){
      bf16x8 af[4], bg[4];
      #pragma unroll
      for (int m = 0; m < 4; m++)
        af[m] = *(const bf16x8*)&As[(wr*64 + m*16 + (lane & 15))*64 + ks*32 + (lane >> 4)*8];
      #pragma unroll
      for (int n = 0; n < 4; n++)
        bg[n] = *(const bf16x8*)&Bs[(wc*64 + n*16 + (lane & 15))*64 + ks*32 + (lane >> 4)*8];
      #pragma unroll
      for (int m = 0; m < 4; m++)
        #pragma unroll
        for (int n = 0; n < 4; n++)
          acc[m][n] = __builtin_amdgcn_mfma_f32_16x16x32_bf16(af[m], bg[n], acc[m][n], 0, 0, 0);
    }
  }
  const int c_l = lane & 15, r4 = (lane >> 4) * 4;
  #pragma unroll
  for (int m = 0; m < 4; m++){
    #pragma unroll
    for (int n = 0; n < 4; n++){
      #pragma unroll
      for (int r = 0; r < 4; r++){
        int token = bm + wr*64 + m*16 + r4 + r;
        int col   = bn + wc*64 + n*16 + c_l;
        float v = acc[m][n][r] + bias[col];
        if (EPI == 0)      Cf[(size_t)token*DM + col] = v;
        else if (EPI == 1) Cf[(size_t)token*DM + col] += v;
        else               Cb[(size_t)token*DM + col] = __float2bfloat16(gelu_tanh(v));
      }
    }
  }
}

// fused Q+K split-bf16 f32-accurate GEMM (A shared): 3 passes, dual accumulators
__global__ __launch_bounds__(256) void mfma_qk2(
    const bf16* __restrict__ Ahi, const bf16* __restrict__ Alo,
    const bf16* __restrict__ WqT, const bf16* __restrict__ WkT,
    const float* __restrict__ bq, const float* __restrict__ bk,
    float* __restrict__ Qo, float* __restrict__ Ko)
{
  __shared__ bf16 As[128*64];
  __shared__ bf16 BsQ[128*64];
  __shared__ bf16 BsK[128*64];
  const int tid = threadIdx.x;
  const int wid = tid >> 6, lane = tid & 63;
  const int wr = wid >> 1, wc = wid & 1;
  const int bm = blockIdx.y * 128;
  const int bn = blockIdx.x * 128;
  const int srow = lane >> 3;
  const int scol = (lane & 7) * 8;

  f32x4 accQ[4][4] = {};
  f32x4 accK[4][4] = {};
  for (int ck = 0; ck < 18; ck++){
    const int p   = ck / 6;              // 0: Ahi@Whi  1: Ahi@Wlo  2: Alo@Whi
    const int kk0 = (ck % 6) * 64;
    const bf16* Asrc = (p < 2) ? Ahi : Alo;
    const size_t wo = (p == 1) ? (size_t)DM*DM : 0;
    __syncthreads();
    #pragma unroll
    for (int s = 0; s < 4; s++){
      int row = wid*32 + s*8 + srow;
      gload16(Asrc + (size_t)(bm + row)*DM + kk0 + scol, &As[(wid*32 + s*8)*64]);
    }
    #pragma unroll
    for (int s = 0; s < 4; s++){
      int row = wid*32 + s*8 + srow;
      gload16(WqT + wo + (size_t)(bn + row)*DM + kk0 + scol, &BsQ[(wid*32 + s*8)*64]);
    }
    #pragma unroll
    for (int s = 0; s < 4; s++){
      int row = wid*32 + s*8 + srow;
      gload16(WkT + wo + (size_t)(bn + row)*DM + kk0 + scol, &BsK[(wid*32 + s*8)*64]);
    }
    __syncthreads();
    #pragma unroll
    for (int ks = 0; ks < 2; ks++){
      bf16x8 af[4], bgq[4], bgk[4];
      #pragma unroll
      for (int m = 0; m < 4; m++)
        af[m] = *(const bf16x8*)&As[(wr*64 + m*16 + (lane & 15))*64 + ks*32 + (lane >> 4)*8];
      #pragma unroll
      for (int n = 0; n < 4; n++){
        bgq[n] = *(const bf16x8*)&BsQ[(wc*64 + n*16 + (lane & 15))*64 + ks*32 + (lane >> 4)*8];
        bgk[n] = *(const bf16x8*)&BsK[(wc*64 + n*16 + (lane & 15))*64 + ks*32 + (lane >> 4)*8];
      }
      #pragma unroll
      for (int m = 0; m < 4; m++)
        #pragma unroll
        for (int n = 0; n < 4; n++){
          accQ[m][n] = __builtin_amdgcn_mfma_f32_16x16x32_bf16(af[m], bgq[n], accQ[m][n], 0, 0, 0);
          accK[m][n] = __builtin_amdgcn_mfma_f32_16x16x32_bf16(af[m], bgk[n], accK[m][n], 0, 0, 0);
        }
    }
  }
  const int c_l = lane & 15, r4 = (lane >> 4) * 4;
  #pragma unroll
  for (int m = 0; m < 4; m++)
    #pragma unroll
    for (int n = 0; n < 4; n++)
      #pragma unroll
      for (int r = 0; r < 4; r++){
        int token = bm + wr*64 + m*16 + r4 + r;
        int col   = bn + wc*64 + n*16 + c_l;
        Qo[(size_t)token*DM + col] = accQ[m][n][r] + bq[col];
        Ko[(size_t)token*DM + col] = accK[m][n][r] + bk[col];
      }
}

// ---------------- conv2 as MFMA ----------------
__global__ __launch_bounds__(256) void conv2_mfma(
    const bf16* __restrict__ HT, const bf16* __restrict__ W2T,
    const float* __restrict__ bias, float* __restrict__ X,
    const bf16* __restrict__ zpage)
{
  __shared__ bf16 As[128*64];
  __shared__ bf16 Bs[128*64];
  const int tid = threadIdx.x;
  const int wid = tid >> 6, lane = tid & 63;
  const int wr = wid >> 1, wc = wid & 1;
  const int bn = blockIdx.x * 128;
  const int g  = blockIdx.y;
  const int b  = blockIdx.z;
  const int srow = lane >> 3;
  const int scol = (lane & 7) * 8;
  const bf16* Wbase = W2T + (size_t)g*3*128*128;

  f32x4 acc[4][4] = {};
  for (int ck = 0; ck < 6; ck++){
    const int tap = ck >> 1;
    const int kk0 = (ck & 1) * 64;
    __syncthreads();
    #pragma unroll
    for (int s = 0; s < 4; s++){
      int row = wid*32 + s*8 + srow;
      gload16(Wbase + ((size_t)tap*128 + row)*128 + kk0 + scol, &As[(wid*32 + s*8)*64]);
    }
    #pragma unroll
    for (int s = 0; s < 4; s++){
      int row = wid*32 + s*8 + srow;
      int sd = bn + row + tap - 1;
      const bf16* src = (sd >= 0 && sd < DM)
        ? (HT + (((size_t)b*DM + sd)*2 + g)*128 + kk0 + scol) : zpage;
      gload16(src, &Bs[(wid*32 + s*8)*64]);
    }
    __syncthreads();
    #pragma unroll
    for (int ks = 0; ks < 2; ks++){
      bf16x8 af[4], bg[4];
      #pragma unroll
      for (int m = 0; m < 4; m++)
        af[m] = *(const bf16x8*)&As[(wr*64 + m*16 + (lane & 15))*64 + ks*32 + (lane >> 4)*8];
      #pragma unroll
      for (int n = 0; n < 4; n++)
        bg[n] = *(const bf16x8*)&Bs[(wc*64 + n*16 + (lane & 15))*64 + ks*32 + (lane >> 4)*8];
      #pragma unroll
      for (int m = 0; m < 4; m++)
        #pragma unroll
        for (int n = 0; n < 4; n++)
          acc[m][n] = __builtin_amdgcn_mfma_f32_16x16x32_bf16(af[m], bg[n], acc[m][n], 0, 0, 0);
    }
  }
  const int c_l = lane & 15, r4 = (lane >> 4) * 4;
  #pragma unroll
  for (int m = 0; m < 4; m++){
    #pragma unroll
    for (int n = 0; n < 4; n++){
      #pragma unroll
      for (int r = 0; r < 4; r++){
        int lo = wr*64 + m*16 + r4 + r;
        if (lo < 125){
          int d = bn + wc*64 + n*16 + c_l;
          float v = acc[m][n][r] + bias[g*125 + lo];
          X[((size_t)b*SEQ + g*125 + lo)*DM + d] += gelu_tanh(v);
        }
      }
    }
  }
}

// ---------------- transpose H[b][l][d] bf16 -> HT[b][d][g*128+li] bf16 ----------------
__global__ __launch_bounds__(256) void transpose_ht(const bf16* __restrict__ H,
                                                    bf16* __restrict__ HT){
  __shared__ bf16 t[68][66];
  int d0 = blockIdx.x * 64;
  int p0 = blockIdx.y * 64;
  int b  = blockIdx.z;
  int tid = threadIdx.x;
  int l0 = p0 - 3;
  for (int i = tid; i < 68*64; i += 256){
    int r = i >> 6, c = i & 63;
    int l = l0 + r;
    bf16 v = __float2bfloat16(0.f);
    if (l >= 0 && l < SEQ) v = H[((size_t)b*SEQ + l)*DM + d0 + c];
    t[r][c] = v;
  }
  __syncthreads();
  for (int i = tid; i < 64*64; i += 256){
    int rr = i >> 6, cc = i & 63;
    int p = p0 + cc;
    int gg = p >> 7, li = p & 127;
    int l = gg*125 + li;
    bf16 v = __float2bfloat16(0.f);
    if (li < 125 && l < SEQ) v = t[l - l0][rr];
    HT[((size_t)b*DM + d0 + rr)*256 + p] = v;
  }
}

// ---------------- weight prep ----------------
__global__ void zfill(bf16* z){ z[threadIdx.x] = __float2bfloat16(0.f); }

__global__ __launch_bounds__(256) void build_projT(const float* __restrict__ Wv,
    const float* __restrict__ Wo, bf16* __restrict__ WvT, bf16* __restrict__ WoT){
  __shared__ float t[32][33];
  int mat = blockIdx.z;
  const float* W = (mat < 4) ? (Wv + (size_t)mat*DM*DM) : (Wo + (size_t)(mat-4)*DM*DM);
  bf16* WT = (mat < 4) ? (WvT + (size_t)mat*DM*DM) : (WoT + (size_t)(mat-4)*DM*DM);
  int k0 = blockIdx.y*32, n0 = blockIdx.x*32;
  int tx = threadIdx.x & 31, ty = threadIdx.x >> 5;
  #pragma unroll
  for (int r = 0; r < 32; r += 8)
    t[ty + r][tx] = W[(size_t)(k0 + ty + r)*DM + n0 + tx];
  __syncthreads();
  #pragma unroll
  for (int r = 0; r < 32; r += 8)
    WT[(size_t)(n0 + ty + r)*DM + k0 + tx] = __float2bfloat16(t[tx][ty + r]);
}

__global__ __launch_bounds__(256) void build_qkhl(const float* __restrict__ Wq,
    const float* __restrict__ Wk, bf16* __restrict__ WT){
  __shared__ float t[32][33];
  int mat = blockIdx.z;
  const float* W = (mat < 4) ? (Wq + (size_t)mat*DM*DM) : (Wk + (size_t)(mat-4)*DM*DM);
  bf16* hi = WT + (size_t)mat*2*DM*DM;
  bf16* lo = hi + (size_t)DM*DM;
  int k0 = blockIdx.y*32, n0 = blockIdx.x*32;
  int tx = threadIdx.x & 31, ty = threadIdx.x >> 5;
  #pragma unroll
  for (int r = 0; r < 32; r += 8)
    t[ty + r][tx] = W[(size_t)(k0 + ty + r)*DM + n0 + tx];
  __syncthreads();
  #pragma unroll
  for (int r = 0; r < 32; r += 8){
    float w = t[tx][ty + r];
    bf16 h = __float2bfloat16(w);
    hi[(size_t)(n0 + ty + r)*DM + k0 + tx] = h;
    lo[(size_t)(n0 + ty + r)*DM + k0 + tx] = __float2bfloat16(w - __bfloat162float(h));
  }
}

__global__ void build_c1aT(const float* __restrict__ W, const float* __restrict__ bin,
                           bf16* __restrict__ WT, float* __restrict__ bias_pad){
  int i = blockIdx.x*256 + threadIdx.x;
  if (i < 4*DM){
    int l = i/DM, n = i%DM;
    bias_pad[i] = (n < HID) ? bin[l*HID + n] : 0.f;
  }
  if (i >= 4*3*DM*DM) return;
  int k = i % DM; int n = (i/DM) % DM; int t = (i/(DM*DM)) % 3; int l = i/(3*DM*DM);
  float v = 0.f;
  if (n < HID){
    int g = n / 114; int ci = k - g*128;
    if (ci >= 0 && ci < 128)
      v = W[(((size_t)l*HID + n)*128 + ci)*3 + t];
  }
  WT[i] = __float2bfloat16(v);
}

__global__ void build_c1bT(const float* __restrict__ W, bf16* __restrict__ WT){
  int i = blockIdx.x*256 + threadIdx.x;
  if (i >= 4*3*DM*DM) return;
  int k = i % DM; int n = (i/DM) % DM; int t = (i/(DM*DM)) % 3; int l = i/(3*DM*DM);
  int g = n >> 7; int ci = k - g*114;
  float v = 0.f;
  if (ci >= 0 && ci < 114)
    v = W[(((size_t)l*DM + n)*114 + ci)*3 + t];
  WT[i] = __float2bfloat16(v);
}

__global__ void build_c2T(const float* __restrict__ W, bf16* __restrict__ WT){
  int i = blockIdx.x*256 + threadIdx.x;
  if (i >= 4*2*3*128*128) return;
  int li = i & 127;
  int lo = (i >> 7) & 127;
  int t  = (i / 16384) % 3;
  int g  = (i / 49152) % 2;
  int l  = i / 98304;
  float v = 0.f;
  if (lo < 125 && li < 125)
    v = W[(((size_t)l*SEQ + g*125 + lo)*125 + li)*3 + t];
  WT[i] = __float2bfloat16(v);
}

// ---------------- fused probe + top-k: one block per (b,h) ----------------
__global__ __launch_bounds__(256) void probe_topk(const float* __restrict__ Q,
    const float* __restrict__ K, const int* __restrict__ idx, int* __restrict__ TOP){
  __shared__ float Ksh[SEQ*49];
  __shared__ float s_redv[4];
  __shared__ int   s_redi[4];
  __shared__ int   s_win;
  int bh = blockIdx.x; int h = bh & 7; int b = bh >> 3;
  int tid = threadIdx.x;
  for (int i = tid; i < SEQ*DHd; i += 256){
    int r = i / DHd, c = i - r*DHd;
    Ksh[r*49 + c] = K[((size_t)(b*SEQ + r))*DM + h*DHd + c];
  }
  __syncthreads();
  int l = tid;
  float Mv = -FLT_MAX;
  if (l < SEQ){
    float qr[DHd];
    const float* qp = Q + ((size_t)(b*SEQ + l))*DM + h*DHd;
    #pragma unroll
    for (int z = 0; z < DHd; z++) qr[z] = qp[z];
    const int* ip = idx + l*UU;
    float mx = -FLT_MAX, sm = 0.f;
    for (int u = 0; u < UU; u++){
      int base = ip[u]*49;
      float d = 0.f;
      #pragma unroll
      for (int z = 0; z < DHd; z++) d += qr[z]*Ksh[base + z];
      mx = fmaxf(mx, d); sm += d;
    }
    Mv = mx - sm*(1.f/UU);
  }
  int myid = (l < SEQ) ? l : (1<<30);
  int lane = tid & 63, wid = tid >> 6;
  for (int sel = 0; sel < UU; sel++){
    float bv = Mv; int bi = myid;
    #pragma unroll
    for (int off = 32; off; off >>= 1){
      float ov = __shfl_xor(bv, off);
      int   oi = __shfl_xor(bi, off);
      if (ov > bv || (ov == bv && oi < bi)){ bv = ov; bi = oi; }
    }
    if (lane == 0){ s_redv[wid] = bv; s_redi[wid] = bi; }
    __syncthreads();
    if (tid == 0){
      float wv = s_redv[0]; int wi = s_redi[0];
      #pragma unroll
      for (int q = 1; q < 4; q++)
        if (s_redv[q] > wv || (s_redv[q] == wv && s_redi[q] < wi)){ wv = s_redv[q]; wi = s_redi[q]; }
      TOP[(size_t)bh*UU + sel] = wi;
      s_win = wi;
    }
    __syncthreads();
    if (myid == s_win) Mv = -FLT_MAX;
  }
}

// ---------------- fused attention context per (b,h): K,V bf16 in LDS, u-groups of 10 ----------------
static constexpr int UG = 10;
__global__ __launch_bounds__(256) void attn_ctx3(const float* __restrict__ Q,
    const float* __restrict__ K, const float* __restrict__ V,
    const int* __restrict__ TOP, bf16* __restrict__ CTX){
  __shared__ bf16  Ksh[SEQ*50];       // 25000 B, stride 50 (25 dwords, gcd(25,32)=1)
  __shared__ bf16  Vsh[SEQ*50];       // 25000 B
  __shared__ float qsh[UG][DHd];      // pre-scaled by 1/sqrt(48)
  __shared__ float psh[UG][SEQ];
  __shared__ float invsh[UG];
  __shared__ float part[UG][5][DHd];
  __shared__ float vmean[DHd];
  __shared__ float red[8];
  __shared__ int   mark[SEQ];
  int bh = blockIdx.x; int h = bh & 7; int b = bh >> 3;
  int tid = threadIdx.x;
  const size_t base = (size_t)b*SEQ*DM + h*DHd;
  // stage K and V (bf16), init mark
  for (int i = tid; i < SEQ*DHd; i += 256){
    int r = i / DHd, c = i - r*DHd;
    Ksh[r*50 + c] = __float2bfloat16(K[base + (size_t)r*DM + c]);
    Vsh[r*50 + c] = __float2bfloat16(V[base + (size_t)r*DM + c]);
  }
  for (int i = tid; i < SEQ; i += 256) mark[i] = -1;
  __syncthreads();
  if (tid < UU) mark[TOP[(size_t)bh*UU + tid]] = tid;
  // vmean from Vsh
  if (tid < 240){
    int dh = tid % DHd, pr = tid / DHd;
    float s = 0.f;
    for (int j = pr*50; j < pr*50+50; j++) s += __bfloat162float(Vsh[j*50 + dh]);
    part[0][pr][dh] = s;
  }
  __syncthreads();
  if (tid < DHd)
    vmean[tid] = (part[0][0][tid]+part[0][1][tid]+part[0][2][tid]+part[0][3][tid]+part[0][4][tid]) * (1.f/SEQ);
  __syncthreads();
  // 3 passes of 10 u's
  for (int u0 = 0; u0 < UU; u0 += UG){
    for (int i = tid; i < UG*DHd; i += 256){
      int uu = i / DHd, z = i - uu*DHd;
      int l0 = TOP[(size_t)bh*UU + u0 + uu];
      qsh[uu][z] = Q[(size_t)(b*SEQ + l0)*DM + h*DHd + z] * 0.14433756729740643f;
    }
    __syncthreads();
    // scores: thread j computes 10 dots from LDS K
    float s[UG];
    #pragma unroll
    for (int u = 0; u < UG; u++) s[u] = -FLT_MAX;
    if (tid < SEQ){
      #pragma unroll
      for (int u = 0; u < UG; u++) s[u] = 0.f;
      for (int z = 0; z < DHd; z++){
        float kv = __bfloat162float(Ksh[tid*50 + z]);
        #pragma unroll
        for (int u = 0; u < UG; u++) s[u] = fmaf(qsh[u][z], kv, s[u]);
      }
    }
    // per-u softmax
    #pragma unroll
    for (int u = 0; u < UG; u++){
      float mx = block_max(s[u], red);
      float e = (tid < SEQ) ? expf(s[u] - mx) : 0.f;
      if (tid < SEQ) psh[u][tid] = e;
      float sm = block_sum(e, red);
      if (tid == 0) invsh[u] = 1.f / sm;
    }
    __syncthreads();
    // PV from LDS V
    if (tid < 240){
      int dh = tid % DHd, pr = tid / DHd;
      float a[UG];
      #pragma unroll
      for (int u = 0; u < UG; u++) a[u] = 0.f;
      for (int j = pr*50; j < pr*50+50; j++){
        float vv = __bfloat162float(Vsh[j*50 + dh]);
        #pragma unroll
        for (int u = 0; u < UG; u++) a[u] = fmaf(psh[u][j], vv, a[u]);
      }
      #pragma unroll
      for (int u = 0; u < UG; u++) part[u][pr][dh] = a[u];
    }
    __syncthreads();
    for (int i = tid; i < UG*DHd; i += 256){
      int uu = i / DHd, dh = i - uu*DHd;
      float acc = (part[uu][0][dh]+part[uu][1][dh]+part[uu][2][dh]+part[uu][3][dh]+part[uu][4][dh]) * invsh[uu];
      int l0 = TOP[(size_t)bh*UU + u0 + uu];
      CTX[(size_t)(b*SEQ + l0)*DM + h*DHd + dh] = __float2bfloat16(acc);
    }
    __syncthreads();
  }
  // fill non-top rows with vmean
  for (int i = tid; i < SEQ*DHd; i += 256){
    int l = i / DHd, dh = i - l*DHd;
    if (mark[l] < 0)
      CTX[(size_t)(b*SEQ + l)*DM + h*DHd + dh] = __float2bfloat16(vmean[dh]);
  }
}

// ---------------- final: max over L -> LN(ln2) -> FC ----------------
__global__ __launch_bounds__(384) void final_kernel(const float* __restrict__ Hin,
    const float* __restrict__ w, const float* __restrict__ bparm,
    const float* __restrict__ fcw, const float* __restrict__ fcb, float* __restrict__ out){
  __shared__ float red[8];
  __shared__ float ybuf[DM];
  int b = blockIdx.x; int d = threadIdx.x;
  const float* hp = Hin + (size_t)b*SEQ*DM + d;
  float mx = -FLT_MAX;
  for (int l=0;l<SEQ;l++) mx = fmaxf(mx, hp[(size_t)l*DM]);
  float mu = block_sum(mx, red) * (1.f/DM);
  float diff = mx - mu;
  float var = block_sum(diff*diff, red) * (1.f/DM);
  float y = diff * rsqrtf(var + 1e-5f) * w[d] + bparm[d];
  ybuf[d] = y;
  __syncthreads();
  if (d < 10){
    float acc = fcb[d];
    for (int k=0;k<DM;k++) acc += ybuf[k] * fcw[k*10 + d];
    out[b*10 + d] = acc;
  }
}

// ---------------- host orchestration ----------------
extern "C" void kernel_launch(void* const* d_in, const int* in_sizes, int n_in,
                              void* d_out, int out_size, void* d_ws, size_t ws_size,
                              hipStream_t stream) {
  const float* x     = (const float*)d_in[0];
  const float* pos   = (const float*)d_in[1];
  const float* lniw  = (const float*)d_in[2];
  const float* lnib  = (const float*)d_in[3];
  const float* lnAw  = (const float*)d_in[4];
  const float* lnAb  = (const float*)d_in[5];
  const float* Wq    = (const float*)d_in[6];
  const float* bq    = (const float*)d_in[7];
  const float* Wk    = (const float*)d_in[8];
  const float* bk    = (const float*)d_in[9];
  const float* Wv    = (const float*)d_in[10];
  const float* bv    = (const float*)d_in[11];
  const float* Wo    = (const float*)d_in[12];
  const float* bo    = (const float*)d_in[13];
  const float* lnBw  = (const float*)d_in[14];
  const float* lnBb  = (const float*)d_in[15];
  const float* c1aw  = (const float*)d_in[16];
  const float* c1ab  = (const float*)d_in[17];
  const float* c1bw  = (const float*)d_in[18];
  const float* c1bb  = (const float*)d_in[19];
  const float* lnCw  = (const float*)d_in[20];
  const float* lnCb  = (const float*)d_in[21];
  const float* c2w   = (const float*)d_in[22];
  const float* c2b   = (const float*)d_in[23];
  const float* ln2w  = (const float*)d_in[24];
  const float* ln2b  = (const float*)d_in[25];
  const float* fcw   = (const float*)d_in[26];
  const float* fcb   = (const float*)d_in[27];
  float* out = (float*)d_out;

  const size_t ACT  = (size_t)Bb*SEQ*DM;        // 12,288,000
  float* Xb  = (float*)d_ws;
  float* Hb  = Xb  + ACT;                       // f32 for final LN; aliased as Alo bf16 early
  float* Qb  = Hb  + ACT;                       // aliased as HT bf16 in conv2 phase
  float* Kb  = Qb  + ACT;
  float* Vb  = Kb  + ACT;
  float* biasA = Vb + ACT;
  int*   TOP = (int*)(biasA + 4*DM);
  int*   IDX = TOP + (size_t)Bb*NH*UU;
  bf16*  Hb16 = (bf16*)(IDX + 4*7500);          // Ahi / CTX16 / conv input
  bf16*  G1   = Hb16 + ACT;
  bf16*  WvT  = G1   + ACT;
  bf16*  WoT  = WvT  + (size_t)4*DM*DM;
  bf16*  WaT  = WoT  + (size_t)4*DM*DM;
  bf16*  WbT  = WaT  + (size_t)12*DM*DM;
  bf16*  WqkT = WbT  + (size_t)12*DM*DM;        // [8][2][384][384]
  bf16*  W2T  = WqkT + (size_t)16*DM*DM;        // [4][2][3][128][128]
  bf16*  zp   = W2T  + (size_t)4*2*3*128*128;

  zfill<<<dim3(1), dim3(256), 0, stream>>>(zp);
  idx_kernel<<<dim3(118), dim3(256), 0, stream>>>(IDX);
  build_projT<<<dim3(12,12,8), dim3(256), 0, stream>>>(Wv, Wo, WvT, WoT);
  build_qkhl<<<dim3(12,12,8), dim3(256), 0, stream>>>(Wq, Wk, WqkT);
  build_c1aT<<<dim3(6912), dim3(256), 0, stream>>>(c1aw, c1ab, WaT, biasA);
  build_c1bT<<<dim3(6912), dim3(256), 0, stream>>>(c1bw, WbT);
  build_c2T<<<dim3(1536), dim3(256), 0, stream>>>(c2w, W2T);
  pool_ln_pos<<<dim3(32000), dim3(384), 0, stream>>>(x, pos, lniw, lnib, Xb);

  for (int l = 0; l < 4; l++){
    const size_t wofs = (size_t)l*DM*DM;
    bf16* Alo16 = (bf16*)Hb;          // alias: Hb f32 unused until final LN
    bf16* CTX16 = Hb16;               // reuse after V-proj
    bf16* HTb   = (bf16*)Qb;          // alias: Qb dead after attention
    ln384hl<<<dim3(32000), dim3(384), 0, stream>>>(Xb, Hb16, Alo16, lnAw + l*DM, lnAb + l*DM);
    mfma_qk2<<<dim3(3,250), dim3(256), 0, stream>>>(Hb16, Alo16,
        WqkT + (size_t)l*2*DM*DM, WqkT + (size_t)(4+l)*2*DM*DM,
        bq + l*DM, bk + l*DM, Qb, Kb);
    mfma_gemm<1,0><<<dim3(3,250), dim3(256), 0, stream>>>(Hb16, WvT + wofs, bv + l*DM, Vb, (bf16*)nullptr, zp);
    probe_topk<<<dim3(Bb*NH), dim3(256), 0, stream>>>(Qb, Kb, IDX + l*7500, TOP);
    attn_ctx3<<<dim3(Bb*NH), dim3(256), 0, stream>>>(Qb, Kb, Vb, TOP, CTX16);
    mfma_gemm<1,1><<<dim3(3,250), dim3(256), 0, stream>>>(CTX16, WoT + wofs, bo + l*DM, Xb, (bf16*)nullptr, zp);

    ln384x<false,true><<<dim3(32000), dim3(384), 0, stream>>>(Xb, (float*)nullptr, Hb16, lnBw + l*DM, lnBb + l*DM);
    mfma_gemm<3,2><<<dim3(3,250), dim3(256), 0, stream>>>(Hb16, WaT + (size_t)l*3*DM*DM, biasA + l*DM, (float*)nullptr, G1, zp);
    mfma_gemm<3,1><<<dim3(3,250), dim3(256), 0, stream>>>(G1, WbT + (size_t)l*3*DM*DM, c1bb + l*DM, Xb, (bf16*)nullptr, zp);

    ln384x<false,true><<<dim3(32000), dim3(384), 0, stream>>>(Xb, (float*)nullptr, Hb16, lnCw + l*DM, lnCb + l*DM);
    transpose_ht<<<dim3(6,4,Bb), dim3(256), 0, stream>>>(Hb16, HTb);
    conv2_mfma<<<dim3(3,2,Bb), dim3(256), 0, stream>>>(HTb, W2T + (size_t)l*2*3*128*128, c2b + l*SEQ, Xb, zp);
  }

  ln384x<true,false><<<dim3(32000), dim3(384), 0, stream>>>(Xb, Hb, (bf16*)nullptr, ln2w, ln2b);
  final_kernel<<<dim3(Bb), dim3(384), 0, stream>>>(Hb, ln2w, ln2b, fcw, fcb, out);
}

// Round 9
// 2976.428 us; speedup vs baseline: 3.7456x; 1.2426x over previous
//
#include <hip/hip_runtime.h>
#include <hip/hip_bf16.h>
#include <cfloat>
#include <cstdint>

// ---------------- constants ----------------
static constexpr int Bb   = 128;
static constexpr int SEQ  = 250;
static constexpr int DM   = 384;
static constexpr int NH   = 8;
static constexpr int DHd  = 48;
static constexpr int HID  = 342;
static constexpr int UU   = 30;   // U == u == 30

using bf16 = __hip_bfloat16;
typedef __attribute__((ext_vector_type(8))) short bf16x8;
typedef __attribute__((ext_vector_type(4))) float f32x4;

__device__ __forceinline__ uint32_t packbf2(float a, float b){
  uint32_t ua = __builtin_bit_cast(uint32_t, __bfloat162float(__float2bfloat16(a)));
  uint32_t ub = __builtin_bit_cast(uint32_t, __bfloat162float(__float2bfloat16(b)));
  return (ua >> 16) | (ub & 0xffff0000u);
}
__device__ __forceinline__ float unpk_lo(uint32_t p){ return __builtin_bit_cast(float, p << 16); }
__device__ __forceinline__ float unpk_hi(uint32_t p){ return __builtin_bit_cast(float, p & 0xffff0000u); }

// ---------------- threefry2x32 (JAX-exact) ----------------
__device__ __forceinline__ uint32_t rotl32(uint32_t x, int n){ return (x<<n)|(x>>(32-n)); }
#define TF_R(x0,x1,r) { x0 += x1; x1 = rotl32(x1,(r)); x1 ^= x0; }
__device__ inline void threefry(uint32_t k0, uint32_t k1, uint32_t x0, uint32_t x1,
                                uint32_t &o0, uint32_t &o1){
  uint32_t ks2 = k0 ^ k1 ^ 0x1BD11BDAu;
  x0 += k0; x1 += k1;
  TF_R(x0,x1,13) TF_R(x0,x1,15) TF_R(x0,x1,26) TF_R(x0,x1,6)
  x0 += k1; x1 += ks2 + 1u;
  TF_R(x0,x1,17) TF_R(x0,x1,29) TF_R(x0,x1,16) TF_R(x0,x1,24)
  x0 += ks2; x1 += k0 + 2u;
  TF_R(x0,x1,13) TF_R(x0,x1,15) TF_R(x0,x1,26) TF_R(x0,x1,6)
  x0 += k0; x1 += k1 + 3u;
  TF_R(x0,x1,17) TF_R(x0,x1,29) TF_R(x0,x1,16) TF_R(x0,x1,24)
  x0 += k1; x1 += ks2 + 4u;
  TF_R(x0,x1,13) TF_R(x0,x1,15) TF_R(x0,x1,26) TF_R(x0,x1,6)
  x0 += ks2; x1 += k0 + 5u;
  o0 = x0; o1 = x1;
}

__global__ void idx_kernel(int* __restrict__ IDX){
  int i = blockIdx.x*256 + threadIdx.x;
  if (i >= 4*7500) return;
  int l = i / 7500;
  int t = i % 7500;
  uint32_t fk0, fk1;
  threefry(0u, 42u, 0u, (uint32_t)l, fk0, fk1);
  uint32_t a0,a1,b0,b1;
  threefry(fk0, fk1, 0u, 2u, a0, a1);
  threefry(fk0, fk1, 1u, 3u, b0, b1);
  uint32_t c0 = (t < 3750) ? (uint32_t)t          : (uint32_t)(t-3750);
  uint32_t c1 = (t < 3750) ? (uint32_t)(t+3750)   : (uint32_t)t;
  uint32_t y0, y1, hi, lo;
  threefry(a0, b0, c0, c1, y0, y1); hi = (t < 3750) ? y0 : y1;
  threefry(a1, b1, c0, c1, y0, y1); lo = (t < 3750) ? y0 : y1;
  uint32_t val = ((hi % 250u) * 46u + (lo % 250u)) % 250u;
  IDX[i] = (int)val;
}

// ---------------- block reductions (used by pool/final) ----------------
__device__ __forceinline__ float block_sum(float v, float* red){
  v += __shfl_down(v,32); v += __shfl_down(v,16); v += __shfl_down(v,8);
  v += __shfl_down(v,4);  v += __shfl_down(v,2);  v += __shfl_down(v,1);
  int lane = threadIdx.x & 63, wid = threadIdx.x >> 6, nw = blockDim.x >> 6;
  __syncthreads();
  if (lane == 0) red[wid] = v;
  __syncthreads();
  float r = red[0];
  for (int i=1;i<nw;i++) r += red[i];
  return r;
}

__device__ __forceinline__ float gelu_tanh(float x){
  float t = 0.7978845608028654f * (x + 0.044715f * x * x * x);
  return 0.5f * x * (1.f + tanhf(t));
}

// ---------------- pool (max over 4) + LN + pos ----------------
__global__ __launch_bounds__(384) void pool_ln_pos(const float* __restrict__ xin,
    const float* __restrict__ pos, const float* __restrict__ w, const float* __restrict__ b,
    float* __restrict__ X){
  __shared__ float red[8];
  int bs = blockIdx.x; int bb = bs / SEQ, s = bs % SEQ; int d = threadIdx.x;
  const float* xp = xin + ((size_t)bb*1000 + (size_t)s*4)*DM + d;
  float v = fmaxf(fmaxf(xp[0], xp[DM]), fmaxf(xp[2*DM], xp[3*DM]));
  float mu = block_sum(v, red) * (1.f/DM);
  float diff = v - mu;
  float var = block_sum(diff*diff, red) * (1.f/DM);
  X[(size_t)bs*DM + d] = diff * rsqrtf(var + 1e-5f) * w[d] + b[d] + pos[(size_t)s*DM + d];
}

// ---------------- wave-per-row LayerNorm (no LDS, no barriers) ----------------
// MODE 0: f32 out; 1: bf16 out; 2: hi+lo bf16 out
template<int MODE>
__global__ __launch_bounds__(256) void ln_wave(const float* __restrict__ in,
    float* __restrict__ o32, bf16* __restrict__ o16, bf16* __restrict__ olo,
    const float* __restrict__ w, const float* __restrict__ b){
  size_t row = (size_t)blockIdx.x*4 + (threadIdx.x >> 6);
  int lane = threadIdx.x & 63;
  const float* rp = in + row*DM;
  float v[6];
  #pragma unroll
  for (int i = 0; i < 6; i++) v[i] = rp[lane + 64*i];
  float s = v[0]+v[1]+v[2]+v[3]+v[4]+v[5];
  #pragma unroll
  for (int off = 32; off; off >>= 1) s += __shfl_xor(s, off);
  float mu = s * (1.f/DM);
  float q = 0.f;
  #pragma unroll
  for (int i = 0; i < 6; i++){ float d = v[i]-mu; q += d*d; }
  #pragma unroll
  for (int off = 32; off; off >>= 1) q += __shfl_xor(q, off);
  float rs = rsqrtf(q*(1.f/DM) + 1e-5f);
  #pragma unroll
  for (int i = 0; i < 6; i++){
    int d = lane + 64*i;
    float y = (v[i]-mu)*rs*w[d] + b[d];
    if (MODE == 0) o32[row*DM + d] = y;
    if (MODE == 1) o16[row*DM + d] = __float2bfloat16(y);
    if (MODE == 2){
      bf16 h = __float2bfloat16(y);
      o16[row*DM + d] = h;
      olo[row*DM + d] = __float2bfloat16(y - __bfloat162float(h));
    }
  }
}

// ---------------- bf16 MFMA GEMM ----------------
__device__ __forceinline__ void gload16(const void* g, void* l){
  __builtin_amdgcn_global_load_lds(
      (__attribute__((address_space(1))) void*)(g),
      (__attribute__((address_space(3))) void*)(l), 16, 0, 0);
}

// C[M x 384] = sum_tap shift(A,tap-1) @ W_tap ; EPI: 0=store f32+bias 1=+= f32+bias 2=bf16 gelu store
template<int TAPS, int EPI>
__global__ __launch_bounds__(256) void mfma_gemm(
    const bf16* __restrict__ A, const bf16* __restrict__ WT,
    const float* __restrict__ bias, float* __restrict__ Cf, bf16* __restrict__ Cb,
    const bf16* __restrict__ zpage)
{
  __shared__ bf16 As[128*64];
  __shared__ bf16 Bs[128*64];
  const int tid = threadIdx.x;
  const int wid = tid >> 6, lane = tid & 63;
  const int wr = wid >> 1, wc = wid & 1;
  const int bm = blockIdx.y * 128;
  const int bn = blockIdx.x * 128;
  const int srow = lane >> 3;
  const int scol = (lane & 7) * 8;

  f32x4 acc[4][4] = {};
  const int NCH = TAPS * 6;
  for (int ck = 0; ck < NCH; ck++){
    const int tap = (TAPS == 3) ? (ck / 6) : 0;
    const int kk0 = (TAPS == 3) ? ((ck % 6) * 64) : (ck * 64);
    __syncthreads();
    #pragma unroll
    for (int s = 0; s < 4; s++){
      int row = wid*32 + s*8 + srow;
      int token = bm + row;
      const bf16* src;
      if (TAPS == 3){
        int l = token - (token/SEQ)*SEQ;
        int ls = l + tap - 1;
        bool valid = (ls >= 0) && (ls < SEQ);
        src = valid ? (A + (size_t)(token + tap - 1)*DM + kk0 + scol) : zpage;
      } else {
        src = A + (size_t)token*DM + kk0 + scol;
      }
      gload16(src, &As[(wid*32 + s*8)*64]);
    }
    #pragma unroll
    for (int s = 0; s < 4; s++){
      int row = wid*32 + s*8 + srow;
      const bf16* src = WT + ((size_t)(tap*DM + bn + row))*DM + kk0 + scol;
      gload16(src, &Bs[(wid*32 + s*8)*64]);
    }
    __syncthreads();
    #pragma unroll
    for (int ks = 0; ks < 2; ks++){
      bf16x8 af[4], bg[4];
      #pragma unroll
      for (int m = 0; m < 4; m++)
        af[m] = *(const bf16x8*)&As[(wr*64 + m*16 + (lane & 15))*64 + ks*32 + (lane >> 4)*8];
      #pragma unroll
      for (int n = 0; n < 4; n++)
        bg[n] = *(const bf16x8*)&Bs[(wc*64 + n*16 + (lane & 15))*64 + ks*32 + (lane >> 4)*8];
      #pragma unroll
      for (int m = 0; m < 4; m++)
        #pragma unroll
        for (int n = 0; n < 4; n++)
          acc[m][n] = __builtin_amdgcn_mfma_f32_16x16x32_bf16(af[m], bg[n], acc[m][n], 0, 0, 0);
    }
  }
  const int c_l = lane & 15, r4 = (lane >> 4) * 4;
  #pragma unroll
  for (int m = 0; m < 4; m++){
    #pragma unroll
    for (int n = 0; n < 4; n++){
      #pragma unroll
      for (int r = 0; r < 4; r++){
        int token = bm + wr*64 + m*16 + r4 + r;
        int col   = bn + wc*64 + n*16 + c_l;
        float v = acc[m][n][r] + bias[col];
        if (EPI == 0)      Cf[(size_t)token*DM + col] = v;
        else if (EPI == 1) Cf[(size_t)token*DM + col] += v;
        else               Cb[(size_t)token*DM + col] = __float2bfloat16(gelu_tanh(v));
      }
    }
  }
}

// fused Q+K split-bf16 f32-accurate GEMM (A shared): kk-major, A-stage skipped for pass 1
__global__ __launch_bounds__(256) void mfma_qk2(
    const bf16* __restrict__ Ahi, const bf16* __restrict__ Alo,
    const bf16* __restrict__ WqT, const bf16* __restrict__ WkT,
    const float* __restrict__ bq, const float* __restrict__ bk,
    float* __restrict__ Qo, float* __restrict__ Ko)
{
  __shared__ bf16 As[128*64];
  __shared__ bf16 BsQ[128*64];
  __shared__ bf16 BsK[128*64];
  const int tid = threadIdx.x;
  const int wid = tid >> 6, lane = tid & 63;
  const int wr = wid >> 1, wc = wid & 1;
  const int bm = blockIdx.y * 128;
  const int bn = blockIdx.x * 128;
  const int srow = lane >> 3;
  const int scol = (lane & 7) * 8;

  f32x4 accQ[4][4] = {};
  f32x4 accK[4][4] = {};
  for (int kk6 = 0; kk6 < 6; kk6++){
    const int kk0 = kk6 * 64;
    for (int p = 0; p < 3; p++){
      // p0: Ahi@Whi, p1: Ahi@Wlo (A reuse), p2: Alo@Whi
      const size_t wo = (p == 1) ? (size_t)DM*DM : 0;
      __syncthreads();
      if (p != 1){
        const bf16* Asrc = (p == 0) ? Ahi : Alo;
        #pragma unroll
        for (int s = 0; s < 4; s++){
          int row = wid*32 + s*8 + srow;
          gload16(Asrc + (size_t)(bm + row)*DM + kk0 + scol, &As[(wid*32 + s*8)*64]);
        }
      }
      #pragma unroll
      for (int s = 0; s < 4; s++){
        int row = wid*32 + s*8 + srow;
        gload16(WqT + wo + (size_t)(bn + row)*DM + kk0 + scol, &BsQ[(wid*32 + s*8)*64]);
      }
      #pragma unroll
      for (int s = 0; s < 4; s++){
        int row = wid*32 + s*8 + srow;
        gload16(WkT + wo + (size_t)(bn + row)*DM + kk0 + scol, &BsK[(wid*32 + s*8)*64]);
      }
      __syncthreads();
      #pragma unroll
      for (int ks = 0; ks < 2; ks++){
        bf16x8 af[4], bgq[4], bgk[4];
        #pragma unroll
        for (int m = 0; m < 4; m++)
          af[m] = *(const bf16x8*)&As[(wr*64 + m*16 + (lane & 15))*64 + ks*32 + (lane >> 4)*8];
        #pragma unroll
        for (int n = 0; n < 4; n++){
          bgq[n] = *(const bf16x8*)&BsQ[(wc*64 + n*16 + (lane & 15))*64 + ks*32 + (lane >> 4)*8];
          bgk[n] = *(const bf16x8*)&BsK[(wc*64 + n*16 + (lane & 15))*64 + ks*32 + (lane >> 4)*8];
        }
        #pragma unroll
        for (int m = 0; m < 4; m++)
          #pragma unroll
          for (int n = 0; n < 4; n++){
            accQ[m][n] = __builtin_amdgcn_mfma_f32_16x16x32_bf16(af[m], bgq[n], accQ[m][n], 0, 0, 0);
            accK[m][n] = __builtin_amdgcn_mfma_f32_16x16x32_bf16(af[m], bgk[n], accK[m][n], 0, 0, 0);
          }
      }
    }
  }
  const int c_l = lane & 15, r4 = (lane >> 4) * 4;
  #pragma unroll
  for (int m = 0; m < 4; m++)
    #pragma unroll
    for (int n = 0; n < 4; n++)
      #pragma unroll
      for (int r = 0; r < 4; r++){
        int token = bm + wr*64 + m*16 + r4 + r;
        int col   = bn + wc*64 + n*16 + c_l;
        Qo[(size_t)token*DM + col] = accQ[m][n][r] + bq[col];
        Ko[(size_t)token*DM + col] = accK[m][n][r] + bk[col];
      }
}

// ---------------- conv2 as MFMA ----------------
__global__ __launch_bounds__(256) void conv2_mfma(
    const bf16* __restrict__ HT, const bf16* __restrict__ W2T,
    const float* __restrict__ bias, float* __restrict__ X,
    const bf16* __restrict__ zpage)
{
  __shared__ bf16 As[128*64];
  __shared__ bf16 Bs[128*64];
  const int tid = threadIdx.x;
  const int wid = tid >> 6, lane = tid & 63;
  const int wr = wid >> 1, wc = wid & 1;
  const int bn = blockIdx.x * 128;
  const int g  = blockIdx.y;
  const int b  = blockIdx.z;
  const int srow = lane >> 3;
  const int scol = (lane & 7) * 8;
  const bf16* Wbase = W2T + (size_t)g*3*128*128;

  f32x4 acc[4][4] = {};
  for (int ck = 0; ck < 6; ck++){
    const int tap = ck >> 1;
    const int kk0 = (ck & 1) * 64;
    __syncthreads();
    #pragma unroll
    for (int s = 0; s < 4; s++){
      int row = wid*32 + s*8 + srow;
      gload16(Wbase + ((size_t)tap*128 + row)*128 + kk0 + scol, &As[(wid*32 + s*8)*64]);
    }
    #pragma unroll
    for (int s = 0; s < 4; s++){
      int row = wid*32 + s*8 + srow;
      int sd = bn + row + tap - 1;
      const bf16* src = (sd >= 0 && sd < DM)
        ? (HT + (((size_t)b*DM + sd)*2 + g)*128 + kk0 + scol) : zpage;
      gload16(src, &Bs[(wid*32 + s*8)*64]);
    }
    __syncthreads();
    #pragma unroll
    for (int ks = 0; ks < 2; ks++){
      bf16x8 af[4], bg[4];
      #pragma unroll
      for (int m = 0; m < 4; m++)
        af[m] = *(const bf16x8*)&As[(wr*64 + m*16 + (lane & 15))*64 + ks*32 + (lane >> 4)*8];
      #pragma unroll
      for (int n = 0; n < 4; n++)
        bg[n] = *(const bf16x8*)&Bs[(wc*64 + n*16 + (lane & 15))*64 + ks*32 + (lane >> 4)*8];
      #pragma unroll
      for (int m = 0; m < 4; m++)
        #pragma unroll
        for (int n = 0; n < 4; n++)
          acc[m][n] = __builtin_amdgcn_mfma_f32_16x16x32_bf16(af[m], bg[n], acc[m][n], 0, 0, 0);
    }
  }
  const int c_l = lane & 15, r4 = (lane >> 4) * 4;
  #pragma unroll
  for (int m = 0; m < 4; m++){
    #pragma unroll
    for (int n = 0; n < 4; n++){
      #pragma unroll
      for (int r = 0; r < 4; r++){
        int lo = wr*64 + m*16 + r4 + r;
        if (lo < 125){
          int d = bn + wc*64 + n*16 + c_l;
          float v = acc[m][n][r] + bias[g*125 + lo];
          X[((size_t)b*SEQ + g*125 + lo)*DM + d] += gelu_tanh(v);
        }
      }
    }
  }
}

// ---------------- transpose H[b][l][d] bf16 -> HT[b][d][g*128+li] bf16 ----------------
__global__ __launch_bounds__(256) void transpose_ht(const bf16* __restrict__ H,
                                                    bf16* __restrict__ HT){
  __shared__ bf16 t[68][66];
  int d0 = blockIdx.x * 64;
  int p0 = blockIdx.y * 64;
  int b  = blockIdx.z;
  int tid = threadIdx.x;
  int l0 = p0 - 3;
  for (int i = tid; i < 68*64; i += 256){
    int r = i >> 6, c = i & 63;
    int l = l0 + r;
    bf16 v = __float2bfloat16(0.f);
    if (l >= 0 && l < SEQ) v = H[((size_t)b*SEQ + l)*DM + d0 + c];
    t[r][c] = v;
  }
  __syncthreads();
  for (int i = tid; i < 64*64; i += 256){
    int rr = i >> 6, cc = i & 63;
    int p = p0 + cc;
    int gg = p >> 7, li = p & 127;
    int l = gg*125 + li;
    bf16 v = __float2bfloat16(0.f);
    if (li < 125 && l < SEQ) v = t[l - l0][rr];
    HT[((size_t)b*DM + d0 + rr)*256 + p] = v;
  }
}

// ---------------- weight prep ----------------
__global__ void zfill(bf16* z){ z[threadIdx.x] = __float2bfloat16(0.f); }

__global__ __launch_bounds__(256) void build_projT(const float* __restrict__ Wv,
    const float* __restrict__ Wo, bf16* __restrict__ WvT, bf16* __restrict__ WoT){
  __shared__ float t[32][33];
  int mat = blockIdx.z;
  const float* W = (mat < 4) ? (Wv + (size_t)mat*DM*DM) : (Wo + (size_t)(mat-4)*DM*DM);
  bf16* WT = (mat < 4) ? (WvT + (size_t)mat*DM*DM) : (WoT + (size_t)(mat-4)*DM*DM);
  int k0 = blockIdx.y*32, n0 = blockIdx.x*32;
  int tx = threadIdx.x & 31, ty = threadIdx.x >> 5;
  #pragma unroll
  for (int r = 0; r < 32; r += 8)
    t[ty + r][tx] = W[(size_t)(k0 + ty + r)*DM + n0 + tx];
  __syncthreads();
  #pragma unroll
  for (int r = 0; r < 32; r += 8)
    WT[(size_t)(n0 + ty + r)*DM + k0 + tx] = __float2bfloat16(t[tx][ty + r]);
}

__global__ __launch_bounds__(256) void build_qkhl(const float* __restrict__ Wq,
    const float* __restrict__ Wk, bf16* __restrict__ WT){
  __shared__ float t[32][33];
  int mat = blockIdx.z;
  const float* W = (mat < 4) ? (Wq + (size_t)mat*DM*DM) : (Wk + (size_t)(mat-4)*DM*DM);
  bf16* hi = WT + (size_t)mat*2*DM*DM;
  bf16* lo = hi + (size_t)DM*DM;
  int k0 = blockIdx.y*32, n0 = blockIdx.x*32;
  int tx = threadIdx.x & 31, ty = threadIdx.x >> 5;
  #pragma unroll
  for (int r = 0; r < 32; r += 8)
    t[ty + r][tx] = W[(size_t)(k0 + ty + r)*DM + n0 + tx];
  __syncthreads();
  #pragma unroll
  for (int r = 0; r < 32; r += 8){
    float w = t[tx][ty + r];
    bf16 h = __float2bfloat16(w);
    hi[(size_t)(n0 + ty + r)*DM + k0 + tx] = h;
    lo[(size_t)(n0 + ty + r)*DM + k0 + tx] = __float2bfloat16(w - __bfloat162float(h));
  }
}

__global__ void build_c1aT(const float* __restrict__ W, const float* __restrict__ bin,
                           bf16* __restrict__ WT, float* __restrict__ bias_pad){
  int i = blockIdx.x*256 + threadIdx.x;
  if (i < 4*DM){
    int l = i/DM, n = i%DM;
    bias_pad[i] = (n < HID) ? bin[l*HID + n] : 0.f;
  }
  if (i >= 4*3*DM*DM) return;
  int k = i % DM; int n = (i/DM) % DM; int t = (i/(DM*DM)) % 3; int l = i/(3*DM*DM);
  float v = 0.f;
  if (n < HID){
    int g = n / 114; int ci = k - g*128;
    if (ci >= 0 && ci < 128)
      v = W[(((size_t)l*HID + n)*128 + ci)*3 + t];
  }
  WT[i] = __float2bfloat16(v);
}

__global__ void build_c1bT(const float* __restrict__ W, bf16* __restrict__ WT){
  int i = blockIdx.x*256 + threadIdx.x;
  if (i >= 4*3*DM*DM) return;
  int k = i % DM; int n = (i/DM) % DM; int t = (i/(DM*DM)) % 3; int l = i/(3*DM*DM);
  int g = n >> 7; int ci = k - g*114;
  float v = 0.f;
  if (ci >= 0 && ci < 114)
    v = W[(((size_t)l*DM + n)*114 + ci)*3 + t];
  WT[i] = __float2bfloat16(v);
}

__global__ void build_c2T(const float* __restrict__ W, bf16* __restrict__ WT){
  int i = blockIdx.x*256 + threadIdx.x;
  if (i >= 4*2*3*128*128) return;
  int li = i & 127;
  int lo = (i >> 7) & 127;
  int t  = (i / 16384) % 3;
  int g  = (i / 49152) % 2;
  int l  = i / 98304;
  float v = 0.f;
  if (lo < 125 && li < 125)
    v = W[(((size_t)l*SEQ + g*125 + lo)*125 + li)*3 + t];
  WT[i] = __float2bfloat16(v);
}

// ---------------- fused probe + top-k: one block per (b,h), float2 K reads ----------------
__global__ __launch_bounds__(256) void probe_topk(const float* __restrict__ Q,
    const float* __restrict__ K, const int* __restrict__ idx, int* __restrict__ TOP){
  __shared__ float Ksh[SEQ*50];    // stride 50 f32 (200 B rows, float2-aligned)
  __shared__ float s_redv[4];
  __shared__ int   s_redi[4];
  __shared__ int   s_win;
  int bh = blockIdx.x; int h = bh & 7; int b = bh >> 3;
  int tid = threadIdx.x;
  const size_t base = (size_t)b*SEQ*DM + h*DHd;
  for (int i = tid; i < SEQ*24; i += 256){
    int r = i / 24, c = i - r*24;
    float2 kv = *(const float2*)&K[base + (size_t)r*DM + 2*c];
    *(float2*)&Ksh[r*50 + 2*c] = kv;
  }
  __syncthreads();
  int l = tid;
  float Mv = -FLT_MAX;
  if (l < SEQ){
    float qr[DHd];
    const float* qp = Q + ((size_t)(b*SEQ + l))*DM + h*DHd;
    #pragma unroll
    for (int z4 = 0; z4 < 12; z4++){
      float4 qv = *(const float4*)&qp[4*z4];
      qr[4*z4] = qv.x; qr[4*z4+1] = qv.y; qr[4*z4+2] = qv.z; qr[4*z4+3] = qv.w;
    }
    const int* ip = idx + l*UU;
    float mx = -FLT_MAX, sm = 0.f;
    for (int u = 0; u < UU; u++){
      const float2* kr = (const float2*)&Ksh[ip[u]*50];
      float d = 0.f;
      #pragma unroll
      for (int z = 0; z < 24; z++){
        float2 kk = kr[z];
        d += qr[2*z]*kk.x + qr[2*z+1]*kk.y;
      }
      mx = fmaxf(mx, d); sm += d;
    }
    Mv = mx - sm*(1.f/UU);
  }
  int myid = (l < SEQ) ? l : (1<<30);
  int lane = tid & 63, wid = tid >> 6;
  for (int sel = 0; sel < UU; sel++){
    float bv = Mv; int bi = myid;
    #pragma unroll
    for (int off = 32; off; off >>= 1){
      float ov = __shfl_xor(bv, off);
      int   oi = __shfl_xor(bi, off);
      if (ov > bv || (ov == bv && oi < bi)){ bv = ov; bi = oi; }
    }
    if (lane == 0){ s_redv[wid] = bv; s_redi[wid] = bi; }
    __syncthreads();
    if (tid == 0){
      float wv = s_redv[0]; int wi = s_redi[0];
      #pragma unroll
      for (int q = 1; q < 4; q++)
        if (s_redv[q] > wv || (s_redv[q] == wv && s_redi[q] < wi)){ wv = s_redv[q]; wi = s_redi[q]; }
      TOP[(size_t)bh*UU + sel] = wi;
      s_win = wi;
    }
    __syncthreads();
    if (myid == s_win) Mv = -FLT_MAX;
  }
}

// ---------------- fused attention context per (b,h): packed bf16x2 LDS, wave softmax ----------------
static constexpr int UG = 10;
__global__ __launch_bounds__(256) void attn_ctx4(const float* __restrict__ Q,
    const float* __restrict__ K, const float* __restrict__ V,
    const int* __restrict__ TOP, bf16* __restrict__ CTX){
  __shared__ uint32_t Ksh[SEQ*25];     // bf16x2, row stride 25 u32 (odd -> banks spread)
  __shared__ uint32_t Vsh[DHd*129];    // transposed bf16x2: Vsh[dh*129+jp] = {V[2jp][dh], V[2jp+1][dh]}
  __shared__ float qsh[UG][DHd];       // pre-scaled by 1/sqrt(48)
  __shared__ float psh[UG][SEQ];
  __shared__ float invsh[UG];
  __shared__ float part[UG][5][DHd];
  __shared__ float vmean[DHd];
  __shared__ int   mark[SEQ];
  int bh = blockIdx.x; int h = bh & 7; int b = bh >> 3;
  int tid = threadIdx.x;
  const size_t base = (size_t)b*SEQ*DM + h*DHd;
  // stage K packed
  for (int i = tid; i < SEQ*24; i += 256){
    int r = i / 24, c = i - r*24;
    float2 kv = *(const float2*)&K[base + (size_t)r*DM + 2*c];
    Ksh[r*25 + c] = packbf2(kv.x, kv.y);
  }
  // stage V transposed packed
  for (int i = tid; i < 125*DHd; i += 256){
    int jp = i / DHd, dh = i - jp*DHd;
    float v0 = V[base + (size_t)(2*jp)*DM + dh];
    float v1 = V[base + (size_t)(2*jp+1)*DM + dh];
    Vsh[dh*129 + jp] = packbf2(v0, v1);
  }
  for (int i = tid; i < SEQ; i += 256) mark[i] = -1;
  __syncthreads();
  if (tid < UU) mark[TOP[(size_t)bh*UU + tid]] = tid;
  // vmean from Vsh
  if (tid < 240){
    int dh = tid % DHd, pr = tid / DHd;
    const uint32_t* vr = &Vsh[dh*129 + pr*25];
    float s = 0.f;
    #pragma unroll
    for (int z = 0; z < 25; z++){ uint32_t vp = vr[z]; s += unpk_lo(vp) + unpk_hi(vp); }
    part[0][pr][dh] = s;
  }
  __syncthreads();
  if (tid < DHd)
    vmean[tid] = (part[0][0][tid]+part[0][1][tid]+part[0][2][tid]+part[0][3][tid]+part[0][4][tid]) * (1.f/SEQ);
  __syncthreads();
  // 3 passes of 10 u's
  for (int u0 = 0; u0 < UU; u0 += UG){
    for (int i = tid; i < UG*DHd; i += 256){
      int uu = i / DHd, z = i - uu*DHd;
      int l0 = TOP[(size_t)bh*UU + u0 + uu];
      qsh[uu][z] = Q[(size_t)(b*SEQ + l0)*DM + h*DHd + z] * 0.14433756729740643f;
    }
    __syncthreads();
    // scores
    if (tid < SEQ){
      float s[UG];
      #pragma unroll
      for (int u = 0; u < UG; u++) s[u] = 0.f;
      const uint32_t* kr = &Ksh[tid*25];
      for (int z = 0; z < 24; z++){
        uint32_t kp = kr[z];
        float k0 = unpk_lo(kp), k1 = unpk_hi(kp);
        #pragma unroll
        for (int u = 0; u < UG; u++)
          s[u] += qsh[u][2*z]*k0 + qsh[u][2*z+1]*k1;
      }
      #pragma unroll
      for (int u = 0; u < UG; u++) psh[u][tid] = s[u];
    }
    __syncthreads();
    // wave-parallel softmax: wave w handles u = w, w+4, w+8
    {
      int wv = tid >> 6, lane = tid & 63;
      for (int u = wv; u < UG; u += 4){
        float x0 = psh[u][lane];
        float x1 = psh[u][lane+64];
        float x2 = psh[u][lane+128];
        float x3 = (lane+192 < SEQ) ? psh[u][lane+192] : -FLT_MAX;
        float mx = fmaxf(fmaxf(x0,x1), fmaxf(x2,x3));
        #pragma unroll
        for (int off = 32; off; off >>= 1) mx = fmaxf(mx, __shfl_xor(mx, off));
        float e0 = expf(x0-mx), e1 = expf(x1-mx), e2 = expf(x2-mx);
        float e3 = (lane+192 < SEQ) ? expf(x3-mx) : 0.f;
        psh[u][lane] = e0; psh[u][lane+64] = e1; psh[u][lane+128] = e2;
        if (lane+192 < SEQ) psh[u][lane+192] = e3;
        float sm = e0+e1+e2+e3;
        #pragma unroll
        for (int off = 32; off; off >>= 1) sm += __shfl_xor(sm, off);
        if (lane == 0) invsh[u] = 1.f/sm;
      }
    }
    __syncthreads();
    // PV from transposed packed V
    if (tid < 240){
      int dh = tid % DHd, pr = tid / DHd;
      float a[UG];
      #pragma unroll
      for (int u = 0; u < UG; u++) a[u] = 0.f;
      const uint32_t* vr = &Vsh[dh*129 + pr*25];
      #pragma unroll 5
      for (int z = 0; z < 25; z++){
        uint32_t vp = vr[z];
        float v0 = unpk_lo(vp), v1 = unpk_hi(vp);
        int j = (pr*25 + z)*2;
        #pragma unroll
        for (int u = 0; u < UG; u++)
          a[u] += psh[u][j]*v0 + psh[u][j+1]*v1;
      }
      #pragma unroll
      for (int u = 0; u < UG; u++) part[u][pr][dh] = a[u];
    }
    __syncthreads();
    for (int i = tid; i < UG*DHd; i += 256){
      int uu = i / DHd, dh = i - uu*DHd;
      float acc = (part[uu][0][dh]+part[uu][1][dh]+part[uu][2][dh]+part[uu][3][dh]+part[uu][4][dh]) * invsh[uu];
      int l0 = TOP[(size_t)bh*UU + u0 + uu];
      CTX[(size_t)(b*SEQ + l0)*DM + h*DHd + dh] = __float2bfloat16(acc);
    }
    __syncthreads();
  }
  // fill non-top rows with vmean
  for (int i = tid; i < SEQ*DHd; i += 256){
    int l = i / DHd, dh = i - l*DHd;
    if (mark[l] < 0)
      CTX[(size_t)(b*SEQ + l)*DM + h*DHd + dh] = __float2bfloat16(vmean[dh]);
  }
}

// ---------------- final: max over L -> LN(ln2) -> FC ----------------
__global__ __launch_bounds__(384) void final_kernel(const float* __restrict__ Hin,
    const float* __restrict__ w, const float* __restrict__ bparm,
    const float* __restrict__ fcw, const float* __restrict__ fcb, float* __restrict__ out){
  __shared__ float red[8];
  __shared__ float ybuf[DM];
  int b = blockIdx.x; int d = threadIdx.x;
  const float* hp = Hin + (size_t)b*SEQ*DM + d;
  float mx = -FLT_MAX;
  for (int l=0;l<SEQ;l++) mx = fmaxf(mx, hp[(size_t)l*DM]);
  float mu = block_sum(mx, red) * (1.f/DM);
  float diff = mx - mu;
  float var = block_sum(diff*diff, red) * (1.f/DM);
  float y = diff * rsqrtf(var + 1e-5f) * w[d] + bparm[d];
  ybuf[d] = y;
  __syncthreads();
  if (d < 10){
    float acc = fcb[d];
    for (int k=0;k<DM;k++) acc += ybuf[k] * fcw[k*10 + d];
    out[b*10 + d] = acc;
  }
}

// ---------------- host orchestration ----------------
extern "C" void kernel_launch(void* const* d_in, const int* in_sizes, int n_in,
                              void* d_out, int out_size, void* d_ws, size_t ws_size,
                              hipStream_t stream) {
  const float* x     = (const float*)d_in[0];
  const float* pos   = (const float*)d_in[1];
  const float* lniw  = (const float*)d_in[2];
  const float* lnib  = (const float*)d_in[3];
  const float* lnAw  = (const float*)d_in[4];
  const float* lnAb  = (const float*)d_in[5];
  const float* Wq    = (const float*)d_in[6];
  const float* bq    = (const float*)d_in[7];
  const float* Wk    = (const float*)d_in[8];
  const float* bk    = (const float*)d_in[9];
  const float* Wv    = (const float*)d_in[10];
  const float* bv    = (const float*)d_in[11];
  const float* Wo    = (const float*)d_in[12];
  const float* bo    = (const float*)d_in[13];
  const float* lnBw  = (const float*)d_in[14];
  const float* lnBb  = (const float*)d_in[15];
  const float* c1aw  = (const float*)d_in[16];
  const float* c1ab  = (const float*)d_in[17];
  const float* c1bw  = (const float*)d_in[18];
  const float* c1bb  = (const float*)d_in[19];
  const float* lnCw  = (const float*)d_in[20];
  const float* lnCb  = (const float*)d_in[21];
  const float* c2w   = (const float*)d_in[22];
  const float* c2b   = (const float*)d_in[23];
  const float* ln2w  = (const float*)d_in[24];
  const float* ln2b  = (const float*)d_in[25];
  const float* fcw   = (const float*)d_in[26];
  const float* fcb   = (const float*)d_in[27];
  float* out = (float*)d_out;

  const size_t ACT  = (size_t)Bb*SEQ*DM;        // 12,288,000
  float* Xb  = (float*)d_ws;
  float* Hb  = Xb  + ACT;                       // f32 for final LN; aliased as Alo bf16 early
  float* Qb  = Hb  + ACT;                       // aliased as HT bf16 in conv2 phase
  float* Kb  = Qb  + ACT;
  float* Vb  = Kb  + ACT;
  float* biasA = Vb + ACT;
  int*   TOP = (int*)(biasA + 4*DM);
  int*   IDX = TOP + (size_t)Bb*NH*UU;
  bf16*  Hb16 = (bf16*)(IDX + 4*7500);          // Ahi / CTX16 / conv input
  bf16*  G1   = Hb16 + ACT;
  bf16*  WvT  = G1   + ACT;
  bf16*  WoT  = WvT  + (size_t)4*DM*DM;
  bf16*  WaT  = WoT  + (size_t)4*DM*DM;
  bf16*  WbT  = WaT  + (size_t)12*DM*DM;
  bf16*  WqkT = WbT  + (size_t)12*DM*DM;        // [8][2][384][384]
  bf16*  W2T  = WqkT + (size_t)16*DM*DM;        // [4][2][3][128][128]
  bf16*  zp   = W2T  + (size_t)4*2*3*128*128;

  zfill<<<dim3(1), dim3(256), 0, stream>>>(zp);
  idx_kernel<<<dim3(118), dim3(256), 0, stream>>>(IDX);
  build_projT<<<dim3(12,12,8), dim3(256), 0, stream>>>(Wv, Wo, WvT, WoT);
  build_qkhl<<<dim3(12,12,8), dim3(256), 0, stream>>>(Wq, Wk, WqkT);
  build_c1aT<<<dim3(6912), dim3(256), 0, stream>>>(c1aw, c1ab, WaT, biasA);
  build_c1bT<<<dim3(6912), dim3(256), 0, stream>>>(c1bw, WbT);
  build_c2T<<<dim3(1536), dim3(256), 0, stream>>>(c2w, W2T);
  pool_ln_pos<<<dim3(32000), dim3(384), 0, stream>>>(x, pos, lniw, lnib, Xb);

  for (int l = 0; l < 4; l++){
    const size_t wofs = (size_t)l*DM*DM;
    bf16* Alo16 = (bf16*)Hb;          // alias: Hb f32 unused until final LN
    bf16* CTX16 = Hb16;               // reuse after V-proj
    bf16* HTb   = (bf16*)Qb;          // alias: Qb dead after attention
    ln_wave<2><<<dim3(8000), dim3(256), 0, stream>>>(Xb, (float*)nullptr, Hb16, Alo16, lnAw + l*DM, lnAb + l*DM);
    mfma_qk2<<<dim3(3,250), dim3(256), 0, stream>>>(Hb16, Alo16,
        WqkT + (size_t)l*2*DM*DM, WqkT + (size_t)(4+l)*2*DM*DM,
        bq + l*DM, bk + l*DM, Qb, Kb);
    mfma_gemm<1,0><<<dim3(3,250), dim3(256), 0, stream>>>(Hb16, WvT + wofs, bv + l*DM, Vb, (bf16*)nullptr, zp);
    probe_topk<<<dim3(Bb*NH), dim3(256), 0, stream>>>(Qb, Kb, IDX + l*7500, TOP);
    attn_ctx4<<<dim3(Bb*NH), dim3(256), 0, stream>>>(Qb, Kb, Vb, TOP, CTX16);
    mfma_gemm<1,1><<<dim3(3,250), dim3(256), 0, stream>>>(CTX16, WoT + wofs, bo + l*DM, Xb, (bf16*)nullptr, zp);

    ln_wave<1><<<dim3(8000), dim3(256), 0, stream>>>(Xb, (float*)nullptr, Hb16, (bf16*)nullptr, lnBw + l*DM, lnBb + l*DM);
    mfma_gemm<3,2><<<dim3(3,250), dim3(256), 0, stream>>>(Hb16, WaT + (size_t)l*3*DM*DM, biasA + l*DM, (float*)nullptr, G1, zp);
    mfma_gemm<3,1><<<dim3(3,250), dim3(256), 0, stream>>>(G1, WbT + (size_t)l*3*DM*DM, c1bb + l*DM, Xb, (bf16*)nullptr, zp);

    ln_wave<1><<<dim3(8000), dim3(256), 0, stream>>>(Xb, (float*)nullptr, Hb16, (bf16*)nullptr, lnCw + l*DM, lnCb + l*DM);
    transpose_ht<<<dim3(6,4,Bb), dim3(256), 0, stream>>>(Hb16, HTb);
    conv2_mfma<<<dim3(3,2,Bb), dim3(256), 0, stream>>>(HTb, W2T + (size_t)l*2*3*128*128, c2b + l*SEQ, Xb, zp);
  }

  ln_wave<0><<<dim3(8000), dim3(256), 0, stream>>>(Xb, Hb, (bf16*)nullptr, (bf16*)nullptr, ln2w, ln2b);
  final_kernel<<<dim3(Bb), dim3(384), 0, stream>>>(Hb, ln2w, ln2b, fcw, fcb, out);
}